// Round 11
// baseline (607.908 us; speedup 1.0000x reference)
//
#include <hip/hip_runtime.h>

typedef unsigned short u16;
typedef unsigned int   u32;

typedef __attribute__((ext_vector_type(8)))  __bf16 bf16x8;
typedef __attribute__((ext_vector_type(4)))  float  f32x4;
typedef __attribute__((ext_vector_type(16))) float  f32x16;

// ---------- scalar/vec conversion helpers ----------
__device__ __forceinline__ float bf2f(u16 v) {
    return __uint_as_float(((u32)v) << 16);
}
__device__ __forceinline__ u16 f2bf(float f) {
    u32 u = __float_as_uint(f);
    u32 r = (u + 0x7fffu + ((u >> 16) & 1u)) >> 16;  // round-to-nearest-even
    return (u16)r;
}
__device__ __forceinline__ float ld1(const u16* p)   { return bf2f(*p); }
__device__ __forceinline__ float ld1(const float* p) { return *p; }

// ---------- problem constants ----------
#define BB 4
#define NTOK 2048
#define NATOM 16384
#define CTOK 384
#define CA 128
#define NQ 32
#define NK 128
#define NH 4
#define DH 32
#define NWIN 512
#define PAD 48

// Transposed-weight workspace layout (u16 elements).
// Each matrix stored as [N][K] hi-plane, then lo-plane (lo = 0 for bf16 input).
#define WT_WA   0          // [128][384], lo plane at +49152
#define WT_L0   98304      // per-layer block start
#define WT_LSZ  393216     // Q 0 | K 32768 | V 65536 | O 98304 | T1 131072 | T2 262144
#define WT_WO   1277952    // [128][128], lo plane at +16384
#define WT_TOT  1310720

// Aux f32 scratch layout (floats)
#define AX_WCL  0
#define AX_WCM  2048
#define AX_WM1  4096
#define AX_WM2  4352
#define AX_WPB  4608
#define AX_L1G  4672
#define AX_L1B  5056
#define AX_L2G  5440
#define AX_L2B  5824
#define AX_TOT  6208

// =====================================================================
// dtype detector: look at low u16 of 1024 words of W_a.
// flag = 1 (bf16 inputs) or 0 (f32 inputs)
// =====================================================================
__global__ __launch_bounds__(256) void detect_kernel(const u32* __restrict__ wa,
                                                     int* __restrict__ flag)
{
    __shared__ int cnt;
    if (threadIdx.x == 0) cnt = 0;
    __syncthreads();
    int local = 0;
#pragma unroll
    for (int i = 0; i < 4; i++) {
        u32 w = wa[threadIdx.x * 4 + i];
        u32 e = (w >> 7) & 0xFFu;   // exponent field of the LOW u16 as bf16
        if (e >= 95u && e <= 135u) local++;
    }
    atomicAdd(&cnt, local);
    __syncthreads();
    if (threadIdx.x == 0) *flag = (cnt >= 614) ? 1 : 0;
}

// =====================================================================
// Weight transpose + bf16 hi/lo split into WT workspace, plus f32 aux
// conversion.  41 blocks; gated on dtype flag.
// =====================================================================
template<typename TIN>
__global__ __launch_bounds__(256) void wtrans_kernel(
    const int* __restrict__ flag, int want,
    const TIN* __restrict__ Wa, const TIN* __restrict__ Wq,
    const TIN* __restrict__ Wk, const TIN* __restrict__ Wv,
    const TIN* __restrict__ Wo, const TIN* __restrict__ Wt1,
    const TIN* __restrict__ Wt2, const TIN* __restrict__ Wout,
    const TIN* __restrict__ Wcl, const TIN* __restrict__ Wcm,
    const TIN* __restrict__ Wm1, const TIN* __restrict__ Wm2,
    const TIN* __restrict__ Wpb, const TIN* __restrict__ l1g,
    const TIN* __restrict__ l1b, const TIN* __restrict__ l2g,
    const TIN* __restrict__ l2b,
    u16* __restrict__ WT, float* __restrict__ AX)
{
    if (*flag != want) return;
    const int t = blockIdx.x;
    const int tid = threadIdx.x;
    if (t == 40) {   // aux f32 conversion
        for (int i = tid; i < 2048; i += 256) AX[AX_WCL + i] = ld1(Wcl + i);
        for (int i = tid; i < 2048; i += 256) AX[AX_WCM + i] = ld1(Wcm + i);
        AX[AX_WM1 + tid] = ld1(Wm1 + tid);
        AX[AX_WM2 + tid] = ld1(Wm2 + tid);
        if (tid < 64) AX[AX_WPB + tid] = ld1(Wpb + tid);
        for (int i = tid; i < 384; i += 256) {
            AX[AX_L1G + i] = ld1(l1g + i);
            AX[AX_L1B + i] = ld1(l1b + i);
            AX[AX_L2G + i] = ld1(l2g + i);
            AX[AX_L2B + i] = ld1(l2b + i);
        }
        return;
    }
    const TIN* S; int sld; u16* D; int dld; int plane;
    if (t < 3) {                                     // W_a [384][128]
        S = Wa + t * 128 * 128; sld = 128;
        D = WT + WT_WA + t * 128; dld = 384; plane = 49152;
    } else if (t < 15) {                             // Wq/k/v/o [128][128]
        const int i = t - 3, l = i >> 2, m = i & 3;
        const TIN* ms = (m == 0) ? Wq : (m == 1) ? Wk : (m == 2) ? Wv : Wo;
        S = ms + l * 16384; sld = 128;
        D = WT + WT_L0 + l * WT_LSZ + m * 32768; dld = 128; plane = 16384;
    } else if (t < 27) {                             // Wt1 [128][512] col-chunk c
        const int i = t - 15, l = i >> 2, c = i & 3;
        S = Wt1 + l * 65536 + c * 128; sld = 512;
        D = WT + WT_L0 + l * WT_LSZ + 131072 + c * 128 * 128; dld = 128; plane = 65536;
    } else if (t < 39) {                             // Wt2 [512][128] row-chunk c
        const int i = t - 27, l = i >> 2, c = i & 3;
        S = Wt2 + l * 65536 + c * 128 * 128; sld = 128;
        D = WT + WT_L0 + l * WT_LSZ + 262144 + c * 128; dld = 512; plane = 65536;
    } else {                                         // W_out [128][128]
        S = Wout; sld = 128;
        D = WT + WT_WO; dld = 128; plane = 16384;
    }
    for (int id = tid; id < 2048; id += 256) {
        const int n = id >> 4, k0 = (id & 15) << 3;
        union { u16 s[8]; uint4 v; } hi, lo;
#pragma unroll
        for (int j = 0; j < 8; j++) {
            if constexpr (sizeof(TIN) == 2) {
                hi.s[j] = ((const u16*)(const void*)S)[(k0 + j) * sld + n];
                lo.s[j] = 0;
            } else {
                const float v = ((const float*)(const void*)S)[(k0 + j) * sld + n];
                const u16 hv = f2bf(v);
                hi.s[j] = hv;
                lo.s[j] = f2bf(v - bf2f(hv));
            }
        }
        *(uint4*)(D + n * dld + k0) = hi.v;
        *(uint4*)(D + plane + n * dld + k0) = lo.v;
    }
}

// =====================================================================
// Async weight-panel staging via global_load_lds (no staging VGPRs).
// LDS image: [plane][128 rows][256 B] LINEAR in segment order; the XOR
// swizzle byte^((row&15)<<4) is applied to the per-lane GLOBAL source
// (inverse-swz source + swz read = both-sides rule).
// =====================================================================
__device__ __forceinline__ void gld16(const void* g, void* l)
{
    __builtin_amdgcn_global_load_lds(
        (const __attribute__((address_space(1))) void*)g,
        (__attribute__((address_space(3))) void*)l, 16, 0, 0);
}

template<int NS, int NTHR>
__device__ __forceinline__ void stage_async(u16* lds, const u16* srcHi,
                                            const u16* srcLo, int strideU16, int tid)
{
    constexpr int NWAVE = NTHR / 64;
    constexpr int NSEG  = NS * 32768 / (NWAVE * 1024);
    const int lane = tid & 63;
    const int wv   = tid >> 6;
#pragma unroll
    for (int i = 0; i < NSEG; i++) {
        const int segoff  = (wv * NSEG + i) << 10;      // byte, wave-uniform
        const int po_full = segoff + lane * 16;
        const int plane   = po_full >> 15;
        const int po      = po_full & 32767;
        const int row     = po >> 8;
        const int colB    = (po & 255) ^ ((row & 15) << 4);
        const u16* g = (plane ? srcLo : srcHi) + row * strideU16 + (colB >> 1);
        gld16(g, (char*)lds + segoff);
    }
}

// Swizzled b128 read of 8 contiguous k-elements of panel row `row`.
__device__ __forceinline__ bf16x8 ld_w32(const u16* lds, int plane, int row, int kbyte)
{
    union { uint4 q; bf16x8 v; } u;
    u.q = *(const uint4*)((const char*)lds + plane * 32768 + row * 256
                          + (kbyte ^ ((row & 15) << 4)));
    return u.v;
}

// C/D row of mfma_f32_32x32x16 for accumulator register r (HW-verified m74/m101)
__device__ __forceinline__ int crow(int r, int lh) {
    return (r & 3) + 8 * (r >> 2) + 4 * lh;
}

__device__ __forceinline__ f32x16 zero16() {
    f32x16 z;
#pragma unroll
    for (int i = 0; i < 16; i++) z[i] = 0.f;
    return z;
}

// MFMA over one staged 128x128 panel with 32x32x16: 32 rows/wave.
template<int NS>
__device__ __forceinline__ void mfma_panel32(const u16* Wbuf, const bf16x8* a,
                                             int l31, int lh, f32x16* acc)
{
#pragma unroll
    for (int ks = 0; ks < 8; ks++)
#pragma unroll
        for (int n = 0; n < 4; n++) {
            const int rw = n * 32 + l31, kb = ks * 32 + lh * 16;
            const bf16x8 b = ld_w32(Wbuf, 0, rw, kb);
            acc[n] = __builtin_amdgcn_mfma_f32_32x32x16_bf16(a[ks], b, acc[n], 0, 0, 0);
            if (NS == 2) {
                const bf16x8 bl = ld_w32(Wbuf, 1, rw, kb);
                acc[n] = __builtin_amdgcn_mfma_f32_32x32x16_bf16(a[ks], bl, acc[n], 0, 0, 0);
            }
        }
}

// Split-A variant: acc += ah@W + al@W (+ ah@Wlo when NS==2)
template<int NS>
__device__ __forceinline__ void mfma_panel32_split(const u16* Wbuf,
    const bf16x8* ah, const bf16x8* al, int l31, int lh, f32x16* acc)
{
#pragma unroll
    for (int ks = 0; ks < 8; ks++)
#pragma unroll
        for (int n = 0; n < 4; n++) {
            const int rw = n * 32 + l31, kb = ks * 32 + lh * 16;
            const bf16x8 b = ld_w32(Wbuf, 0, rw, kb);
            acc[n] = __builtin_amdgcn_mfma_f32_32x32x16_bf16(ah[ks], b, acc[n], 0, 0, 0);
            acc[n] = __builtin_amdgcn_mfma_f32_32x32x16_bf16(al[ks], b, acc[n], 0, 0, 0);
            if (NS == 2) {
                const bf16x8 bl = ld_w32(Wbuf, 1, rw, kb);
                acc[n] = __builtin_amdgcn_mfma_f32_32x32x16_bf16(ah[ks], bl, acc[n], 0, 0, 0);
            }
        }
}

// split 8 contiguous f32 into hi/lo bf16x8
__device__ __forceinline__ void splitf8(const float* p, bf16x8* hi, bf16x8* lo)
{
    const float4 f0 = *(const float4*)p;
    const float4 f1 = *(const float4*)(p + 4);
    const float f[8] = {f0.x, f0.y, f0.z, f0.w, f1.x, f1.y, f1.z, f1.w};
    union { u16 s[8]; bf16x8 v; } H, L;
#pragma unroll
    for (int j = 0; j < 8; j++) {
        const u16 hv = f2bf(f[j]);
        H.s[j] = hv;
        L.s[j] = f2bf(f[j] - bf2f(hv));
    }
    *hi = H.v; *lo = L.v;
}

// =====================================================================
// Staged-weight MFMA GEMM (bf16 A): C[M x 128] = A[M x K] @ W.
// 128-row blocks, 256 thr, 4 waves x 32 rows, 2 blocks/CU.
// =====================================================================
template<int NS, int KCH, bool OUT_BF16, bool ADD>
__global__ __launch_bounds__(256, 2) void sgemm_bf(
    const int* __restrict__ flag, int want,
    const u16* __restrict__ A, int lda,
    const u16* __restrict__ WHi, const u16* __restrict__ WLo,
    int wstride, int wcstep,
    void* __restrict__ Cv, int ldc)
{
    if (want >= 0 && *flag != want) return;
    __shared__ __align__(16) u16 Wbuf[NS * 16384];
    const int tid = threadIdx.x;
    const int lane = tid & 63, wv = tid >> 6;
    const int l31 = lane & 31, lh = lane >> 5;
    const long long row0 = (long long)blockIdx.x * 128 + wv * 32;

    f32x16 acc[4];
#pragma unroll
    for (int n = 0; n < 4; n++) acc[n] = zero16();

    const u16* A0 = A + (row0 + l31) * (long long)lda + lh * 8;

    stage_async<NS, 256>(Wbuf, WHi, WLo, wstride, tid);
    for (int ks = 0; ks < KCH; ks++) {
        bf16x8 a[8];
#pragma unroll
        for (int kk = 0; kk < 8; kk++)
            a[kk] = *(const bf16x8*)(A0 + ks * 128 + kk * 16);
        __syncthreads();                       // panel staged (vmcnt drained)
        mfma_panel32<NS>(Wbuf, a, l31, lh, acc);
        if (ks + 1 < KCH) {
            __syncthreads();                   // panel reads done before restage
            stage_async<NS, 256>(Wbuf, WHi + (ks + 1) * wcstep,
                                 WLo + (ks + 1) * wcstep, wstride, tid);
        }
    }

#pragma unroll
    for (int r = 0; r < 16; r++) {
        const long long row = row0 + crow(r, lh);
        if (OUT_BF16) {
            u16* C = (u16*)Cv + row * ldc;
#pragma unroll
            for (int n = 0; n < 4; n++) C[n * 32 + l31] = f2bf(acc[n][r]);
        } else {
            float* C = (float*)Cv + row * ldc;
#pragma unroll
            for (int n = 0; n < 4; n++) {
                float v = acc[n][r];
                if (ADD) v += C[n * 32 + l31];
                C[n * 32 + l31] = v;
            }
        }
    }
}

// =====================================================================
// Staged-weight MFMA GEMM (f32 A, split in-kernel into hi+lo bf16).
// =====================================================================
template<int NS, int KCH, bool OUT_BF16>
__global__ __launch_bounds__(256, 2) void sgemm_f32(
    const int* __restrict__ flag, int want,
    const float* __restrict__ A, int lda,
    const u16* __restrict__ WHi, const u16* __restrict__ WLo,
    int wstride, int wcstep,
    void* __restrict__ Cv, int ldc)
{
    if (want >= 0 && *flag != want) return;
    __shared__ __align__(16) u16 Wbuf[NS * 16384];
    const int tid = threadIdx.x;
    const int lane = tid & 63, wv = tid >> 6;
    const int l31 = lane & 31, lh = lane >> 5;
    const long long row0 = (long long)blockIdx.x * 128 + wv * 32;

    f32x16 acc[4];
#pragma unroll
    for (int n = 0; n < 4; n++) acc[n] = zero16();

    const float* A0 = A + (row0 + l31) * (long long)lda + lh * 8;

    stage_async<NS, 256>(Wbuf, WHi, WLo, wstride, tid);
    for (int ks = 0; ks < KCH; ks++) {
        bf16x8 ah[8], al[8];
#pragma unroll
        for (int kk = 0; kk < 8; kk++)
            splitf8(A0 + ks * 128 + kk * 16, &ah[kk], &al[kk]);
        __syncthreads();
        mfma_panel32_split<NS>(Wbuf, ah, al, l31, lh, acc);
        if (ks + 1 < KCH) {
            __syncthreads();
            stage_async<NS, 256>(Wbuf, WHi + (ks + 1) * wcstep,
                                 WLo + (ks + 1) * wcstep, wstride, tid);
        }
    }

#pragma unroll
    for (int r = 0; r < 16; r++) {
        const long long row = row0 + crow(r, lh);
        if (OUT_BF16) {
            u16* C = (u16*)Cv + row * ldc;
#pragma unroll
            for (int n = 0; n < 4; n++) C[n * 32 + l31] = f2bf(acc[n][r]);
        } else {
            float* C = (float*)Cv + row * ldc;
#pragma unroll
            for (int n = 0; n < 4; n++) C[n * 32 + l31] = acc[n][r];
        }
    }
}

// =====================================================================
// Fused QKV v3 (256 thr, 128 rows/block, 2 blocks/CU): one 64 KB panel
// buffer staged serially for Q, K, V; cross-block TLP hides the stalls.
// =====================================================================
__global__ __launch_bounds__(256, 2) void qkv_fused(
    const u16* __restrict__ h, const u16* __restrict__ wl,
    u16* __restrict__ qb, u16* __restrict__ kb, u16* __restrict__ vb)
{
    __shared__ __align__(16) u16 Wbuf[2 * 16384];
    const int tid = threadIdx.x;
    const int lane = tid & 63, wv = tid >> 6;
    const int l31 = lane & 31, lh = lane >> 5;
    const long long row0 = (long long)blockIdx.x * 128 + wv * 32;

    bf16x8 a[8];
#pragma unroll
    for (int kk = 0; kk < 8; kk++)
        a[kk] = *(const bf16x8*)(h + (row0 + l31) * 128 + kk * 16 + lh * 8);

#pragma unroll
    for (int m = 0; m < 3; m++) {
        if (m) __syncthreads();    // previous panel's reads done
        stage_async<2, 256>(Wbuf, wl + m * 32768, wl + m * 32768 + 16384, 128, tid);
        __syncthreads();           // panel staged (vmcnt drained)
        f32x16 acc[4];
#pragma unroll
        for (int n = 0; n < 4; n++) acc[n] = zero16();
        mfma_panel32<2>(Wbuf, a, l31, lh, acc);
        u16* out = (m == 0) ? qb : (m == 1) ? kb : vb;
#pragma unroll
        for (int r = 0; r < 16; r++) {
            u16* C = out + (row0 + crow(r, lh)) * CA;
#pragma unroll
            for (int n = 0; n < 4; n++) C[n * 32 + l31] = f2bf(acc[n][r]);
        }
    }
}

// =====================================================================
// Fused MLP + residual + next-layer LN1 v6 (256 thr, 128 rows/block,
// 2 blocks/CU): x += relu(h @ Wt1) @ Wt2; h_out = LN(x)*g+b (EMIT_H).
// =====================================================================
template<bool EMIT_H>
__global__ __launch_bounds__(256, 2) void mlp_ln(
    const u16* __restrict__ h,
    const u16* __restrict__ W1T, const u16* __restrict__ W2T,
    float* __restrict__ x, const float* __restrict__ g,
    const float* __restrict__ bvec, u16* __restrict__ hout)
{
    __shared__ __align__(16) u16 Wbuf[2 * 16384];
    __shared__ __align__(16) u16 Plq[4][32][40];   // per-wave 32 rows x 80 B
    const int tid = threadIdx.x;
    const int lane = tid & 63, wv = tid >> 6;
    const int l31 = lane & 31, lh = lane >> 5;
    const long long row0 = (long long)blockIdx.x * 128 + wv * 32;
    u16* pw = &Plq[wv][0][0];

    bf16x8 ah[8];
#pragma unroll
    for (int kk = 0; kk < 8; kk++)
        ah[kk] = *(const bf16x8*)(h + (row0 + l31) * 128 + kk * 16 + lh * 8);

    f32x16 xacc[4];
#pragma unroll
    for (int n = 0; n < 4; n++) xacc[n] = zero16();

    for (int c = 0; c < 4; c++) {
        // ---- W1 phase ----
        if (c) __syncthreads();          // prior chunk's W2 reads done
        stage_async<2, 256>(Wbuf, W1T + c * 16384, W1T + 65536 + c * 16384, 128, tid);
        __syncthreads();                 // W1c staged
        f32x16 hacc[4];
#pragma unroll
        for (int n = 0; n < 4; n++) hacc[n] = zero16();
        mfma_panel32<2>(Wbuf, ah, l31, lh, hacc);
        __syncthreads();                 // all waves done W1c reads

        // ---- W2 phase ----
        stage_async<2, 256>(Wbuf, W2T + c * 128, W2T + 65536 + c * 128, 512, tid);
        __syncthreads();                 // W2c staged
#pragma unroll
        for (int q = 0; q < 4; q++) {
            // prior quarter's Pl reads done before overwrite (wave-local)
            asm volatile("s_waitcnt lgkmcnt(0)" ::: "memory");
#pragma unroll
            for (int r = 0; r < 16; r++)
                pw[crow(r, lh) * 40 + l31] = f2bf(fmaxf(hacc[q][r], 0.f));
            asm volatile("s_waitcnt lgkmcnt(0)" ::: "memory");
#pragma unroll
            for (int ks2 = 0; ks2 < 2; ks2++) {
                union { uint4 v; bf16x8 b; } t;
                t.v = *(const uint4*)(pw + l31 * 40 + ks2 * 16 + lh * 8);
#pragma unroll
                for (int n = 0; n < 4; n++) {
                    const int rw = n * 32 + l31;
                    const int kb = q * 64 + ks2 * 32 + lh * 16;
                    const bf16x8 b = ld_w32(Wbuf, 0, rw, kb);
                    xacc[n] = __builtin_amdgcn_mfma_f32_32x32x16_bf16(t.b, b, xacc[n], 0, 0, 0);
                    const bf16x8 bl = ld_w32(Wbuf, 1, rw, kb);
                    xacc[n] = __builtin_amdgcn_mfma_f32_32x32x16_bf16(t.b, bl, xacc[n], 0, 0, 0);
                }
            }
        }
    }

    float gv[4], bv[4];
    if (EMIT_H) {
#pragma unroll
        for (int n = 0; n < 4; n++) { gv[n] = g[n * 32 + l31]; bv[n] = bvec[n * 32 + l31]; }
    }

#pragma unroll
    for (int r = 0; r < 16; r++) {
        const long long row = row0 + crow(r, lh);
        float* X = x + row * CA;
        float v[4]; float s = 0.f, sq = 0.f;
#pragma unroll
        for (int n = 0; n < 4; n++) {
            v[n] = X[n * 32 + l31] + xacc[n][r];
            X[n * 32 + l31] = v[n];
            s += v[n]; sq += v[n] * v[n];
        }
        if (EMIT_H) {
            s  += __shfl_xor(s, 1, 64);  s  += __shfl_xor(s, 2, 64);
            s  += __shfl_xor(s, 4, 64);  s  += __shfl_xor(s, 8, 64);
            s  += __shfl_xor(s, 16, 64);
            sq += __shfl_xor(sq, 1, 64); sq += __shfl_xor(sq, 2, 64);
            sq += __shfl_xor(sq, 4, 64); sq += __shfl_xor(sq, 8, 64);
            sq += __shfl_xor(sq, 16, 64);
            const float mean = s * 0.0078125f;
            const float var  = sq * 0.0078125f - mean * mean;
            const float inv  = rsqrtf(var + 1e-5f);
            u16* H = hout + row * CA;
#pragma unroll
            for (int n = 0; n < 4; n++)
                H[n * 32 + l31] = f2bf((v[n] - mean) * inv * gv[n] + bv[n]);
        }
    }
}

// =====================================================================
// Gather + LN1 of layer 0: one wave per atom row.
// =====================================================================
__global__ __launch_bounds__(256) void gather_ln_kernel(
    const float* __restrict__ atok, const int* __restrict__ idx,
    const float* __restrict__ g, const float* __restrict__ bvec,
    float* __restrict__ x, u16* __restrict__ h)
{
    const int lane = threadIdx.x & 63;
    const int wv   = threadIdx.x >> 6;
    const size_t an = (size_t)blockIdx.x * 4 + wv;
    const int b = (int)(an >> 14);
    const int n = (int)(an & (NATOM - 1));
    const int t = idx[b * NATOM + n];
    const float* src = atok + ((size_t)b * NTOK + t) * CA;
    const float v0 = src[lane], v1 = src[lane + 64];
    float* xr = x + an * CA;
    xr[lane] = v0; xr[lane + 64] = v1;
    float s  = v0 + v1;
    float sq = v0 * v0 + v1 * v1;
#pragma unroll
    for (int off = 32; off > 0; off >>= 1) {
        s  += __shfl_xor(s,  off, 64);
        sq += __shfl_xor(sq, off, 64);
    }
    const float mean = s * 0.0078125f;
    const float var  = sq * 0.0078125f - mean * mean;
    const float inv  = rsqrtf(var + 1e-5f);
    u16* hr = h + an * CA;
    hr[lane]      = f2bf((v0 - mean) * inv * g[lane]      + bvec[lane]);
    hr[lane + 64] = f2bf((v1 - mean) * inv * g[lane + 64] + bvec[lane + 64]);
}

// =====================================================================
// Bias: t[b,a,h] for a < 128 from the pair-MLP (f32 aux weights).
// =====================================================================
__global__ __launch_bounds__(512) void bias_kernel(
    const float* __restrict__ x, const float* __restrict__ AX,
    float* __restrict__ tb)
{
    __shared__ float Wsum[128][16];
    __shared__ float M1[16][16];
    __shared__ float M2[16][16];
    __shared__ float Pb[16][4];
    const int tid = threadIdx.x;
    for (int i = tid; i < 128 * 16; i += 512)
        Wsum[i >> 4][i & 15] = AX[AX_WCL + i] + AX[AX_WCM + i];
    if (tid < 256) M1[tid >> 4][tid & 15] = AX[AX_WM1 + tid];
    if (tid >= 256 && tid < 512) { int t2 = tid - 256; M2[t2 >> 4][t2 & 15] = AX[AX_WM2 + t2]; }
    if (tid < 64) Pb[tid >> 2][tid & 3] = AX[AX_WPB + tid];
    __syncthreads();

    const int b = tid >> 7, a = tid & 127;
    const float* xa = x + ((size_t)b * NATOM + a) * CA;
    float u[16];
#pragma unroll
    for (int p = 0; p < 16; p++) u[p] = 0.f;
    for (int c = 0; c < 128; c++) {
        const float xv = xa[c];
#pragma unroll
        for (int p = 0; p < 16; p++) u[p] = fmaf(xv, Wsum[c][p], u[p]);
    }
    float r1[16];
#pragma unroll
    for (int p = 0; p < 16; p++) r1[p] = 0.f;
    for (int c = 0; c < 16; c++) {
        const float rv = fmaxf(u[c], 0.f);
#pragma unroll
        for (int p = 0; p < 16; p++) r1[p] = fmaf(rv, M1[c][p], r1[p]);
    }
    float r2[16];
#pragma unroll
    for (int p = 0; p < 16; p++) r2[p] = 0.f;
    for (int c = 0; c < 16; c++) {
        const float rv = fmaxf(r1[c], 0.f);
#pragma unroll
        for (int p = 0; p < 16; p++) r2[p] = fmaf(rv, M2[c][p], r2[p]);
    }
#pragma unroll
    for (int hh = 0; hh < 4; hh++) {
        float s = 0.f;
#pragma unroll
        for (int p = 0; p < 16; p++) s = fmaf(r2[p], Pb[p][hh], s);
        tb[(size_t)tid * 4 + hh] = s;
    }
}

// =====================================================================
// Windowed attention + O-projection + residual + LN2, fused.
// One block per (b, w); wave = head for attention; for the O-proj each
// wave computes output cols h*32..+31 with A-frags from the shared Ol
// tile and B-frags (Wo hi+lo) direct from L2 (shared by all blocks).
// LN2 reduce: per-wave shfl over its 32-col slice + LDS partials.
// =====================================================================
#define VTP 132   // V^T row stride in u16
#define PPS 68    // P row stride in u16

__global__ __launch_bounds__(256) void attn_oln(
    const u16* __restrict__ qg, const u16* __restrict__ kg,
    const u16* __restrict__ vg, const float* __restrict__ tb,
    const u16* __restrict__ WoHi,            // [128][128] hi; lo at +16384
    float* __restrict__ x, const float* __restrict__ g,
    const float* __restrict__ bvec, u16* __restrict__ hout)
{
    __shared__ __align__(16) u16 VT[128][VTP];    // V^T: [d][j]
    __shared__ __align__(16) u16 Pl[NH][32][PPS]; // per-head P half
    __shared__ __align__(16) u16 Ol[32][VTP];     // O rows (bf16), full 128 cols
    __shared__ float part[32][NH][2];             // LN partial sums per wave

    const int tid  = threadIdx.x;
    const int lane = tid & 63;
    const int h    = tid >> 6;             // wave id == head
    const int b    = blockIdx.x >> 9;
    const int w    = blockIdx.x & (NWIN - 1);
    const int row0 = w * NQ;
    const int kbase = row0 - PAD;          // first key atom (may be < 0)
    const int l15 = lane & 15;
    const int lg  = lane >> 4;

    // ---- stage V^T into LDS (all 256 threads; zero invalid rows) ----
    {
        const int j  = tid & 127;
        const int d0 = (tid >> 7) << 6;    // 0 or 64
        const int ga = kbase + j;
        const bool val = (ga >= 0) && (ga < NATOM);
        const u16* vrow = vg + ((long long)b * NATOM + ga) * CA + d0;
#pragma unroll
        for (int t2 = 0; t2 < 8; t2++) {
            union { uint4 q; u16 s[8]; } u;
            if (val) u.q = *(const uint4*)(vrow + t2 * 8);
            else     u.q = make_uint4(0u, 0u, 0u, 0u);
#pragma unroll
            for (int e = 0; e < 8; e++) VT[d0 + t2 * 8 + e][j] = u.s[e];
        }
    }

    // ---- QK^T: S[32][128] per head, frags direct from global ----
    const long long qoff = ((long long)b * NATOM + row0) * CA + h * DH;
    const long long koff = ((long long)b * NATOM + kbase) * CA + h * DH;
    bf16x8 aq0 = *(const bf16x8*)(qg + qoff + (long long)l15 * CA + lg * 8);
    bf16x8 aq1 = *(const bf16x8*)(qg + qoff + (long long)(l15 + 16) * CA + lg * 8);

    f32x4 acc[2][8];
    {
        f32x4 z = {0.f, 0.f, 0.f, 0.f};
#pragma unroll
        for (int m = 0; m < 2; m++)
#pragma unroll
            for (int n = 0; n < 8; n++) acc[m][n] = z;
    }
#pragma unroll
    for (int n = 0; n < 8; n++) {
        bf16x8 bk = *(const bf16x8*)(kg + koff + (long long)(n * 16 + l15) * CA + lg * 8);
        acc[0][n] = __builtin_amdgcn_mfma_f32_16x16x32_bf16(aq0, bk, acc[0][n], 0, 0, 0);
        acc[1][n] = __builtin_amdgcn_mfma_f32_16x16x32_bf16(aq1, bk, acc[1][n], 0, 0, 0);
    }

    // ---- bias + scale + mask ----
    const float scale = 0.17677669529663687f;  // 1/sqrt(32)
    float tj[8], ti[2][4];
#pragma unroll
    for (int n = 0; n < 8; n++)
        tj[n] = tb[((size_t)b * 128 + n * 16 + l15) * 4 + h];
#pragma unroll
    for (int m = 0; m < 2; m++)
#pragma unroll
        for (int r = 0; r < 4; r++)
            ti[m][r] = tb[((size_t)b * 128 + m * 16 + lg * 4 + r) * 4 + h];

#pragma unroll
    for (int n = 0; n < 8; n++) {
        const int ga = kbase + n * 16 + l15;
        const bool val = (ga >= 0) && (ga < NATOM);
#pragma unroll
        for (int m = 0; m < 2; m++)
#pragma unroll
            for (int r = 0; r < 4; r++) {
                const float s = acc[m][n][r] * scale + ti[m][r] + tj[n];
                acc[m][n][r] = val ? s : -1e9f;
            }
    }

    // ---- softmax ----
    float mx[2][4], inv[2][4];
#pragma unroll
    for (int m = 0; m < 2; m++)
#pragma unroll
        for (int r = 0; r < 4; r++) {
            float v = acc[m][0][r];
#pragma unroll
            for (int n = 1; n < 8; n++) v = fmaxf(v, acc[m][n][r]);
            v = fmaxf(v, __shfl_xor(v, 1, 64));
            v = fmaxf(v, __shfl_xor(v, 2, 64));
            v = fmaxf(v, __shfl_xor(v, 4, 64));
            v = fmaxf(v, __shfl_xor(v, 8, 64));
            mx[m][r] = v;
        }
#pragma unroll
    for (int m = 0; m < 2; m++)
#pragma unroll
        for (int n = 0; n < 8; n++)
#pragma unroll
            for (int r = 0; r < 4; r++)
                acc[m][n][r] = __expf(acc[m][n][r] - mx[m][r]);
#pragma unroll
    for (int m = 0; m < 2; m++)
#pragma unroll
        for (int r = 0; r < 4; r++) {
            float v = 0.f;
#pragma unroll
            for (int n = 0; n < 8; n++) v += acc[m][n][r];
            v += __shfl_xor(v, 1, 64);
            v += __shfl_xor(v, 2, 64);
            v += __shfl_xor(v, 4, 64);
            v += __shfl_xor(v, 8, 64);
            inv[m][r] = 1.0f / v;
        }

    __syncthreads();   // V^T staged

    // ---- PV ----
    f32x4 o[2][2];
    {
        f32x4 z = {0.f, 0.f, 0.f, 0.f};
        o[0][0] = z; o[0][1] = z; o[1][0] = z; o[1][1] = z;
    }
    union B8 { bf16x8 v; uint2 u[2]; };
#pragma unroll
    for (int half = 0; half < 2; half++) {
        asm volatile("s_waitcnt lgkmcnt(0)" ::: "memory");
#pragma unroll
        for (int m = 0; m < 2; m++)
#pragma unroll
            for (int nn = 0; nn < 4; nn++)
#pragma unroll
                for (int r = 0; r < 4; r++)
                    Pl[h][m * 16 + lg * 4 + r][nn * 16 + l15]
                        = f2bf(acc[m][half * 4 + nn][r]);
        asm volatile("s_waitcnt lgkmcnt(0)" ::: "memory");
#pragma unroll
        for (int ks2 = 0; ks2 < 2; ks2++) {
            const int jo = ks2 * 32 + lg * 8;
            const int jg = half * 64 + jo;
            B8 pa0, pa1, vb0, vb1;
            pa0.u[0] = *(const uint2*)&Pl[h][l15][jo];
            pa0.u[1] = *(const uint2*)&Pl[h][l15][jo + 4];
            pa1.u[0] = *(const uint2*)&Pl[h][l15 + 16][jo];
            pa1.u[1] = *(const uint2*)&Pl[h][l15 + 16][jo + 4];
            vb0.u[0] = *(const uint2*)&VT[h * DH + l15][jg];
            vb0.u[1] = *(const uint2*)&VT[h * DH + l15][jg + 4];
            vb1.u[0] = *(const uint2*)&VT[h * DH + 16 + l15][jg];
            vb1.u[1] = *(const uint2*)&VT[h * DH + 16 + l15][jg + 4];
            o[0][0] = __builtin_amdgcn_mfma_f32_16x16x32_bf16(pa0.v, vb0.v, o[0][0], 0, 0, 0);
            o[0][1] = __builtin_amdgcn_mfma_f32_16x16x32_bf16(pa0.v, vb1.v, o[0][1], 0, 0, 0);
            o[1][0] = __builtin_amdgcn_mfma_f32_16x16x32_bf16(pa1.v, vb0.v, o[1][0], 0, 0, 0);
            o[1][1] = __builtin_amdgcn_mfma_f32_16x16x32_bf16(pa1.v, vb1.v, o[1][1], 0, 0, 0);
        }
    }

    // ---- write normalized O (bf16) to Ol; cols h*DH..+31 per wave ----
#pragma unroll
    for (int m = 0; m < 2; m++)
#pragma unroll
        for (int n = 0; n < 2; n++)
#pragma unroll
            for (int r = 0; r < 4; r++)
                Ol[m * 16 + lg * 4 + r][h * DH + n * 16 + l15]
                    = f2bf(o[m][n][r] * inv[m][r]);
    __syncthreads();   // Ol complete (all waves)

    // ---- O-projection: wave h computes output cols h*32..+31 ----
    bf16x8 oa[2][4];
#pragma unroll
    for (int m = 0; m < 2; m++)
#pragma unroll
        for (int kk = 0; kk < 4; kk++) {
            union { uint2 u[2]; bf16x8 v; } t;
            t.u[0] = *(const uint2*)&Ol[m * 16 + l15][kk * 32 + lg * 8];
            t.u[1] = *(const uint2*)&Ol[m * 16 + l15][kk * 32 + lg * 8 + 4];
            oa[m][kk] = t.v;
        }
    f32x4 oacc[2][2];
    {
        f32x4 z = {0.f, 0.f, 0.f, 0.f};
        oacc[0][0] = z; oacc[0][1] = z; oacc[1][0] = z; oacc[1][1] = z;
    }
#pragma unroll
    for (int kk = 0; kk < 4; kk++)
#pragma unroll
        for (int n = 0; n < 2; n++) {
            const u16* wp = WoHi + (h * 32 + n * 16 + l15) * 128 + kk * 32 + lg * 8;
            const bf16x8 bw = *(const bf16x8*)wp;
            oacc[0][n] = __builtin_amdgcn_mfma_f32_16x16x32_bf16(oa[0][kk], bw, oacc[0][n], 0, 0, 0);
            oacc[1][n] = __builtin_amdgcn_mfma_f32_16x16x32_bf16(oa[1][kk], bw, oacc[1][n], 0, 0, 0);
            const bf16x8 bl = *(const bf16x8*)(wp + 16384);
            oacc[0][n] = __builtin_amdgcn_mfma_f32_16x16x32_bf16(oa[0][kk], bl, oacc[0][n], 0, 0, 0);
            oacc[1][n] = __builtin_amdgcn_mfma_f32_16x16x32_bf16(oa[1][kk], bl, oacc[1][n], 0, 0, 0);
        }

    // ---- residual into x + LN2 partials (wave covers cols h*32..+31) ----
    float vv[2][4][2];
#pragma unroll
    for (int m = 0; m < 2; m++)
#pragma unroll
        for (int r = 0; r < 4; r++) {
            const int rl = m * 16 + lg * 4 + r;
            float* X = x + ((long long)b * NATOM + row0 + rl) * CA;
            float s = 0.f, sq = 0.f;
#pragma unroll
            for (int n = 0; n < 2; n++) {
                const float v = X[h * 32 + n * 16 + l15] + oacc[m][n][r];
                X[h * 32 + n * 16 + l15] = v;
                vv[m][r][n] = v;
                s += v; sq += v * v;
            }
            s  += __shfl_xor(s, 1, 64);  s  += __shfl_xor(s, 2, 64);
            s  += __shfl_xor(s, 4, 64);  s  += __shfl_xor(s, 8, 64);
            sq += __shfl_xor(sq, 1, 64); sq += __shfl_xor(sq, 2, 64);
            sq += __shfl_xor(sq, 4, 64); sq += __shfl_xor(sq, 8, 64);
            if (l15 == 0) { part[rl][h][0] = s; part[rl][h][1] = sq; }
        }
    __syncthreads();   // partials complete

    float gv[2], bvv[2];
#pragma unroll
    for (int n = 0; n < 2; n++) {
        gv[n]  = g[h * 32 + n * 16 + l15];
        bvv[n] = bvec[h * 32 + n * 16 + l15];
    }
#pragma unroll
    for (int m = 0; m < 2; m++)
#pragma unroll
        for (int r = 0; r < 4; r++) {
            const int rl = m * 16 + lg * 4 + r;
            const float s  = part[rl][0][0] + part[rl][1][0] + part[rl][2][0] + part[rl][3][0];
            const float sq = part[rl][0][1] + part[rl][1][1] + part[rl][2][1] + part[rl][3][1];
            const float mean = s * 0.0078125f;
            const float var  = sq * 0.0078125f - mean * mean;
            const float inv2 = rsqrtf(var + 1e-5f);
            u16* H = hout + ((long long)b * NATOM + row0 + rl) * CA;
#pragma unroll
            for (int n = 0; n < 2; n++)
                H[h * 32 + n * 16 + l15]
                    = f2bf((vv[m][r][n] - mean) * inv2 * gv[n] + bvv[n]);
        }
}

// =====================================================================
// Final selector: write d_out as bf16 (flag=1) or f32 (flag=0)
// =====================================================================
__global__ __launch_bounds__(256) void select_kernel(
    const int* __restrict__ flag, const u16* __restrict__ outb,
    void* __restrict__ d_out)
{
    const size_t i = (size_t)blockIdx.x * 256 + threadIdx.x;
    if (*flag) ((u16*)d_out)[i]   = outb[i];
    else       ((float*)d_out)[i] = bf2f(outb[i]);
}

// =====================================================================
// Launch — single dtype-independent pipeline; only wtrans + token
// projection are flag-gated pairs.
// =====================================================================
extern "C" void kernel_launch(void* const* d_in, const int* in_sizes, int n_in,
                              void* d_out, int out_size, void* d_ws, size_t ws_size,
                              hipStream_t stream)
{
    (void)in_sizes; (void)n_in; (void)out_size;
    const size_t NEL = (size_t)BB * NATOM * CA;   // 8388608

    char* p = (char*)d_ws;
    float* x    = (float*)p;  p += NEL * 4;
    u16*   h    = (u16*)p;    p += NEL * 2;
    u16*   qb   = (u16*)p;    p += NEL * 2;
    u16*   kb   = (u16*)p;    p += NEL * 2;
    u16*   vb   = (u16*)p;    p += NEL * 2;
    float* atok = (float*)p;  p += (size_t)BB * NTOK * CA * 4;
    float* tbv  = (float*)p;  p += 8192;
    u16*   outb = (u16*)p;    p += NEL * 2;
    int*   flag = (int*)p;    p += 256;
    u16*   wt   = (u16*)p;    p += (size_t)WT_TOT * 2;
    float* aux  = (float*)p;  p += AX_TOT * 4;
    if ((size_t)(p - (char*)d_ws) > ws_size) return;  // workspace too small

    // 1) detect input storage dtype (writes flag: 1=bf16, 0=f32)
    detect_kernel<<<1, 256, 0, stream>>>((const u32*)d_in[3], flag);

    // 2) weight preprocessing (gated pair; exactly one runs)
    wtrans_kernel<u16><<<41, 256, 0, stream>>>(
        flag, 1, (const u16*)d_in[3], (const u16*)d_in[10], (const u16*)d_in[11],
        (const u16*)d_in[12], (const u16*)d_in[13], (const u16*)d_in[16],
        (const u16*)d_in[17], (const u16*)d_in[4], (const u16*)d_in[5],
        (const u16*)d_in[6], (const u16*)d_in[7], (const u16*)d_in[8],
        (const u16*)d_in[9], (const u16*)d_in[14], (const u16*)d_in[15],
        (const u16*)d_in[18], (const u16*)d_in[19], wt, aux);
    wtrans_kernel<float><<<41, 256, 0, stream>>>(
        flag, 0, (const float*)d_in[3], (const float*)d_in[10], (const float*)d_in[11],
        (const float*)d_in[12], (const float*)d_in[13], (const float*)d_in[16],
        (const float*)d_in[17], (const float*)d_in[4], (const float*)d_in[5],
        (const float*)d_in[6], (const float*)d_in[7], (const float*)d_in[8],
        (const float*)d_in[9], (const float*)d_in[14], (const float*)d_in[15],
        (const float*)d_in[18], (const float*)d_in[19], wt, aux);

    // 3) token projection (gated pair)
    sgemm_bf<1, 3, false, false><<<BB * NTOK / 128, 256, 0, stream>>>(
        flag, 1, (const u16*)d_in[0], CTOK, wt + WT_WA, wt + WT_WA + 49152,
        CTOK, 128, atok, CA);
    sgemm_f32<2, 3, false><<<BB * NTOK / 128, 256, 0, stream>>>(
        flag, 0, (const float*)d_in[0], CTOK, wt + WT_WA, wt + WT_WA + 49152,
        CTOK, 128, atok, CA);

    // 4) gather + layer-0 LN1
    gather_ln_kernel<<<BB * NATOM / 4, 256, 0, stream>>>(
        atok, (const int*)d_in[2], aux + AX_L1G, aux + AX_L1B, x, h);
    bias_kernel<<<1, 512, 0, stream>>>(x, aux, tbv);

    // 5) layers
    for (int l = 0; l < 3; l++) {
        u16* wl = wt + WT_L0 + (size_t)l * WT_LSZ;
        qkv_fused<<<512, 256, 0, stream>>>(h, wl, qb, kb, vb);
        attn_oln<<<BB * NWIN, 256, 0, stream>>>(
            qb, kb, vb, tbv, wl + 98304, x,
            aux + AX_L2G + l * 128, aux + AX_L2B + l * 128, h);
        if (l < 2)
            mlp_ln<true><<<512, 256, 0, stream>>>(
                h, wl + 131072, wl + 262144, x,
                aux + AX_L1G + (l + 1) * 128, aux + AX_L1B + (l + 1) * 128, h);
        else
            mlp_ln<false><<<512, 256, 0, stream>>>(
                h, wl + 131072, wl + 262144, x, aux, aux, h);
    }

    // 6) out = x @ W_out -> bf16 outb (always runs)
    sgemm_f32<2, 1, true><<<512, 256, 0, stream>>>(
        flag, -1, x, CA, wt + WT_WO, wt + WT_WO + 16384, CA, 0, outb, CA);

    // 7) write d_out in the detected output format
    select_kernel<<<(unsigned)(NEL / 256), 256, 0, stream>>>(flag, outb, d_out);
}

// Round 12
// 558.217 us; speedup vs baseline: 1.0890x; 1.0890x over previous
//
#include <hip/hip_runtime.h>

typedef unsigned short u16;
typedef unsigned int   u32;

typedef __attribute__((ext_vector_type(8))) __bf16 bf16x8;
typedef __attribute__((ext_vector_type(4))) float  f32x4;

// ---------- scalar/vec conversion helpers ----------
__device__ __forceinline__ float bf2f(u16 v) {
    return __uint_as_float(((u32)v) << 16);
}
__device__ __forceinline__ u16 f2bf(float f) {
    u32 u = __float_as_uint(f);
    u32 r = (u + 0x7fffu + ((u >> 16) & 1u)) >> 16;  // round-to-nearest-even
    return (u16)r;
}
__device__ __forceinline__ float ld1(const u16* p)   { return bf2f(*p); }
__device__ __forceinline__ float ld1(const float* p) { return *p; }

// ---------- problem constants ----------
#define BB 4
#define NTOK 2048
#define NATOM 16384
#define CTOK 384
#define CA 128
#define NQ 32
#define NK 128
#define NH 4
#define DH 32
#define NWIN 512
#define PAD 48

// Transposed-weight workspace layout (u16 elements).
// Each matrix stored as [N][K] hi-plane, then lo-plane (lo = 0 for bf16 input).
#define WT_WA   0          // [128][384], lo plane at +49152
#define WT_L0   98304      // per-layer block start
#define WT_LSZ  393216     // Q 0 | K 32768 | V 65536 | O 98304 | T1 131072 | T2 262144
#define WT_WO   1277952    // [128][128], lo plane at +16384
#define WT_TOT  1310720

// Aux f32 scratch layout (floats)
#define AX_WCL  0
#define AX_WCM  2048
#define AX_WM1  4096
#define AX_WM2  4352
#define AX_WPB  4608
#define AX_L1G  4672
#define AX_L1B  5056
#define AX_L2G  5440
#define AX_L2B  5824
#define AX_TOT  6208

// =====================================================================
// dtype detector: look at low u16 of 1024 words of W_a.
// flag = 1 (bf16 inputs) or 0 (f32 inputs)
// =====================================================================
__global__ __launch_bounds__(256) void detect_kernel(const u32* __restrict__ wa,
                                                     int* __restrict__ flag)
{
    __shared__ int cnt;
    if (threadIdx.x == 0) cnt = 0;
    __syncthreads();
    int local = 0;
#pragma unroll
    for (int i = 0; i < 4; i++) {
        u32 w = wa[threadIdx.x * 4 + i];
        u32 e = (w >> 7) & 0xFFu;   // exponent field of the LOW u16 as bf16
        if (e >= 95u && e <= 135u) local++;
    }
    atomicAdd(&cnt, local);
    __syncthreads();
    if (threadIdx.x == 0) *flag = (cnt >= 614) ? 1 : 0;
}

// =====================================================================
// Weight transpose + bf16 hi/lo split into WT workspace, plus f32 aux
// conversion.  41 blocks; gated on dtype flag.
// =====================================================================
template<typename TIN>
__global__ __launch_bounds__(256) void wtrans_kernel(
    const int* __restrict__ flag, int want,
    const TIN* __restrict__ Wa, const TIN* __restrict__ Wq,
    const TIN* __restrict__ Wk, const TIN* __restrict__ Wv,
    const TIN* __restrict__ Wo, const TIN* __restrict__ Wt1,
    const TIN* __restrict__ Wt2, const TIN* __restrict__ Wout,
    const TIN* __restrict__ Wcl, const TIN* __restrict__ Wcm,
    const TIN* __restrict__ Wm1, const TIN* __restrict__ Wm2,
    const TIN* __restrict__ Wpb, const TIN* __restrict__ l1g,
    const TIN* __restrict__ l1b, const TIN* __restrict__ l2g,
    const TIN* __restrict__ l2b,
    u16* __restrict__ WT, float* __restrict__ AX)
{
    if (*flag != want) return;
    const int t = blockIdx.x;
    const int tid = threadIdx.x;
    if (t == 40) {   // aux f32 conversion
        for (int i = tid; i < 2048; i += 256) AX[AX_WCL + i] = ld1(Wcl + i);
        for (int i = tid; i < 2048; i += 256) AX[AX_WCM + i] = ld1(Wcm + i);
        AX[AX_WM1 + tid] = ld1(Wm1 + tid);
        AX[AX_WM2 + tid] = ld1(Wm2 + tid);
        if (tid < 64) AX[AX_WPB + tid] = ld1(Wpb + tid);
        for (int i = tid; i < 384; i += 256) {
            AX[AX_L1G + i] = ld1(l1g + i);
            AX[AX_L1B + i] = ld1(l1b + i);
            AX[AX_L2G + i] = ld1(l2g + i);
            AX[AX_L2B + i] = ld1(l2b + i);
        }
        return;
    }
    const TIN* S; int sld; u16* D; int dld; int plane;
    if (t < 3) {                                     // W_a [384][128]
        S = Wa + t * 128 * 128; sld = 128;
        D = WT + WT_WA + t * 128; dld = 384; plane = 49152;
    } else if (t < 15) {                             // Wq/k/v/o [128][128]
        const int i = t - 3, l = i >> 2, m = i & 3;
        const TIN* ms = (m == 0) ? Wq : (m == 1) ? Wk : (m == 2) ? Wv : Wo;
        S = ms + l * 16384; sld = 128;
        D = WT + WT_L0 + l * WT_LSZ + m * 32768; dld = 128; plane = 16384;
    } else if (t < 27) {                             // Wt1 [128][512] col-chunk c
        const int i = t - 15, l = i >> 2, c = i & 3;
        S = Wt1 + l * 65536 + c * 128; sld = 512;
        D = WT + WT_L0 + l * WT_LSZ + 131072 + c * 128 * 128; dld = 128; plane = 65536;
    } else if (t < 39) {                             // Wt2 [512][128] row-chunk c
        const int i = t - 27, l = i >> 2, c = i & 3;
        S = Wt2 + l * 65536 + c * 128 * 128; sld = 128;
        D = WT + WT_L0 + l * WT_LSZ + 262144 + c * 128; dld = 512; plane = 65536;
    } else {                                         // W_out [128][128]
        S = Wout; sld = 128;
        D = WT + WT_WO; dld = 128; plane = 16384;
    }
    for (int id = tid; id < 2048; id += 256) {
        const int n = id >> 4, k0 = (id & 15) << 3;
        union { u16 s[8]; uint4 v; } hi, lo;
#pragma unroll
        for (int j = 0; j < 8; j++) {
            if constexpr (sizeof(TIN) == 2) {
                hi.s[j] = ((const u16*)(const void*)S)[(k0 + j) * sld + n];
                lo.s[j] = 0;
            } else {
                const float v = ((const float*)(const void*)S)[(k0 + j) * sld + n];
                const u16 hv = f2bf(v);
                hi.s[j] = hv;
                lo.s[j] = f2bf(v - bf2f(hv));
            }
        }
        *(uint4*)(D + n * dld + k0) = hi.v;
        *(uint4*)(D + plane + n * dld + k0) = lo.v;
    }
}

// =====================================================================
// Async weight-panel staging via global_load_lds (no staging VGPRs).
// LDS image: [plane][128 rows][256 B] LINEAR in segment order; the XOR
// swizzle byte^((row&7)<<4) is applied to the per-lane GLOBAL source
// (inverse-swz source + swz read = both-sides rule).
// =====================================================================
__device__ __forceinline__ void gld16(const void* g, void* l)
{
    __builtin_amdgcn_global_load_lds(
        (const __attribute__((address_space(1))) void*)g,
        (__attribute__((address_space(3))) void*)l, 16, 0, 0);
}

template<int NS, int NTHR>
__device__ __forceinline__ void stage_async(u16* lds, const u16* srcHi,
                                            const u16* srcLo, int strideU16, int tid)
{
    constexpr int NWAVE = NTHR / 64;
    constexpr int NSEG  = NS * 32768 / (NWAVE * 1024);
    const int lane = tid & 63;
    const int wv   = tid >> 6;
#pragma unroll
    for (int i = 0; i < NSEG; i++) {
        const int segoff  = (wv * NSEG + i) << 10;      // byte, wave-uniform
        const int po_full = segoff + lane * 16;
        const int plane   = po_full >> 15;
        const int po      = po_full & 32767;
        const int row     = po >> 8;
        const int colB    = (po & 255) ^ ((row & 7) << 4);
        const u16* g = (plane ? srcLo : srcHi) + row * strideU16 + (colB >> 1);
        gld16(g, (char*)lds + segoff);
    }
}

__device__ __forceinline__ bf16x8 ld_w(const u16* lds, int plane, int row, int kbyte)
{
    union { uint4 q; bf16x8 v; } u;
    u.q = *(const uint4*)((const char*)lds + plane * 32768 + row * 256
                          + (kbyte ^ ((row & 7) << 4)));
    return u.v;
}

// MFMA over one staged panel: acc[2][8] += a{0,1}[kk] @ W(+lo)
template<int NS>
__device__ __forceinline__ void mfma_panel(const u16* Wbuf, const bf16x8* a0,
                                           const bf16x8* a1, int l15, int lg,
                                           f32x4 acc[][8])
{
#pragma unroll
    for (int kk = 0; kk < 4; kk++)
#pragma unroll
        for (int n = 0; n < 8; n++) {
            const int rw = n * 16 + l15, kb = kk * 64 + lg * 16;
            const bf16x8 b = ld_w(Wbuf, 0, rw, kb);
            acc[0][n] = __builtin_amdgcn_mfma_f32_16x16x32_bf16(a0[kk], b, acc[0][n], 0, 0, 0);
            acc[1][n] = __builtin_amdgcn_mfma_f32_16x16x32_bf16(a1[kk], b, acc[1][n], 0, 0, 0);
            if (NS == 2) {
                const bf16x8 bl = ld_w(Wbuf, 1, rw, kb);
                acc[0][n] = __builtin_amdgcn_mfma_f32_16x16x32_bf16(a0[kk], bl, acc[0][n], 0, 0, 0);
                acc[1][n] = __builtin_amdgcn_mfma_f32_16x16x32_bf16(a1[kk], bl, acc[1][n], 0, 0, 0);
            }
        }
}

// Split-A variant: acc += ah@W + al@W (+ ah@Wlo when NS==2)
template<int NS>
__device__ __forceinline__ void mfma_panel_split(const u16* Wbuf,
    const bf16x8* a0h, const bf16x8* a0l, const bf16x8* a1h, const bf16x8* a1l,
    int l15, int lg, f32x4 acc[][8])
{
#pragma unroll
    for (int kk = 0; kk < 4; kk++)
#pragma unroll
        for (int n = 0; n < 8; n++) {
            const int rw = n * 16 + l15, kb = kk * 64 + lg * 16;
            const bf16x8 b = ld_w(Wbuf, 0, rw, kb);
            acc[0][n] = __builtin_amdgcn_mfma_f32_16x16x32_bf16(a0h[kk], b, acc[0][n], 0, 0, 0);
            acc[0][n] = __builtin_amdgcn_mfma_f32_16x16x32_bf16(a0l[kk], b, acc[0][n], 0, 0, 0);
            acc[1][n] = __builtin_amdgcn_mfma_f32_16x16x32_bf16(a1h[kk], b, acc[1][n], 0, 0, 0);
            acc[1][n] = __builtin_amdgcn_mfma_f32_16x16x32_bf16(a1l[kk], b, acc[1][n], 0, 0, 0);
            if (NS == 2) {
                const bf16x8 bl = ld_w(Wbuf, 1, rw, kb);
                acc[0][n] = __builtin_amdgcn_mfma_f32_16x16x32_bf16(a0h[kk], bl, acc[0][n], 0, 0, 0);
                acc[1][n] = __builtin_amdgcn_mfma_f32_16x16x32_bf16(a1h[kk], bl, acc[1][n], 0, 0, 0);
            }
        }
}

__device__ __forceinline__ void splitf8(const float* p, bf16x8* hi, bf16x8* lo)
{
    const float4 f0 = *(const float4*)p;
    const float4 f1 = *(const float4*)(p + 4);
    const float f[8] = {f0.x, f0.y, f0.z, f0.w, f1.x, f1.y, f1.z, f1.w};
    union { u16 s[8]; bf16x8 v; } H, L;
#pragma unroll
    for (int j = 0; j < 8; j++) {
        const u16 hv = f2bf(f[j]);
        H.s[j] = hv;
        L.s[j] = f2bf(f[j] - bf2f(hv));
    }
    *hi = H.v; *lo = L.v;
}

// =====================================================================
// Staged-weight MFMA GEMM (bf16 A): C[M x 128] = A[M x K] @ W.
// 128-row blocks, 256 threads, 4 waves x 32 rows, 2 blocks/CU.
// want < 0: always run; else gated on dtype flag.
// =====================================================================
template<int NS, int KCH, bool OUT_BF16, bool ADD>
__global__ __launch_bounds__(256, 2) void sgemm_bf(
    const int* __restrict__ flag, int want,
    const u16* __restrict__ A, int lda,
    const u16* __restrict__ WHi, const u16* __restrict__ WLo,
    int wstride, int wcstep,
    void* __restrict__ Cv, int ldc)
{
    if (want >= 0 && *flag != want) return;
    __shared__ __align__(16) u16 Wbuf[NS * 16384];
    const int tid = threadIdx.x;
    const int lane = tid & 63, wv = tid >> 6;
    const int l15 = lane & 15, lg = lane >> 4;
    const long long row0 = (long long)blockIdx.x * 128 + wv * 32;

    f32x4 acc[2][8];
    {
        f32x4 z = {0.f, 0.f, 0.f, 0.f};
#pragma unroll
        for (int m = 0; m < 2; m++)
#pragma unroll
            for (int n = 0; n < 8; n++) acc[m][n] = z;
    }

    const u16* A0 = A + (row0 + l15) * (long long)lda + lg * 8;
    const u16* A1 = A0 + 16LL * lda;

    stage_async<NS, 256>(Wbuf, WHi, WLo, wstride, tid);
    for (int ks = 0; ks < KCH; ks++) {
        bf16x8 a0[4], a1[4];
#pragma unroll
        for (int kk = 0; kk < 4; kk++) {
            a0[kk] = *(const bf16x8*)(A0 + ks * 128 + kk * 32);
            a1[kk] = *(const bf16x8*)(A1 + ks * 128 + kk * 32);
        }
        __syncthreads();                       // panel staged (vmcnt drained)
        mfma_panel<NS>(Wbuf, a0, a1, l15, lg, acc);
        if (ks + 1 < KCH) {
            __syncthreads();                   // panel reads done before restage
            stage_async<NS, 256>(Wbuf, WHi + (ks + 1) * wcstep,
                                 WLo + (ks + 1) * wcstep, wstride, tid);
        }
    }

#pragma unroll
    for (int m = 0; m < 2; m++)
#pragma unroll
        for (int r = 0; r < 4; r++) {
            const long long row = row0 + m * 16 + lg * 4 + r;
            if (OUT_BF16) {
                u16* C = (u16*)Cv + row * ldc;
#pragma unroll
                for (int n = 0; n < 8; n++) C[n * 16 + l15] = f2bf(acc[m][n][r]);
            } else {
                float* C = (float*)Cv + row * ldc;
#pragma unroll
                for (int n = 0; n < 8; n++) {
                    float v = acc[m][n][r];
                    if (ADD) v += C[n * 16 + l15];
                    C[n * 16 + l15] = v;
                }
            }
        }
}

// =====================================================================
// Staged-weight MFMA GEMM (f32 A, split in-kernel into hi+lo bf16).
// OM: 0 = f32 store, 1 = bf16 store, 2 = d_out store by *flag
//     (bf16 if flag, else f32 = bf2f(f2bf(v)) to keep bits identical).
// =====================================================================
template<int NS, int KCH, int OM>
__global__ __launch_bounds__(256, 2) void sgemm_f32(
    const int* __restrict__ flag, int want,
    const float* __restrict__ A, int lda,
    const u16* __restrict__ WHi, const u16* __restrict__ WLo,
    int wstride, int wcstep,
    void* __restrict__ Cv, int ldc)
{
    if (want >= 0 && *flag != want) return;
    __shared__ __align__(16) u16 Wbuf[NS * 16384];
    const int tid = threadIdx.x;
    const int lane = tid & 63, wv = tid >> 6;
    const int l15 = lane & 15, lg = lane >> 4;
    const long long row0 = (long long)blockIdx.x * 128 + wv * 32;

    f32x4 acc[2][8];
    {
        f32x4 z = {0.f, 0.f, 0.f, 0.f};
#pragma unroll
        for (int m = 0; m < 2; m++)
#pragma unroll
            for (int n = 0; n < 8; n++) acc[m][n] = z;
    }

    const float* A0 = A + (row0 + l15) * (long long)lda + lg * 8;
    const float* A1 = A0 + 16LL * lda;

    stage_async<NS, 256>(Wbuf, WHi, WLo, wstride, tid);
    for (int ks = 0; ks < KCH; ks++) {
        bf16x8 a0h[4], a0l[4], a1h[4], a1l[4];
#pragma unroll
        for (int kk = 0; kk < 4; kk++) {
            splitf8(A0 + ks * 128 + kk * 32, &a0h[kk], &a0l[kk]);
            splitf8(A1 + ks * 128 + kk * 32, &a1h[kk], &a1l[kk]);
        }
        __syncthreads();
        mfma_panel_split<NS>(Wbuf, a0h, a0l, a1h, a1l, l15, lg, acc);
        if (ks + 1 < KCH) {
            __syncthreads();
            stage_async<NS, 256>(Wbuf, WHi + (ks + 1) * wcstep,
                                 WLo + (ks + 1) * wcstep, wstride, tid);
        }
    }

    const bool asbf = (OM == 2) ? (*flag != 0) : (OM == 1);
#pragma unroll
    for (int m = 0; m < 2; m++)
#pragma unroll
        for (int r = 0; r < 4; r++) {
            const long long row = row0 + m * 16 + lg * 4 + r;
            if (OM == 0) {
                float* C = (float*)Cv + row * ldc;
#pragma unroll
                for (int n = 0; n < 8; n++) C[n * 16 + l15] = acc[m][n][r];
            } else if (asbf) {
                u16* C = (u16*)Cv + row * ldc;
#pragma unroll
                for (int n = 0; n < 8; n++) C[n * 16 + l15] = f2bf(acc[m][n][r]);
            } else {
                float* C = (float*)Cv + row * ldc;
#pragma unroll
                for (int n = 0; n < 8; n++)
                    C[n * 16 + l15] = bf2f(f2bf(acc[m][n][r]));
            }
        }
}

// =====================================================================
// O-projection + residual + fused LN2: x += ob@Wo; h = LN(x)*g+b.
// 128-row blocks, 256 threads; each wave holds full 128-wide rows, so
// LN reduce = 8 local adds + shfl_xor(1,2,4,8) over the l15 group.
// =====================================================================
__global__ __launch_bounds__(256, 2) void sgemm_add_ln(
    const u16* __restrict__ A,
    const u16* __restrict__ WHi, const u16* __restrict__ WLo,
    float* __restrict__ x, const float* __restrict__ g,
    const float* __restrict__ bvec, u16* __restrict__ h)
{
    __shared__ __align__(16) u16 Wbuf[2 * 16384];
    const int tid = threadIdx.x;
    const int lane = tid & 63, wv = tid >> 6;
    const int l15 = lane & 15, lg = lane >> 4;
    const long long row0 = (long long)blockIdx.x * 128 + wv * 32;

    f32x4 acc[2][8];
    {
        f32x4 z = {0.f, 0.f, 0.f, 0.f};
#pragma unroll
        for (int m = 0; m < 2; m++)
#pragma unroll
            for (int n = 0; n < 8; n++) acc[m][n] = z;
    }

    const u16* A0 = A + (row0 + l15) * 128LL + lg * 8;
    const u16* A1 = A0 + 16LL * 128;

    stage_async<2, 256>(Wbuf, WHi, WLo, 128, tid);
    bf16x8 a0[4], a1[4];
#pragma unroll
    for (int kk = 0; kk < 4; kk++) {
        a0[kk] = *(const bf16x8*)(A0 + kk * 32);
        a1[kk] = *(const bf16x8*)(A1 + kk * 32);
    }
    __syncthreads();
    mfma_panel<2>(Wbuf, a0, a1, l15, lg, acc);

    float gv[8], bv[8];
#pragma unroll
    for (int n = 0; n < 8; n++) { gv[n] = g[n * 16 + l15]; bv[n] = bvec[n * 16 + l15]; }

#pragma unroll
    for (int m = 0; m < 2; m++)
#pragma unroll
        for (int r = 0; r < 4; r++) {
            const long long row = row0 + m * 16 + lg * 4 + r;
            float* X = x + row * CA;
            float v[8]; float s = 0.f, sq = 0.f;
#pragma unroll
            for (int n = 0; n < 8; n++) {
                v[n] = X[n * 16 + l15] + acc[m][n][r];
                X[n * 16 + l15] = v[n];
                s += v[n]; sq += v[n] * v[n];
            }
            s  += __shfl_xor(s, 1, 64);  s  += __shfl_xor(s, 2, 64);
            s  += __shfl_xor(s, 4, 64);  s  += __shfl_xor(s, 8, 64);
            sq += __shfl_xor(sq, 1, 64); sq += __shfl_xor(sq, 2, 64);
            sq += __shfl_xor(sq, 4, 64); sq += __shfl_xor(sq, 8, 64);
            const float mean = s * 0.0078125f;
            const float var  = sq * 0.0078125f - mean * mean;
            const float inv  = rsqrtf(var + 1e-5f);
            u16* H = h + row * CA;
#pragma unroll
            for (int n = 0; n < 8; n++)
                H[n * 16 + l15] = f2bf((v[n] - mean) * inv * gv[n] + bv[n]);
        }
}

// =====================================================================
// Fused QKV (512 thr, 256 rows/block): ping-pong two panel buffers;
// next panel's async loads issue before this panel's MFMA.
// =====================================================================
__global__ __launch_bounds__(512, 1) void qkv_fused(
    const u16* __restrict__ h, const u16* __restrict__ wl,
    u16* __restrict__ qb, u16* __restrict__ kb, u16* __restrict__ vb)
{
    __shared__ __align__(16) u16 bufA[2 * 16384];
    __shared__ __align__(16) u16 bufB[2 * 16384];
    const int tid = threadIdx.x;
    const int lane = tid & 63, wv = tid >> 6;
    const int l15 = lane & 15, lg = lane >> 4;
    const long long row0 = (long long)blockIdx.x * 256 + wv * 32;

    bf16x8 a0[4], a1[4];
#pragma unroll
    for (int kk = 0; kk < 4; kk++) {
        a0[kk] = *(const bf16x8*)(h + (row0 + l15) * 128 + kk * 32 + lg * 8);
        a1[kk] = *(const bf16x8*)(h + (row0 + 16 + l15) * 128 + kk * 32 + lg * 8);
    }

    stage_async<2, 512>(bufA, wl, wl + 16384, 128, tid);          // Q
    __syncthreads();

#pragma unroll
    for (int m = 0; m < 3; m++) {
        if (m < 2)   // prefetch next panel
            stage_async<2, 512>((m == 0) ? bufB : bufA,
                                wl + (m + 1) * 32768,
                                wl + (m + 1) * 32768 + 16384, 128, tid);
        f32x4 acc[2][8];
        {
            f32x4 z = {0.f, 0.f, 0.f, 0.f};
#pragma unroll
            for (int i = 0; i < 2; i++)
#pragma unroll
                for (int n = 0; n < 8; n++) acc[i][n] = z;
        }
        const u16* cur = (m == 1) ? bufB : bufA;   // Q:A, K:B, V:A
        mfma_panel<2>(cur, a0, a1, l15, lg, acc);
        u16* out = (m == 0) ? qb : (m == 1) ? kb : vb;
#pragma unroll
        for (int i = 0; i < 2; i++)
#pragma unroll
            for (int r = 0; r < 4; r++) {
                u16* C = out + (row0 + i * 16 + lg * 4 + r) * CA;
#pragma unroll
                for (int n = 0; n < 8; n++) C[n * 16 + l15] = f2bf(acc[i][n][r]);
            }
        if (m < 2) __syncthreads();   // drains prefetch; cur reads done
    }
}

// =====================================================================
// Fused MLP + residual + next-layer LN1 (512 thr, 256 rows/block):
// x += relu(h @ Wt1) @ Wt2; h_out = LN(x)*g+b (EMIT_H).
// Two weight buffers, async staging; hidden transpose via per-wave
// 32x80B quarter buffer (wave-local waits). LDS 148 KB.
// =====================================================================
template<bool EMIT_H>
__global__ __launch_bounds__(512, 1) void mlp_ln(
    const u16* __restrict__ h,
    const u16* __restrict__ W1T, const u16* __restrict__ W2T,
    float* __restrict__ x, const float* __restrict__ g,
    const float* __restrict__ bvec, u16* __restrict__ hout)
{
    __shared__ __align__(16) u16 W1buf[2 * 16384];
    __shared__ __align__(16) u16 W2buf[2 * 16384];
    __shared__ __align__(16) u16 Plq[8][32][40];   // per-wave 32 rows x 80 B
    const int tid = threadIdx.x;
    const int lane = tid & 63, wv = tid >> 6;
    const int l15 = lane & 15, lg = lane >> 4;
    const long long row0 = (long long)blockIdx.x * 256 + wv * 32;
    u16* pw = &Plq[wv][0][0];

    bf16x8 ah0[4], ah1[4];
#pragma unroll
    for (int kk = 0; kk < 4; kk++) {
        ah0[kk] = *(const bf16x8*)(h + (row0 + l15) * 128 + kk * 32 + lg * 8);
        ah1[kk] = *(const bf16x8*)(h + (row0 + 16 + l15) * 128 + kk * 32 + lg * 8);
    }

    f32x4 xacc[2][8];
    {
        f32x4 z = {0.f, 0.f, 0.f, 0.f};
#pragma unroll
        for (int m = 0; m < 2; m++)
#pragma unroll
            for (int n = 0; n < 8; n++) xacc[m][n] = z;
    }

    stage_async<2, 512>(W1buf, W1T, W1T + 65536, 128, tid);
    __syncthreads();

    for (int c = 0; c < 4; c++) {
        // ---- W1 phase: issue W2c loads, MFMA W1 under them ----
        stage_async<2, 512>(W2buf, W2T + c * 128, W2T + 65536 + c * 128, 512, tid);
        f32x4 hacc[2][8];
        {
            f32x4 z = {0.f, 0.f, 0.f, 0.f};
#pragma unroll
            for (int m = 0; m < 2; m++)
#pragma unroll
                for (int n = 0; n < 8; n++) hacc[m][n] = z;
        }
        mfma_panel<2>(W1buf, ah0, ah1, l15, lg, hacc);
        __syncthreads();                 // W2buf staged; all waves done W1 reads

        // ---- W2 phase: issue W1(c+1) loads, quarters + MFMA W2 ----
        if (c < 3)
            stage_async<2, 512>(W1buf, W1T + (c + 1) * 16384,
                                W1T + 65536 + (c + 1) * 16384, 128, tid);
#pragma unroll
        for (int q = 0; q < 4; q++) {
            asm volatile("s_waitcnt lgkmcnt(0)" ::: "memory");
#pragma unroll
            for (int m = 0; m < 2; m++)
#pragma unroll
                for (int j = 0; j < 2; j++)
#pragma unroll
                    for (int r = 0; r < 4; r++)
                        pw[(m * 16 + lg * 4 + r) * 40 + j * 16 + l15]
                            = f2bf(fmaxf(hacc[m][2 * q + j][r], 0.f));
            asm volatile("s_waitcnt lgkmcnt(0)" ::: "memory");
            union { uint4 v; bf16x8 b; } t0, t1;
            t0.v = *(const uint4*)(pw + l15 * 40 + lg * 8);
            t1.v = *(const uint4*)(pw + (16 + l15) * 40 + lg * 8);
#pragma unroll
            for (int n = 0; n < 8; n++) {
                const int rw = n * 16 + l15, kb = q * 64 + lg * 16;
                const bf16x8 b = ld_w(W2buf, 0, rw, kb);
                xacc[0][n] = __builtin_amdgcn_mfma_f32_16x16x32_bf16(t0.b, b, xacc[0][n], 0, 0, 0);
                xacc[1][n] = __builtin_amdgcn_mfma_f32_16x16x32_bf16(t1.b, b, xacc[1][n], 0, 0, 0);
                const bf16x8 bl = ld_w(W2buf, 1, rw, kb);
                xacc[0][n] = __builtin_amdgcn_mfma_f32_16x16x32_bf16(t0.b, bl, xacc[0][n], 0, 0, 0);
                xacc[1][n] = __builtin_amdgcn_mfma_f32_16x16x32_bf16(t1.b, bl, xacc[1][n], 0, 0, 0);
            }
        }
        if (c < 3) __syncthreads();      // W1buf(c+1) staged; W2buf reads done
    }

    float gv[8], bv[8];
    if (EMIT_H) {
#pragma unroll
        for (int n = 0; n < 8; n++) { gv[n] = g[n * 16 + l15]; bv[n] = bvec[n * 16 + l15]; }
    }

#pragma unroll
    for (int m = 0; m < 2; m++)
#pragma unroll
        for (int r = 0; r < 4; r++) {
            const long long row = row0 + m * 16 + lg * 4 + r;
            float* X = x + row * CA;
            float v[8]; float s = 0.f, sq = 0.f;
#pragma unroll
            for (int n = 0; n < 8; n++) {
                v[n] = X[n * 16 + l15] + xacc[m][n][r];
                X[n * 16 + l15] = v[n];
                s += v[n]; sq += v[n] * v[n];
            }
            if (EMIT_H) {
                s  += __shfl_xor(s, 1, 64);  s  += __shfl_xor(s, 2, 64);
                s  += __shfl_xor(s, 4, 64);  s  += __shfl_xor(s, 8, 64);
                sq += __shfl_xor(sq, 1, 64); sq += __shfl_xor(sq, 2, 64);
                sq += __shfl_xor(sq, 4, 64); sq += __shfl_xor(sq, 8, 64);
                const float mean = s * 0.0078125f;
                const float var  = sq * 0.0078125f - mean * mean;
                const float inv  = rsqrtf(var + 1e-5f);
                u16* H = hout + row * CA;
#pragma unroll
                for (int n = 0; n < 8; n++)
                    H[n * 16 + l15] = f2bf((v[n] - mean) * inv * gv[n] + bv[n]);
            }
        }
}

// =====================================================================
// Gather + LN1 of layer 0: one wave per atom row.
// =====================================================================
__global__ __launch_bounds__(256) void gather_ln_kernel(
    const float* __restrict__ atok, const int* __restrict__ idx,
    const float* __restrict__ g, const float* __restrict__ bvec,
    float* __restrict__ x, u16* __restrict__ h)
{
    const int lane = threadIdx.x & 63;
    const int wv   = threadIdx.x >> 6;
    const size_t an = (size_t)blockIdx.x * 4 + wv;
    const int b = (int)(an >> 14);
    const int n = (int)(an & (NATOM - 1));
    const int t = idx[b * NATOM + n];
    const float* src = atok + ((size_t)b * NTOK + t) * CA;
    const float v0 = src[lane], v1 = src[lane + 64];
    float* xr = x + an * CA;
    xr[lane] = v0; xr[lane + 64] = v1;
    float s  = v0 + v1;
    float sq = v0 * v0 + v1 * v1;
#pragma unroll
    for (int off = 32; off > 0; off >>= 1) {
        s  += __shfl_xor(s,  off, 64);
        sq += __shfl_xor(sq, off, 64);
    }
    const float mean = s * 0.0078125f;
    const float var  = sq * 0.0078125f - mean * mean;
    const float inv  = rsqrtf(var + 1e-5f);
    u16* hr = h + an * CA;
    hr[lane]      = f2bf((v0 - mean) * inv * g[lane]      + bvec[lane]);
    hr[lane + 64] = f2bf((v1 - mean) * inv * g[lane + 64] + bvec[lane + 64]);
}

// =====================================================================
// Bias: t[b,a,h] for a < 128 from the pair-MLP (f32 aux weights).
// =====================================================================
__global__ __launch_bounds__(512) void bias_kernel(
    const float* __restrict__ x, const float* __restrict__ AX,
    float* __restrict__ tb)
{
    __shared__ float Wsum[128][16];
    __shared__ float M1[16][16];
    __shared__ float M2[16][16];
    __shared__ float Pb[16][4];
    const int tid = threadIdx.x;
    for (int i = tid; i < 128 * 16; i += 512)
        Wsum[i >> 4][i & 15] = AX[AX_WCL + i] + AX[AX_WCM + i];
    if (tid < 256) M1[tid >> 4][tid & 15] = AX[AX_WM1 + tid];
    if (tid >= 256 && tid < 512) { int t2 = tid - 256; M2[t2 >> 4][t2 & 15] = AX[AX_WM2 + t2]; }
    if (tid < 64) Pb[tid >> 2][tid & 3] = AX[AX_WPB + tid];
    __syncthreads();

    const int b = tid >> 7, a = tid & 127;
    const float* xa = x + ((size_t)b * NATOM + a) * CA;
    float u[16];
#pragma unroll
    for (int p = 0; p < 16; p++) u[p] = 0.f;
    for (int c = 0; c < 128; c++) {
        const float xv = xa[c];
#pragma unroll
        for (int p = 0; p < 16; p++) u[p] = fmaf(xv, Wsum[c][p], u[p]);
    }
    float r1[16];
#pragma unroll
    for (int p = 0; p < 16; p++) r1[p] = 0.f;
    for (int c = 0; c < 16; c++) {
        const float rv = fmaxf(u[c], 0.f);
#pragma unroll
        for (int p = 0; p < 16; p++) r1[p] = fmaf(rv, M1[c][p], r1[p]);
    }
    float r2[16];
#pragma unroll
    for (int p = 0; p < 16; p++) r2[p] = 0.f;
    for (int c = 0; c < 16; c++) {
        const float rv = fmaxf(r1[c], 0.f);
#pragma unroll
        for (int p = 0; p < 16; p++) r2[p] = fmaf(rv, M2[c][p], r2[p]);
    }
#pragma unroll
    for (int hh = 0; hh < 4; hh++) {
        float s = 0.f;
#pragma unroll
        for (int p = 0; p < 16; p++) s = fmaf(r2[p], Pb[p][hh], s);
        tb[(size_t)tid * 4 + hh] = s;
    }
}

// =====================================================================
// Windowed attention via MFMA (verified round 1): one block per (b, w).
// =====================================================================
#define VTP 132   // V^T row stride in u16
#define PPS 68    // P row stride in u16

__global__ __launch_bounds__(256) void attn_kernel(
    const u16* __restrict__ qg, const u16* __restrict__ kg,
    const u16* __restrict__ vg, const float* __restrict__ tb,
    u16* __restrict__ og)
{
    __shared__ __align__(16) u16 VT[128][VTP];    // V^T: [d][j]
    __shared__ __align__(16) u16 Pl[NH][32][PPS]; // per-head P half

    const int tid  = threadIdx.x;
    const int lane = tid & 63;
    const int h    = tid >> 6;             // wave id == head
    const int b    = blockIdx.x >> 9;
    const int w    = blockIdx.x & (NWIN - 1);
    const int row0 = w * NQ;
    const int kbase = row0 - PAD;          // first key atom (may be < 0)
    const int l15 = lane & 15;
    const int lg  = lane >> 4;

    // ---- stage V^T into LDS (all 256 threads; zero invalid rows) ----
    {
        const int j  = tid & 127;
        const int d0 = (tid >> 7) << 6;    // 0 or 64
        const int ga = kbase + j;
        const bool val = (ga >= 0) && (ga < NATOM);
        const u16* vrow = vg + ((long long)b * NATOM + ga) * CA + d0;
#pragma unroll
        for (int t2 = 0; t2 < 8; t2++) {
            union { uint4 q; u16 s[8]; } u;
            if (val) u.q = *(const uint4*)(vrow + t2 * 8);
            else     u.q = make_uint4(0u, 0u, 0u, 0u);
#pragma unroll
            for (int e = 0; e < 8; e++) VT[d0 + t2 * 8 + e][j] = u.s[e];
        }
    }

    // ---- QK^T: S[32][128] per head, frags direct from global ----
    const long long qoff = ((long long)b * NATOM + row0) * CA + h * DH;
    const long long koff = ((long long)b * NATOM + kbase) * CA + h * DH;
    bf16x8 aq0 = *(const bf16x8*)(qg + qoff + (long long)l15 * CA + lg * 8);
    bf16x8 aq1 = *(const bf16x8*)(qg + qoff + (long long)(l15 + 16) * CA + lg * 8);

    f32x4 acc[2][8];
    {
        f32x4 z = {0.f, 0.f, 0.f, 0.f};
#pragma unroll
        for (int m = 0; m < 2; m++)
#pragma unroll
            for (int n = 0; n < 8; n++) acc[m][n] = z;
    }
#pragma unroll
    for (int n = 0; n < 8; n++) {
        bf16x8 bk = *(const bf16x8*)(kg + koff + (long long)(n * 16 + l15) * CA + lg * 8);
        acc[0][n] = __builtin_amdgcn_mfma_f32_16x16x32_bf16(aq0, bk, acc[0][n], 0, 0, 0);
        acc[1][n] = __builtin_amdgcn_mfma_f32_16x16x32_bf16(aq1, bk, acc[1][n], 0, 0, 0);
    }

    // ---- bias + scale + mask ----
    const float scale = 0.17677669529663687f;  // 1/sqrt(32)
    float tj[8], ti[2][4];
#pragma unroll
    for (int n = 0; n < 8; n++)
        tj[n] = tb[((size_t)b * 128 + n * 16 + l15) * 4 + h];
#pragma unroll
    for (int m = 0; m < 2; m++)
#pragma unroll
        for (int r = 0; r < 4; r++)
            ti[m][r] = tb[((size_t)b * 128 + m * 16 + lg * 4 + r) * 4 + h];

#pragma unroll
    for (int n = 0; n < 8; n++) {
        const int ga = kbase + n * 16 + l15;
        const bool val = (ga >= 0) && (ga < NATOM);
#pragma unroll
        for (int m = 0; m < 2; m++)
#pragma unroll
            for (int r = 0; r < 4; r++) {
                const float s = acc[m][n][r] * scale + ti[m][r] + tj[n];
                acc[m][n][r] = val ? s : -1e9f;
            }
    }

    // ---- softmax ----
    float mx[2][4], inv[2][4];
#pragma unroll
    for (int m = 0; m < 2; m++)
#pragma unroll
        for (int r = 0; r < 4; r++) {
            float v = acc[m][0][r];
#pragma unroll
            for (int n = 1; n < 8; n++) v = fmaxf(v, acc[m][n][r]);
            v = fmaxf(v, __shfl_xor(v, 1, 64));
            v = fmaxf(v, __shfl_xor(v, 2, 64));
            v = fmaxf(v, __shfl_xor(v, 4, 64));
            v = fmaxf(v, __shfl_xor(v, 8, 64));
            mx[m][r] = v;
        }
#pragma unroll
    for (int m = 0; m < 2; m++)
#pragma unroll
        for (int n = 0; n < 8; n++)
#pragma unroll
            for (int r = 0; r < 4; r++)
                acc[m][n][r] = __expf(acc[m][n][r] - mx[m][r]);
#pragma unroll
    for (int m = 0; m < 2; m++)
#pragma unroll
        for (int r = 0; r < 4; r++) {
            float v = 0.f;
#pragma unroll
            for (int n = 0; n < 8; n++) v += acc[m][n][r];
            v += __shfl_xor(v, 1, 64);
            v += __shfl_xor(v, 2, 64);
            v += __shfl_xor(v, 4, 64);
            v += __shfl_xor(v, 8, 64);
            inv[m][r] = 1.0f / v;
        }

    __syncthreads();   // V^T staged

    // ---- PV ----
    f32x4 o[2][2];
    {
        f32x4 z = {0.f, 0.f, 0.f, 0.f};
        o[0][0] = z; o[0][1] = z; o[1][0] = z; o[1][1] = z;
    }
    union B8 { bf16x8 v; uint2 u[2]; };
#pragma unroll
    for (int half = 0; half < 2; half++) {
        asm volatile("s_waitcnt lgkmcnt(0)" ::: "memory");
#pragma unroll
        for (int m = 0; m < 2; m++)
#pragma unroll
            for (int nn = 0; nn < 4; nn++)
#pragma unroll
                for (int r = 0; r < 4; r++)
                    Pl[h][m * 16 + lg * 4 + r][nn * 16 + l15]
                        = f2bf(acc[m][half * 4 + nn][r]);
        asm volatile("s_waitcnt lgkmcnt(0)" ::: "memory");
#pragma unroll
        for (int ks2 = 0; ks2 < 2; ks2++) {
            const int jo = ks2 * 32 + lg * 8;
            const int jg = half * 64 + jo;
            B8 pa0, pa1, vb0, vb1;
            pa0.u[0] = *(const uint2*)&Pl[h][l15][jo];
            pa0.u[1] = *(const uint2*)&Pl[h][l15][jo + 4];
            pa1.u[0] = *(const uint2*)&Pl[h][l15 + 16][jo];
            pa1.u[1] = *(const uint2*)&Pl[h][l15 + 16][jo + 4];
            vb0.u[0] = *(const uint2*)&VT[h * DH + l15][jg];
            vb0.u[1] = *(const uint2*)&VT[h * DH + l15][jg + 4];
            vb1.u[0] = *(const uint2*)&VT[h * DH + 16 + l15][jg];
            vb1.u[1] = *(const uint2*)&VT[h * DH + 16 + l15][jg + 4];
            o[0][0] = __builtin_amdgcn_mfma_f32_16x16x32_bf16(pa0.v, vb0.v, o[0][0], 0, 0, 0);
            o[0][1] = __builtin_amdgcn_mfma_f32_16x16x32_bf16(pa0.v, vb1.v, o[0][1], 0, 0, 0);
            o[1][0] = __builtin_amdgcn_mfma_f32_16x16x32_bf16(pa1.v, vb0.v, o[1][0], 0, 0, 0);
            o[1][1] = __builtin_amdgcn_mfma_f32_16x16x32_bf16(pa1.v, vb1.v, o[1][1], 0, 0, 0);
        }
    }

#pragma unroll
    for (int m = 0; m < 2; m++)
#pragma unroll
        for (int n = 0; n < 2; n++)
#pragma unroll
            for (int r = 0; r < 4; r++)
                og[((long long)b * NATOM + row0 + m * 16 + lg * 4 + r) * CA
                   + h * DH + n * 16 + l15]
                    = f2bf(o[m][n][r] * inv[m][r]);
}

// =====================================================================
// Launch — single dtype-independent pipeline; only wtrans + token
// projection are flag-gated pairs.  Final GEMM writes d_out directly.
// =====================================================================
extern "C" void kernel_launch(void* const* d_in, const int* in_sizes, int n_in,
                              void* d_out, int out_size, void* d_ws, size_t ws_size,
                              hipStream_t stream)
{
    (void)in_sizes; (void)n_in; (void)out_size;
    const size_t NEL = (size_t)BB * NATOM * CA;   // 8388608

    char* p = (char*)d_ws;
    float* x    = (float*)p;  p += NEL * 4;
    u16*   h    = (u16*)p;    p += NEL * 2;
    u16*   qb   = (u16*)p;    p += NEL * 2;
    u16*   kb   = (u16*)p;    p += NEL * 2;
    u16*   vb   = (u16*)p;    p += NEL * 2;
    u16*   ob   = (u16*)p;    p += NEL * 2;
    float* atok = (float*)p;  p += (size_t)BB * NTOK * CA * 4;
    float* tbv  = (float*)p;  p += 8192;
    int*   flag = (int*)p;    p += 256;
    u16*   wt   = (u16*)p;    p += (size_t)WT_TOT * 2;
    float* aux  = (float*)p;  p += AX_TOT * 4;
    if ((size_t)(p - (char*)d_ws) > ws_size) return;  // workspace too small

    // 1) detect input storage dtype (writes flag: 1=bf16, 0=f32)
    detect_kernel<<<1, 256, 0, stream>>>((const u32*)d_in[3], flag);

    // 2) weight preprocessing (gated pair; exactly one runs)
    wtrans_kernel<u16><<<41, 256, 0, stream>>>(
        flag, 1, (const u16*)d_in[3], (const u16*)d_in[10], (const u16*)d_in[11],
        (const u16*)d_in[12], (const u16*)d_in[13], (const u16*)d_in[16],
        (const u16*)d_in[17], (const u16*)d_in[4], (const u16*)d_in[5],
        (const u16*)d_in[6], (const u16*)d_in[7], (const u16*)d_in[8],
        (const u16*)d_in[9], (const u16*)d_in[14], (const u16*)d_in[15],
        (const u16*)d_in[18], (const u16*)d_in[19], wt, aux);
    wtrans_kernel<float><<<41, 256, 0, stream>>>(
        flag, 0, (const float*)d_in[3], (const float*)d_in[10], (const float*)d_in[11],
        (const float*)d_in[12], (const float*)d_in[13], (const float*)d_in[16],
        (const float*)d_in[17], (const float*)d_in[4], (const float*)d_in[5],
        (const float*)d_in[6], (const float*)d_in[7], (const float*)d_in[8],
        (const float*)d_in[9], (const float*)d_in[14], (const float*)d_in[15],
        (const float*)d_in[18], (const float*)d_in[19], wt, aux);

    // 3) token projection (gated pair)
    sgemm_bf<1, 3, false, false><<<BB * NTOK / 128, 256, 0, stream>>>(
        flag, 1, (const u16*)d_in[0], CTOK, wt + WT_WA, wt + WT_WA + 49152,
        CTOK, 128, atok, CA);
    sgemm_f32<2, 3, 0><<<BB * NTOK / 128, 256, 0, stream>>>(
        flag, 0, (const float*)d_in[0], CTOK, wt + WT_WA, wt + WT_WA + 49152,
        CTOK, 128, atok, CA);

    // 4) gather + layer-0 LN1
    gather_ln_kernel<<<BB * NATOM / 4, 256, 0, stream>>>(
        atok, (const int*)d_in[2], aux + AX_L1G, aux + AX_L1B, x, h);
    bias_kernel<<<1, 512, 0, stream>>>(x, aux, tbv);

    // 5) layers
    for (int l = 0; l < 3; l++) {
        u16* wl = wt + WT_L0 + (size_t)l * WT_LSZ;
        qkv_fused<<<256, 512, 0, stream>>>(h, wl, qb, kb, vb);
        attn_kernel<<<BB * NWIN, 256, 0, stream>>>(qb, kb, vb, tbv, ob);
        sgemm_add_ln<<<512, 256, 0, stream>>>(
            ob, wl + 98304, wl + 98304 + 16384, x,
            aux + AX_L2G + l * 128, aux + AX_L2B + l * 128, h);
        if (l < 2)
            mlp_ln<true><<<256, 512, 0, stream>>>(
                h, wl + 131072, wl + 262144, x,
                aux + AX_L1G + (l + 1) * 128, aux + AX_L1B + (l + 1) * 128, h);
        else
            mlp_ln<false><<<256, 512, 0, stream>>>(
                h, wl + 131072, wl + 262144, x, aux, aux, h);
    }

    // 6) out = x @ W_out -> d_out directly, format by flag (always runs)
    sgemm_f32<2, 1, 2><<<512, 256, 0, stream>>>(
        flag, -1, x, CA, wt + WT_WO, wt + WT_WO + 16384, CA, 0, d_out, CA);
}

// Round 13
// 548.488 us; speedup vs baseline: 1.1083x; 1.0177x over previous
//
#include <hip/hip_runtime.h>

typedef unsigned short u16;
typedef unsigned int   u32;

typedef __attribute__((ext_vector_type(8))) __bf16 bf16x8;
typedef __attribute__((ext_vector_type(4))) float  f32x4;

// ---------- scalar/vec conversion helpers ----------
__device__ __forceinline__ float bf2f(u16 v) {
    return __uint_as_float(((u32)v) << 16);
}
__device__ __forceinline__ u16 f2bf(float f) {
    u32 u = __float_as_uint(f);
    u32 r = (u + 0x7fffu + ((u >> 16) & 1u)) >> 16;  // round-to-nearest-even
    return (u16)r;
}
__device__ __forceinline__ float ld1(const u16* p)   { return bf2f(*p); }
__device__ __forceinline__ float ld1(const float* p) { return *p; }

// ---------- problem constants ----------
#define BB 4
#define NTOK 2048
#define NATOM 16384
#define CTOK 384
#define CA 128
#define NQ 32
#define NK 128
#define NH 4
#define DH 32
#define NWIN 512
#define PAD 48

// Transposed-weight workspace layout (u16 elements).
// Each matrix stored as [N][K] hi-plane, then lo-plane (lo = 0 for bf16 input).
#define WT_WA   0          // [128][384], lo plane at +49152
#define WT_L0   98304      // per-layer block start
#define WT_LSZ  393216     // Q 0 | K 32768 | V 65536 | O 98304 | T1 131072 | T2 262144
#define WT_WO   1277952    // [128][128], lo plane at +16384
#define WT_TOT  1310720

// Aux f32 scratch layout (floats)
#define AX_WCL  0
#define AX_WCM  2048
#define AX_WM1  4096
#define AX_WM2  4352
#define AX_WPB  4608
#define AX_L1G  4672
#define AX_L1B  5056
#define AX_L2G  5440
#define AX_L2B  5824
#define AX_TOT  6208

// =====================================================================
// dtype detector: look at low u16 of 1024 words of W_a.
// flag = 1 (bf16 inputs) or 0 (f32 inputs)
// =====================================================================
__global__ __launch_bounds__(256) void detect_kernel(const u32* __restrict__ wa,
                                                     int* __restrict__ flag)
{
    __shared__ int cnt;
    if (threadIdx.x == 0) cnt = 0;
    __syncthreads();
    int local = 0;
#pragma unroll
    for (int i = 0; i < 4; i++) {
        u32 w = wa[threadIdx.x * 4 + i];
        u32 e = (w >> 7) & 0xFFu;   // exponent field of the LOW u16 as bf16
        if (e >= 95u && e <= 135u) local++;
    }
    atomicAdd(&cnt, local);
    __syncthreads();
    if (threadIdx.x == 0) *flag = (cnt >= 614) ? 1 : 0;
}

// =====================================================================
// Weight transpose + bf16 hi/lo split into WT workspace, plus f32 aux
// conversion.  41 blocks; gated on dtype flag.
// =====================================================================
template<typename TIN>
__global__ __launch_bounds__(256) void wtrans_kernel(
    const int* __restrict__ flag, int want,
    const TIN* __restrict__ Wa, const TIN* __restrict__ Wq,
    const TIN* __restrict__ Wk, const TIN* __restrict__ Wv,
    const TIN* __restrict__ Wo, const TIN* __restrict__ Wt1,
    const TIN* __restrict__ Wt2, const TIN* __restrict__ Wout,
    const TIN* __restrict__ Wcl, const TIN* __restrict__ Wcm,
    const TIN* __restrict__ Wm1, const TIN* __restrict__ Wm2,
    const TIN* __restrict__ Wpb, const TIN* __restrict__ l1g,
    const TIN* __restrict__ l1b, const TIN* __restrict__ l2g,
    const TIN* __restrict__ l2b,
    u16* __restrict__ WT, float* __restrict__ AX)
{
    if (*flag != want) return;
    const int t = blockIdx.x;
    const int tid = threadIdx.x;
    if (t == 40) {   // aux f32 conversion
        for (int i = tid; i < 2048; i += 256) AX[AX_WCL + i] = ld1(Wcl + i);
        for (int i = tid; i < 2048; i += 256) AX[AX_WCM + i] = ld1(Wcm + i);
        AX[AX_WM1 + tid] = ld1(Wm1 + tid);
        AX[AX_WM2 + tid] = ld1(Wm2 + tid);
        if (tid < 64) AX[AX_WPB + tid] = ld1(Wpb + tid);
        for (int i = tid; i < 384; i += 256) {
            AX[AX_L1G + i] = ld1(l1g + i);
            AX[AX_L1B + i] = ld1(l1b + i);
            AX[AX_L2G + i] = ld1(l2g + i);
            AX[AX_L2B + i] = ld1(l2b + i);
        }
        return;
    }
    const TIN* S; int sld; u16* D; int dld; int plane;
    if (t < 3) {                                     // W_a [384][128]
        S = Wa + t * 128 * 128; sld = 128;
        D = WT + WT_WA + t * 128; dld = 384; plane = 49152;
    } else if (t < 15) {                             // Wq/k/v/o [128][128]
        const int i = t - 3, l = i >> 2, m = i & 3;
        const TIN* ms = (m == 0) ? Wq : (m == 1) ? Wk : (m == 2) ? Wv : Wo;
        S = ms + l * 16384; sld = 128;
        D = WT + WT_L0 + l * WT_LSZ + m * 32768; dld = 128; plane = 16384;
    } else if (t < 27) {                             // Wt1 [128][512] col-chunk c
        const int i = t - 15, l = i >> 2, c = i & 3;
        S = Wt1 + l * 65536 + c * 128; sld = 512;
        D = WT + WT_L0 + l * WT_LSZ + 131072 + c * 128 * 128; dld = 128; plane = 65536;
    } else if (t < 39) {                             // Wt2 [512][128] row-chunk c
        const int i = t - 27, l = i >> 2, c = i & 3;
        S = Wt2 + l * 65536 + c * 128 * 128; sld = 128;
        D = WT + WT_L0 + l * WT_LSZ + 262144 + c * 128; dld = 512; plane = 65536;
    } else {                                         // W_out [128][128]
        S = Wout; sld = 128;
        D = WT + WT_WO; dld = 128; plane = 16384;
    }
    for (int id = tid; id < 2048; id += 256) {
        const int n = id >> 4, k0 = (id & 15) << 3;
        union { u16 s[8]; uint4 v; } hi, lo;
#pragma unroll
        for (int j = 0; j < 8; j++) {
            if constexpr (sizeof(TIN) == 2) {
                hi.s[j] = ((const u16*)(const void*)S)[(k0 + j) * sld + n];
                lo.s[j] = 0;
            } else {
                const float v = ((const float*)(const void*)S)[(k0 + j) * sld + n];
                const u16 hv = f2bf(v);
                hi.s[j] = hv;
                lo.s[j] = f2bf(v - bf2f(hv));
            }
        }
        *(uint4*)(D + n * dld + k0) = hi.v;
        *(uint4*)(D + plane + n * dld + k0) = lo.v;
    }
}

// =====================================================================
// Async weight-panel staging via global_load_lds (no staging VGPRs).
// LDS image: [plane][128 rows][256 B] LINEAR in segment order; the XOR
// swizzle byte^((row&15)<<4) is applied to the per-lane GLOBAL source
// (inverse-swz source + swz read = both-sides rule).  (row&15) spreads
// the 16 lanes of a b128 read over all 16 slots -> conflict-free
// (HW-verified round 9: SQ_LDS_BANK_CONFLICT 4.46M -> 0).
// =====================================================================
__device__ __forceinline__ void gld16(const void* g, void* l)
{
    __builtin_amdgcn_global_load_lds(
        (const __attribute__((address_space(1))) void*)g,
        (__attribute__((address_space(3))) void*)l, 16, 0, 0);
}

template<int NS, int NTHR>
__device__ __forceinline__ void stage_async(u16* lds, const u16* srcHi,
                                            const u16* srcLo, int strideU16, int tid)
{
    constexpr int NWAVE = NTHR / 64;
    constexpr int NSEG  = NS * 32768 / (NWAVE * 1024);
    const int lane = tid & 63;
    const int wv   = tid >> 6;
#pragma unroll
    for (int i = 0; i < NSEG; i++) {
        const int segoff  = (wv * NSEG + i) << 10;      // byte, wave-uniform
        const int po_full = segoff + lane * 16;
        const int plane   = po_full >> 15;
        const int po      = po_full & 32767;
        const int row     = po >> 8;
        const int colB    = (po & 255) ^ ((row & 15) << 4);
        const u16* g = (plane ? srcLo : srcHi) + row * strideU16 + (colB >> 1);
        gld16(g, (char*)lds + segoff);
    }
}

__device__ __forceinline__ bf16x8 ld_w(const u16* lds, int plane, int row, int kbyte)
{
    union { uint4 q; bf16x8 v; } u;
    u.q = *(const uint4*)((const char*)lds + plane * 32768 + row * 256
                          + (kbyte ^ ((row & 15) << 4)));
    return u.v;
}

// MFMA over one staged panel: acc[2][8] += a{0,1}[kk] @ W(+lo)
template<int NS>
__device__ __forceinline__ void mfma_panel(const u16* Wbuf, const bf16x8* a0,
                                           const bf16x8* a1, int l15, int lg,
                                           f32x4 acc[][8])
{
#pragma unroll
    for (int kk = 0; kk < 4; kk++)
#pragma unroll
        for (int n = 0; n < 8; n++) {
            const int rw = n * 16 + l15, kb = kk * 64 + lg * 16;
            const bf16x8 b = ld_w(Wbuf, 0, rw, kb);
            acc[0][n] = __builtin_amdgcn_mfma_f32_16x16x32_bf16(a0[kk], b, acc[0][n], 0, 0, 0);
            acc[1][n] = __builtin_amdgcn_mfma_f32_16x16x32_bf16(a1[kk], b, acc[1][n], 0, 0, 0);
            if (NS == 2) {
                const bf16x8 bl = ld_w(Wbuf, 1, rw, kb);
                acc[0][n] = __builtin_amdgcn_mfma_f32_16x16x32_bf16(a0[kk], bl, acc[0][n], 0, 0, 0);
                acc[1][n] = __builtin_amdgcn_mfma_f32_16x16x32_bf16(a1[kk], bl, acc[1][n], 0, 0, 0);
            }
        }
}

// Split-A variant: acc += ah@W + al@W (+ ah@Wlo when NS==2)
template<int NS>
__device__ __forceinline__ void mfma_panel_split(const u16* Wbuf,
    const bf16x8* a0h, const bf16x8* a0l, const bf16x8* a1h, const bf16x8* a1l,
    int l15, int lg, f32x4 acc[][8])
{
#pragma unroll
    for (int kk = 0; kk < 4; kk++)
#pragma unroll
        for (int n = 0; n < 8; n++) {
            const int rw = n * 16 + l15, kb = kk * 64 + lg * 16;
            const bf16x8 b = ld_w(Wbuf, 0, rw, kb);
            acc[0][n] = __builtin_amdgcn_mfma_f32_16x16x32_bf16(a0h[kk], b, acc[0][n], 0, 0, 0);
            acc[0][n] = __builtin_amdgcn_mfma_f32_16x16x32_bf16(a0l[kk], b, acc[0][n], 0, 0, 0);
            acc[1][n] = __builtin_amdgcn_mfma_f32_16x16x32_bf16(a1h[kk], b, acc[1][n], 0, 0, 0);
            acc[1][n] = __builtin_amdgcn_mfma_f32_16x16x32_bf16(a1l[kk], b, acc[1][n], 0, 0, 0);
            if (NS == 2) {
                const bf16x8 bl = ld_w(Wbuf, 1, rw, kb);
                acc[0][n] = __builtin_amdgcn_mfma_f32_16x16x32_bf16(a0h[kk], bl, acc[0][n], 0, 0, 0);
                acc[1][n] = __builtin_amdgcn_mfma_f32_16x16x32_bf16(a1h[kk], bl, acc[1][n], 0, 0, 0);
            }
        }
}

__device__ __forceinline__ void splitf8(const float* p, bf16x8* hi, bf16x8* lo)
{
    const float4 f0 = *(const float4*)p;
    const float4 f1 = *(const float4*)(p + 4);
    const float f[8] = {f0.x, f0.y, f0.z, f0.w, f1.x, f1.y, f1.z, f1.w};
    union { u16 s[8]; bf16x8 v; } H, L;
#pragma unroll
    for (int j = 0; j < 8; j++) {
        const u16 hv = f2bf(f[j]);
        H.s[j] = hv;
        L.s[j] = f2bf(f[j] - bf2f(hv));
    }
    *hi = H.v; *lo = L.v;
}

// =====================================================================
// Staged-weight MFMA GEMM (bf16 A): C[M x 128] = A[M x K] @ W.
// 128-row blocks, 256 threads, 4 waves x 32 rows, 2 blocks/CU.
// want < 0: always run; else gated on dtype flag.
// =====================================================================
template<int NS, int KCH, bool OUT_BF16, bool ADD>
__global__ __launch_bounds__(256, 2) void sgemm_bf(
    const int* __restrict__ flag, int want,
    const u16* __restrict__ A, int lda,
    const u16* __restrict__ WHi, const u16* __restrict__ WLo,
    int wstride, int wcstep,
    void* __restrict__ Cv, int ldc)
{
    if (want >= 0 && *flag != want) return;
    __shared__ __align__(16) u16 Wbuf[NS * 16384];
    const int tid = threadIdx.x;
    const int lane = tid & 63, wv = tid >> 6;
    const int l15 = lane & 15, lg = lane >> 4;
    const long long row0 = (long long)blockIdx.x * 128 + wv * 32;

    f32x4 acc[2][8];
    {
        f32x4 z = {0.f, 0.f, 0.f, 0.f};
#pragma unroll
        for (int m = 0; m < 2; m++)
#pragma unroll
            for (int n = 0; n < 8; n++) acc[m][n] = z;
    }

    const u16* A0 = A + (row0 + l15) * (long long)lda + lg * 8;
    const u16* A1 = A0 + 16LL * lda;

    stage_async<NS, 256>(Wbuf, WHi, WLo, wstride, tid);
    for (int ks = 0; ks < KCH; ks++) {
        bf16x8 a0[4], a1[4];
#pragma unroll
        for (int kk = 0; kk < 4; kk++) {
            a0[kk] = *(const bf16x8*)(A0 + ks * 128 + kk * 32);
            a1[kk] = *(const bf16x8*)(A1 + ks * 128 + kk * 32);
        }
        __syncthreads();                       // panel staged (vmcnt drained)
        mfma_panel<NS>(Wbuf, a0, a1, l15, lg, acc);
        if (ks + 1 < KCH) {
            __syncthreads();                   // panel reads done before restage
            stage_async<NS, 256>(Wbuf, WHi + (ks + 1) * wcstep,
                                 WLo + (ks + 1) * wcstep, wstride, tid);
        }
    }

#pragma unroll
    for (int m = 0; m < 2; m++)
#pragma unroll
        for (int r = 0; r < 4; r++) {
            const long long row = row0 + m * 16 + lg * 4 + r;
            if (OUT_BF16) {
                u16* C = (u16*)Cv + row * ldc;
#pragma unroll
                for (int n = 0; n < 8; n++) C[n * 16 + l15] = f2bf(acc[m][n][r]);
            } else {
                float* C = (float*)Cv + row * ldc;
#pragma unroll
                for (int n = 0; n < 8; n++) {
                    float v = acc[m][n][r];
                    if (ADD) v += C[n * 16 + l15];
                    C[n * 16 + l15] = v;
                }
            }
        }
}

// =====================================================================
// Staged-weight MFMA GEMM (f32 A, split in-kernel into hi+lo bf16).
// OM: 0 = f32 store, 1 = bf16 store, 2 = d_out store by *flag
//     (bf16 if flag, else f32 = bf2f(f2bf(v)) to keep bits identical).
// =====================================================================
template<int NS, int KCH, int OM>
__global__ __launch_bounds__(256, 2) void sgemm_f32(
    const int* __restrict__ flag, int want,
    const float* __restrict__ A, int lda,
    const u16* __restrict__ WHi, const u16* __restrict__ WLo,
    int wstride, int wcstep,
    void* __restrict__ Cv, int ldc)
{
    if (want >= 0 && *flag != want) return;
    __shared__ __align__(16) u16 Wbuf[NS * 16384];
    const int tid = threadIdx.x;
    const int lane = tid & 63, wv = tid >> 6;
    const int l15 = lane & 15, lg = lane >> 4;
    const long long row0 = (long long)blockIdx.x * 128 + wv * 32;

    f32x4 acc[2][8];
    {
        f32x4 z = {0.f, 0.f, 0.f, 0.f};
#pragma unroll
        for (int m = 0; m < 2; m++)
#pragma unroll
            for (int n = 0; n < 8; n++) acc[m][n] = z;
    }

    const float* A0 = A + (row0 + l15) * (long long)lda + lg * 8;
    const float* A1 = A0 + 16LL * lda;

    stage_async<NS, 256>(Wbuf, WHi, WLo, wstride, tid);
    for (int ks = 0; ks < KCH; ks++) {
        bf16x8 a0h[4], a0l[4], a1h[4], a1l[4];
#pragma unroll
        for (int kk = 0; kk < 4; kk++) {
            splitf8(A0 + ks * 128 + kk * 32, &a0h[kk], &a0l[kk]);
            splitf8(A1 + ks * 128 + kk * 32, &a1h[kk], &a1l[kk]);
        }
        __syncthreads();
        mfma_panel_split<NS>(Wbuf, a0h, a0l, a1h, a1l, l15, lg, acc);
        if (ks + 1 < KCH) {
            __syncthreads();
            stage_async<NS, 256>(Wbuf, WHi + (ks + 1) * wcstep,
                                 WLo + (ks + 1) * wcstep, wstride, tid);
        }
    }

    const bool asbf = (OM == 2) ? (*flag != 0) : (OM == 1);
#pragma unroll
    for (int m = 0; m < 2; m++)
#pragma unroll
        for (int r = 0; r < 4; r++) {
            const long long row = row0 + m * 16 + lg * 4 + r;
            if (OM == 0) {
                float* C = (float*)Cv + row * ldc;
#pragma unroll
                for (int n = 0; n < 8; n++) C[n * 16 + l15] = acc[m][n][r];
            } else if (asbf) {
                u16* C = (u16*)Cv + row * ldc;
#pragma unroll
                for (int n = 0; n < 8; n++) C[n * 16 + l15] = f2bf(acc[m][n][r]);
            } else {
                float* C = (float*)Cv + row * ldc;
#pragma unroll
                for (int n = 0; n < 8; n++)
                    C[n * 16 + l15] = bf2f(f2bf(acc[m][n][r]));
            }
        }
}

// =====================================================================
// O-projection + residual + fused LN2: x += ob@Wo; h = LN(x)*g+b.
// 128-row blocks, 256 threads; each wave holds full 128-wide rows, so
// LN reduce = 8 local adds + shfl_xor(1,2,4,8) over the l15 group.
// =====================================================================
__global__ __launch_bounds__(256, 2) void sgemm_add_ln(
    const u16* __restrict__ A,
    const u16* __restrict__ WHi, const u16* __restrict__ WLo,
    float* __restrict__ x, const float* __restrict__ g,
    const float* __restrict__ bvec, u16* __restrict__ h)
{
    __shared__ __align__(16) u16 Wbuf[2 * 16384];
    const int tid = threadIdx.x;
    const int lane = tid & 63, wv = tid >> 6;
    const int l15 = lane & 15, lg = lane >> 4;
    const long long row0 = (long long)blockIdx.x * 128 + wv * 32;

    f32x4 acc[2][8];
    {
        f32x4 z = {0.f, 0.f, 0.f, 0.f};
#pragma unroll
        for (int m = 0; m < 2; m++)
#pragma unroll
            for (int n = 0; n < 8; n++) acc[m][n] = z;
    }

    const u16* A0 = A + (row0 + l15) * 128LL + lg * 8;
    const u16* A1 = A0 + 16LL * 128;

    stage_async<2, 256>(Wbuf, WHi, WLo, 128, tid);
    bf16x8 a0[4], a1[4];
#pragma unroll
    for (int kk = 0; kk < 4; kk++) {
        a0[kk] = *(const bf16x8*)(A0 + kk * 32);
        a1[kk] = *(const bf16x8*)(A1 + kk * 32);
    }
    __syncthreads();
    mfma_panel<2>(Wbuf, a0, a1, l15, lg, acc);

    float gv[8], bv[8];
#pragma unroll
    for (int n = 0; n < 8; n++) { gv[n] = g[n * 16 + l15]; bv[n] = bvec[n * 16 + l15]; }

#pragma unroll
    for (int m = 0; m < 2; m++)
#pragma unroll
        for (int r = 0; r < 4; r++) {
            const long long row = row0 + m * 16 + lg * 4 + r;
            float* X = x + row * CA;
            float v[8]; float s = 0.f, sq = 0.f;
#pragma unroll
            for (int n = 0; n < 8; n++) {
                v[n] = X[n * 16 + l15] + acc[m][n][r];
                X[n * 16 + l15] = v[n];
                s += v[n]; sq += v[n] * v[n];
            }
            s  += __shfl_xor(s, 1, 64);  s  += __shfl_xor(s, 2, 64);
            s  += __shfl_xor(s, 4, 64);  s  += __shfl_xor(s, 8, 64);
            sq += __shfl_xor(sq, 1, 64); sq += __shfl_xor(sq, 2, 64);
            sq += __shfl_xor(sq, 4, 64); sq += __shfl_xor(sq, 8, 64);
            const float mean = s * 0.0078125f;
            const float var  = sq * 0.0078125f - mean * mean;
            const float inv  = rsqrtf(var + 1e-5f);
            u16* H = h + row * CA;
#pragma unroll
            for (int n = 0; n < 8; n++)
                H[n * 16 + l15] = f2bf((v[n] - mean) * inv * gv[n] + bv[n]);
        }
}

// =====================================================================
// Fused QKV (512 thr, 256 rows/block): ping-pong two panel buffers;
// next panel's async loads issue before this panel's MFMA.
// =====================================================================
__global__ __launch_bounds__(512, 1) void qkv_fused(
    const u16* __restrict__ h, const u16* __restrict__ wl,
    u16* __restrict__ qb, u16* __restrict__ kb, u16* __restrict__ vb)
{
    __shared__ __align__(16) u16 bufA[2 * 16384];
    __shared__ __align__(16) u16 bufB[2 * 16384];
    const int tid = threadIdx.x;
    const int lane = tid & 63, wv = tid >> 6;
    const int l15 = lane & 15, lg = lane >> 4;
    const long long row0 = (long long)blockIdx.x * 256 + wv * 32;

    bf16x8 a0[4], a1[4];
#pragma unroll
    for (int kk = 0; kk < 4; kk++) {
        a0[kk] = *(const bf16x8*)(h + (row0 + l15) * 128 + kk * 32 + lg * 8);
        a1[kk] = *(const bf16x8*)(h + (row0 + 16 + l15) * 128 + kk * 32 + lg * 8);
    }

    stage_async<2, 512>(bufA, wl, wl + 16384, 128, tid);          // Q
    __syncthreads();

#pragma unroll
    for (int m = 0; m < 3; m++) {
        if (m < 2)   // prefetch next panel
            stage_async<2, 512>((m == 0) ? bufB : bufA,
                                wl + (m + 1) * 32768,
                                wl + (m + 1) * 32768 + 16384, 128, tid);
        f32x4 acc[2][8];
        {
            f32x4 z = {0.f, 0.f, 0.f, 0.f};
#pragma unroll
            for (int i = 0; i < 2; i++)
#pragma unroll
                for (int n = 0; n < 8; n++) acc[i][n] = z;
        }
        const u16* cur = (m == 1) ? bufB : bufA;   // Q:A, K:B, V:A
        mfma_panel<2>(cur, a0, a1, l15, lg, acc);
        u16* out = (m == 0) ? qb : (m == 1) ? kb : vb;
#pragma unroll
        for (int i = 0; i < 2; i++)
#pragma unroll
            for (int r = 0; r < 4; r++) {
                u16* C = out + (row0 + i * 16 + lg * 4 + r) * CA;
#pragma unroll
                for (int n = 0; n < 8; n++) C[n * 16 + l15] = f2bf(acc[i][n][r]);
            }
        if (m < 2) __syncthreads();   // drains prefetch; cur reads done
    }
}

// =====================================================================
// Fused MLP + residual + next-layer LN1 (512 thr, 256 rows/block):
// x += relu(h @ Wt1) @ Wt2; h_out = LN(x)*g+b (EMIT_H).
// Two weight buffers, async staging; hidden transpose via per-wave
// 32x80B quarter buffer (wave-local waits). LDS 148 KB.
// =====================================================================
template<bool EMIT_H>
__global__ __launch_bounds__(512, 1) void mlp_ln(
    const u16* __restrict__ h,
    const u16* __restrict__ W1T, const u16* __restrict__ W2T,
    float* __restrict__ x, const float* __restrict__ g,
    const float* __restrict__ bvec, u16* __restrict__ hout)
{
    __shared__ __align__(16) u16 W1buf[2 * 16384];
    __shared__ __align__(16) u16 W2buf[2 * 16384];
    __shared__ __align__(16) u16 Plq[8][32][40];   // per-wave 32 rows x 80 B
    const int tid = threadIdx.x;
    const int lane = tid & 63, wv = tid >> 6;
    const int l15 = lane & 15, lg = lane >> 4;
    const long long row0 = (long long)blockIdx.x * 256 + wv * 32;
    u16* pw = &Plq[wv][0][0];

    bf16x8 ah0[4], ah1[4];
#pragma unroll
    for (int kk = 0; kk < 4; kk++) {
        ah0[kk] = *(const bf16x8*)(h + (row0 + l15) * 128 + kk * 32 + lg * 8);
        ah1[kk] = *(const bf16x8*)(h + (row0 + 16 + l15) * 128 + kk * 32 + lg * 8);
    }

    f32x4 xacc[2][8];
    {
        f32x4 z = {0.f, 0.f, 0.f, 0.f};
#pragma unroll
        for (int m = 0; m < 2; m++)
#pragma unroll
            for (int n = 0; n < 8; n++) xacc[m][n] = z;
    }

    stage_async<2, 512>(W1buf, W1T, W1T + 65536, 128, tid);
    __syncthreads();

    for (int c = 0; c < 4; c++) {
        // ---- W1 phase: issue W2c loads, MFMA W1 under them ----
        stage_async<2, 512>(W2buf, W2T + c * 128, W2T + 65536 + c * 128, 512, tid);
        f32x4 hacc[2][8];
        {
            f32x4 z = {0.f, 0.f, 0.f, 0.f};
#pragma unroll
            for (int m = 0; m < 2; m++)
#pragma unroll
                for (int n = 0; n < 8; n++) hacc[m][n] = z;
        }
        mfma_panel<2>(W1buf, ah0, ah1, l15, lg, hacc);
        __syncthreads();                 // W2buf staged; all waves done W1 reads

        // ---- W2 phase: issue W1(c+1) loads, quarters + MFMA W2 ----
        if (c < 3)
            stage_async<2, 512>(W1buf, W1T + (c + 1) * 16384,
                                W1T + 65536 + (c + 1) * 16384, 128, tid);
#pragma unroll
        for (int q = 0; q < 4; q++) {
            asm volatile("s_waitcnt lgkmcnt(0)" ::: "memory");
#pragma unroll
            for (int m = 0; m < 2; m++)
#pragma unroll
                for (int j = 0; j < 2; j++)
#pragma unroll
                    for (int r = 0; r < 4; r++)
                        pw[(m * 16 + lg * 4 + r) * 40 + j * 16 + l15]
                            = f2bf(fmaxf(hacc[m][2 * q + j][r], 0.f));
            asm volatile("s_waitcnt lgkmcnt(0)" ::: "memory");
            union { uint4 v; bf16x8 b; } t0, t1;
            t0.v = *(const uint4*)(pw + l15 * 40 + lg * 8);
            t1.v = *(const uint4*)(pw + (16 + l15) * 40 + lg * 8);
#pragma unroll
            for (int n = 0; n < 8; n++) {
                const int rw = n * 16 + l15, kb = q * 64 + lg * 16;
                const bf16x8 b = ld_w(W2buf, 0, rw, kb);
                xacc[0][n] = __builtin_amdgcn_mfma_f32_16x16x32_bf16(t0.b, b, xacc[0][n], 0, 0, 0);
                xacc[1][n] = __builtin_amdgcn_mfma_f32_16x16x32_bf16(t1.b, b, xacc[1][n], 0, 0, 0);
                const bf16x8 bl = ld_w(W2buf, 1, rw, kb);
                xacc[0][n] = __builtin_amdgcn_mfma_f32_16x16x32_bf16(t0.b, bl, xacc[0][n], 0, 0, 0);
                xacc[1][n] = __builtin_amdgcn_mfma_f32_16x16x32_bf16(t1.b, bl, xacc[1][n], 0, 0, 0);
            }
        }
        if (c < 3) __syncthreads();      // W1buf(c+1) staged; W2buf reads done
    }

    float gv[8], bv[8];
    if (EMIT_H) {
#pragma unroll
        for (int n = 0; n < 8; n++) { gv[n] = g[n * 16 + l15]; bv[n] = bvec[n * 16 + l15]; }
    }

#pragma unroll
    for (int m = 0; m < 2; m++)
#pragma unroll
        for (int r = 0; r < 4; r++) {
            const long long row = row0 + m * 16 + lg * 4 + r;
            float* X = x + row * CA;
            float v[8]; float s = 0.f, sq = 0.f;
#pragma unroll
            for (int n = 0; n < 8; n++) {
                v[n] = X[n * 16 + l15] + xacc[m][n][r];
                X[n * 16 + l15] = v[n];
                s += v[n]; sq += v[n] * v[n];
            }
            if (EMIT_H) {
                s  += __shfl_xor(s, 1, 64);  s  += __shfl_xor(s, 2, 64);
                s  += __shfl_xor(s, 4, 64);  s  += __shfl_xor(s, 8, 64);
                sq += __shfl_xor(sq, 1, 64); sq += __shfl_xor(sq, 2, 64);
                sq += __shfl_xor(sq, 4, 64); sq += __shfl_xor(sq, 8, 64);
                const float mean = s * 0.0078125f;
                const float var  = sq * 0.0078125f - mean * mean;
                const float inv  = rsqrtf(var + 1e-5f);
                u16* H = hout + row * CA;
#pragma unroll
                for (int n = 0; n < 8; n++)
                    H[n * 16 + l15] = f2bf((v[n] - mean) * inv * gv[n] + bv[n]);
            }
        }
}

// =====================================================================
// Gather + LN1 of layer 0: one wave per atom row.
// =====================================================================
__global__ __launch_bounds__(256) void gather_ln_kernel(
    const float* __restrict__ atok, const int* __restrict__ idx,
    const float* __restrict__ g, const float* __restrict__ bvec,
    float* __restrict__ x, u16* __restrict__ h)
{
    const int lane = threadIdx.x & 63;
    const int wv   = threadIdx.x >> 6;
    const size_t an = (size_t)blockIdx.x * 4 + wv;
    const int b = (int)(an >> 14);
    const int n = (int)(an & (NATOM - 1));
    const int t = idx[b * NATOM + n];
    const float* src = atok + ((size_t)b * NTOK + t) * CA;
    const float v0 = src[lane], v1 = src[lane + 64];
    float* xr = x + an * CA;
    xr[lane] = v0; xr[lane + 64] = v1;
    float s  = v0 + v1;
    float sq = v0 * v0 + v1 * v1;
#pragma unroll
    for (int off = 32; off > 0; off >>= 1) {
        s  += __shfl_xor(s,  off, 64);
        sq += __shfl_xor(sq, off, 64);
    }
    const float mean = s * 0.0078125f;
    const float var  = sq * 0.0078125f - mean * mean;
    const float inv  = rsqrtf(var + 1e-5f);
    u16* hr = h + an * CA;
    hr[lane]      = f2bf((v0 - mean) * inv * g[lane]      + bvec[lane]);
    hr[lane + 64] = f2bf((v1 - mean) * inv * g[lane + 64] + bvec[lane + 64]);
}

// =====================================================================
// Bias: t[b,a,h] for a < 128 from the pair-MLP (f32 aux weights).
// =====================================================================
__global__ __launch_bounds__(512) void bias_kernel(
    const float* __restrict__ x, const float* __restrict__ AX,
    float* __restrict__ tb)
{
    __shared__ float Wsum[128][16];
    __shared__ float M1[16][16];
    __shared__ float M2[16][16];
    __shared__ float Pb[16][4];
    const int tid = threadIdx.x;
    for (int i = tid; i < 128 * 16; i += 512)
        Wsum[i >> 4][i & 15] = AX[AX_WCL + i] + AX[AX_WCM + i];
    if (tid < 256) M1[tid >> 4][tid & 15] = AX[AX_WM1 + tid];
    if (tid >= 256 && tid < 512) { int t2 = tid - 256; M2[t2 >> 4][t2 & 15] = AX[AX_WM2 + t2]; }
    if (tid < 64) Pb[tid >> 2][tid & 3] = AX[AX_WPB + tid];
    __syncthreads();

    const int b = tid >> 7, a = tid & 127;
    const float* xa = x + ((size_t)b * NATOM + a) * CA;
    float u[16];
#pragma unroll
    for (int p = 0; p < 16; p++) u[p] = 0.f;
    for (int c = 0; c < 128; c++) {
        const float xv = xa[c];
#pragma unroll
        for (int p = 0; p < 16; p++) u[p] = fmaf(xv, Wsum[c][p], u[p]);
    }
    float r1[16];
#pragma unroll
    for (int p = 0; p < 16; p++) r1[p] = 0.f;
    for (int c = 0; c < 16; c++) {
        const float rv = fmaxf(u[c], 0.f);
#pragma unroll
        for (int p = 0; p < 16; p++) r1[p] = fmaf(rv, M1[c][p], r1[p]);
    }
    float r2[16];
#pragma unroll
    for (int p = 0; p < 16; p++) r2[p] = 0.f;
    for (int c = 0; c < 16; c++) {
        const float rv = fmaxf(r1[c], 0.f);
#pragma unroll
        for (int p = 0; p < 16; p++) r2[p] = fmaf(rv, M2[c][p], r2[p]);
    }
#pragma unroll
    for (int hh = 0; hh < 4; hh++) {
        float s = 0.f;
#pragma unroll
        for (int p = 0; p < 16; p++) s = fmaf(r2[p], Pb[p][hh], s);
        tb[(size_t)tid * 4 + hh] = s;
    }
}

// =====================================================================
// Windowed attention via MFMA (verified round 1): one block per (b, w).
// XCD-aware blockIdx swizzle (T1): nwg = 2048 = 8 XCDs x 256, so each
// XCD gets 256 CONSECUTIVE windows -> the 96/128-row K/V window overlap
// between neighbors becomes per-XCD L2 hits instead of HBM refetches.
// =====================================================================
#define VTP 132   // V^T row stride in u16
#define PPS 68    // P row stride in u16

__global__ __launch_bounds__(256) void attn_kernel(
    const u16* __restrict__ qg, const u16* __restrict__ kg,
    const u16* __restrict__ vg, const float* __restrict__ tb,
    u16* __restrict__ og)
{
    __shared__ __align__(16) u16 VT[128][VTP];    // V^T: [d][j]
    __shared__ __align__(16) u16 Pl[NH][32][PPS]; // per-head P half

    const int tid  = threadIdx.x;
    const int lane = tid & 63;
    const int h    = tid >> 6;             // wave id == head
    const int bw   = (blockIdx.x & 7) * (BB * NWIN / 8) + (blockIdx.x >> 3);
    const int b    = bw >> 9;
    const int w    = bw & (NWIN - 1);
    const int row0 = w * NQ;
    const int kbase = row0 - PAD;          // first key atom (may be < 0)
    const int l15 = lane & 15;
    const int lg  = lane >> 4;

    // ---- stage V^T into LDS (all 256 threads; zero invalid rows) ----
    {
        const int j  = tid & 127;
        const int d0 = (tid >> 7) << 6;    // 0 or 64
        const int ga = kbase + j;
        const bool val = (ga >= 0) && (ga < NATOM);
        const u16* vrow = vg + ((long long)b * NATOM + ga) * CA + d0;
#pragma unroll
        for (int t2 = 0; t2 < 8; t2++) {
            union { uint4 q; u16 s[8]; } u;
            if (val) u.q = *(const uint4*)(vrow + t2 * 8);
            else     u.q = make_uint4(0u, 0u, 0u, 0u);
#pragma unroll
            for (int e = 0; e < 8; e++) VT[d0 + t2 * 8 + e][j] = u.s[e];
        }
    }

    // ---- QK^T: S[32][128] per head, frags direct from global ----
    const long long qoff = ((long long)b * NATOM + row0) * CA + h * DH;
    const long long koff = ((long long)b * NATOM + kbase) * CA + h * DH;
    bf16x8 aq0 = *(const bf16x8*)(qg + qoff + (long long)l15 * CA + lg * 8);
    bf16x8 aq1 = *(const bf16x8*)(qg + qoff + (long long)(l15 + 16) * CA + lg * 8);

    f32x4 acc[2][8];
    {
        f32x4 z = {0.f, 0.f, 0.f, 0.f};
#pragma unroll
        for (int m = 0; m < 2; m++)
#pragma unroll
            for (int n = 0; n < 8; n++) acc[m][n] = z;
    }
#pragma unroll
    for (int n = 0; n < 8; n++) {
        bf16x8 bk = *(const bf16x8*)(kg + koff + (long long)(n * 16 + l15) * CA + lg * 8);
        acc[0][n] = __builtin_amdgcn_mfma_f32_16x16x32_bf16(aq0, bk, acc[0][n], 0, 0, 0);
        acc[1][n] = __builtin_amdgcn_mfma_f32_16x16x32_bf16(aq1, bk, acc[1][n], 0, 0, 0);
    }

    // ---- bias + scale + mask ----
    const float scale = 0.17677669529663687f;  // 1/sqrt(32)
    float tj[8], ti[2][4];
#pragma unroll
    for (int n = 0; n < 8; n++)
        tj[n] = tb[((size_t)b * 128 + n * 16 + l15) * 4 + h];
#pragma unroll
    for (int m = 0; m < 2; m++)
#pragma unroll
        for (int r = 0; r < 4; r++)
            ti[m][r] = tb[((size_t)b * 128 + m * 16 + lg * 4 + r) * 4 + h];

#pragma unroll
    for (int n = 0; n < 8; n++) {
        const int ga = kbase + n * 16 + l15;
        const bool val = (ga >= 0) && (ga < NATOM);
#pragma unroll
        for (int m = 0; m < 2; m++)
#pragma unroll
            for (int r = 0; r < 4; r++) {
                const float s = acc[m][n][r] * scale + ti[m][r] + tj[n];
                acc[m][n][r] = val ? s : -1e9f;
            }
    }

    // ---- softmax ----
    float mx[2][4], inv[2][4];
#pragma unroll
    for (int m = 0; m < 2; m++)
#pragma unroll
        for (int r = 0; r < 4; r++) {
            float v = acc[m][0][r];
#pragma unroll
            for (int n = 1; n < 8; n++) v = fmaxf(v, acc[m][n][r]);
            v = fmaxf(v, __shfl_xor(v, 1, 64));
            v = fmaxf(v, __shfl_xor(v, 2, 64));
            v = fmaxf(v, __shfl_xor(v, 4, 64));
            v = fmaxf(v, __shfl_xor(v, 8, 64));
            mx[m][r] = v;
        }
#pragma unroll
    for (int m = 0; m < 2; m++)
#pragma unroll
        for (int n = 0; n < 8; n++)
#pragma unroll
            for (int r = 0; r < 4; r++)
                acc[m][n][r] = __expf(acc[m][n][r] - mx[m][r]);
#pragma unroll
    for (int m = 0; m < 2; m++)
#pragma unroll
        for (int r = 0; r < 4; r++) {
            float v = 0.f;
#pragma unroll
            for (int n = 0; n < 8; n++) v += acc[m][n][r];
            v += __shfl_xor(v, 1, 64);
            v += __shfl_xor(v, 2, 64);
            v += __shfl_xor(v, 4, 64);
            v += __shfl_xor(v, 8, 64);
            inv[m][r] = 1.0f / v;
        }

    __syncthreads();   // V^T staged

    // ---- PV ----
    f32x4 o[2][2];
    {
        f32x4 z = {0.f, 0.f, 0.f, 0.f};
        o[0][0] = z; o[0][1] = z; o[1][0] = z; o[1][1] = z;
    }
    union B8 { bf16x8 v; uint2 u[2]; };
#pragma unroll
    for (int half = 0; half < 2; half++) {
        asm volatile("s_waitcnt lgkmcnt(0)" ::: "memory");
#pragma unroll
        for (int m = 0; m < 2; m++)
#pragma unroll
            for (int nn = 0; nn < 4; nn++)
#pragma unroll
                for (int r = 0; r < 4; r++)
                    Pl[h][m * 16 + lg * 4 + r][nn * 16 + l15]
                        = f2bf(acc[m][half * 4 + nn][r]);
        asm volatile("s_waitcnt lgkmcnt(0)" ::: "memory");
#pragma unroll
        for (int ks2 = 0; ks2 < 2; ks2++) {
            const int jo = ks2 * 32 + lg * 8;
            const int jg = half * 64 + jo;
            B8 pa0, pa1, vb0, vb1;
            pa0.u[0] = *(const uint2*)&Pl[h][l15][jo];
            pa0.u[1] = *(const uint2*)&Pl[h][l15][jo + 4];
            pa1.u[0] = *(const uint2*)&Pl[h][l15 + 16][jo];
            pa1.u[1] = *(const uint2*)&Pl[h][l15 + 16][jo + 4];
            vb0.u[0] = *(const uint2*)&VT[h * DH + l15][jg];
            vb0.u[1] = *(const uint2*)&VT[h * DH + l15][jg + 4];
            vb1.u[0] = *(const uint2*)&VT[h * DH + 16 + l15][jg];
            vb1.u[1] = *(const uint2*)&VT[h * DH + 16 + l15][jg + 4];
            o[0][0] = __builtin_amdgcn_mfma_f32_16x16x32_bf16(pa0.v, vb0.v, o[0][0], 0, 0, 0);
            o[0][1] = __builtin_amdgcn_mfma_f32_16x16x32_bf16(pa0.v, vb1.v, o[0][1], 0, 0, 0);
            o[1][0] = __builtin_amdgcn_mfma_f32_16x16x32_bf16(pa1.v, vb0.v, o[1][0], 0, 0, 0);
            o[1][1] = __builtin_amdgcn_mfma_f32_16x16x32_bf16(pa1.v, vb1.v, o[1][1], 0, 0, 0);
        }
    }

#pragma unroll
    for (int m = 0; m < 2; m++)
#pragma unroll
        for (int n = 0; n < 2; n++)
#pragma unroll
            for (int r = 0; r < 4; r++)
                og[((long long)b * NATOM + row0 + m * 16 + lg * 4 + r) * CA
                   + h * DH + n * 16 + l15]
                    = f2bf(o[m][n][r] * inv[m][r]);
}

// =====================================================================
// Launch — single dtype-independent pipeline; only wtrans + token
// projection are flag-gated pairs.  Final GEMM writes d_out directly.
// =====================================================================
extern "C" void kernel_launch(void* const* d_in, const int* in_sizes, int n_in,
                              void* d_out, int out_size, void* d_ws, size_t ws_size,
                              hipStream_t stream)
{
    (void)in_sizes; (void)n_in; (void)out_size;
    const size_t NEL = (size_t)BB * NATOM * CA;   // 8388608

    char* p = (char*)d_ws;
    float* x    = (float*)p;  p += NEL * 4;
    u16*   h    = (u16*)p;    p += NEL * 2;
    u16*   qb   = (u16*)p;    p += NEL * 2;
    u16*   kb   = (u16*)p;    p += NEL * 2;
    u16*   vb   = (u16*)p;    p += NEL * 2;
    u16*   ob   = (u16*)p;    p += NEL * 2;
    float* atok = (float*)p;  p += (size_t)BB * NTOK * CA * 4;
    float* tbv  = (float*)p;  p += 8192;
    int*   flag = (int*)p;    p += 256;
    u16*   wt   = (u16*)p;    p += (size_t)WT_TOT * 2;
    float* aux  = (float*)p;  p += AX_TOT * 4;
    if ((size_t)(p - (char*)d_ws) > ws_size) return;  // workspace too small

    // 1) detect input storage dtype (writes flag: 1=bf16, 0=f32)
    detect_kernel<<<1, 256, 0, stream>>>((const u32*)d_in[3], flag);

    // 2) weight preprocessing (gated pair; exactly one runs)
    wtrans_kernel<u16><<<41, 256, 0, stream>>>(
        flag, 1, (const u16*)d_in[3], (const u16*)d_in[10], (const u16*)d_in[11],
        (const u16*)d_in[12], (const u16*)d_in[13], (const u16*)d_in[16],
        (const u16*)d_in[17], (const u16*)d_in[4], (const u16*)d_in[5],
        (const u16*)d_in[6], (const u16*)d_in[7], (const u16*)d_in[8],
        (const u16*)d_in[9], (const u16*)d_in[14], (const u16*)d_in[15],
        (const u16*)d_in[18], (const u16*)d_in[19], wt, aux);
    wtrans_kernel<float><<<41, 256, 0, stream>>>(
        flag, 0, (const float*)d_in[3], (const float*)d_in[10], (const float*)d_in[11],
        (const float*)d_in[12], (const float*)d_in[13], (const float*)d_in[16],
        (const float*)d_in[17], (const float*)d_in[4], (const float*)d_in[5],
        (const float*)d_in[6], (const float*)d_in[7], (const float*)d_in[8],
        (const float*)d_in[9], (const float*)d_in[14], (const float*)d_in[15],
        (const float*)d_in[18], (const float*)d_in[19], wt, aux);

    // 3) token projection (gated pair)
    sgemm_bf<1, 3, false, false><<<BB * NTOK / 128, 256, 0, stream>>>(
        flag, 1, (const u16*)d_in[0], CTOK, wt + WT_WA, wt + WT_WA + 49152,
        CTOK, 128, atok, CA);
    sgemm_f32<2, 3, 0><<<BB * NTOK / 128, 256, 0, stream>>>(
        flag, 0, (const float*)d_in[0], CTOK, wt + WT_WA, wt + WT_WA + 49152,
        CTOK, 128, atok, CA);

    // 4) gather + layer-0 LN1
    gather_ln_kernel<<<BB * NATOM / 4, 256, 0, stream>>>(
        atok, (const int*)d_in[2], aux + AX_L1G, aux + AX_L1B, x, h);
    bias_kernel<<<1, 512, 0, stream>>>(x, aux, tbv);

    // 5) layers
    for (int l = 0; l < 3; l++) {
        u16* wl = wt + WT_L0 + (size_t)l * WT_LSZ;
        qkv_fused<<<256, 512, 0, stream>>>(h, wl, qb, kb, vb);
        attn_kernel<<<BB * NWIN, 256, 0, stream>>>(qb, kb, vb, tbv, ob);
        sgemm_add_ln<<<512, 256, 0, stream>>>(
            ob, wl + 98304, wl + 98304 + 16384, x,
            aux + AX_L2G + l * 128, aux + AX_L2B + l * 128, h);
        if (l < 2)
            mlp_ln<true><<<256, 512, 0, stream>>>(
                h, wl + 131072, wl + 262144, x,
                aux + AX_L1G + (l + 1) * 128, aux + AX_L1B + (l + 1) * 128, h);
        else
            mlp_ln<false><<<256, 512, 0, stream>>>(
                h, wl + 131072, wl + 262144, x, aux, aux, h);
    }

    // 6) out = x @ W_out -> d_out directly, format by flag (always runs)
    sgemm_f32<2, 1, 2><<<512, 256, 0, stream>>>(
        flag, -1, x, CA, wt + WT_WO, wt + WT_WO + 16384, CA, 0, d_out, CA);
}

// Round 14
// 538.303 us; speedup vs baseline: 1.1293x; 1.0189x over previous
//
#include <hip/hip_runtime.h>

typedef unsigned short u16;
typedef unsigned int   u32;

typedef __attribute__((ext_vector_type(8))) __bf16 bf16x8;
typedef __attribute__((ext_vector_type(4))) float  f32x4;

// ---------- scalar/vec conversion helpers ----------
__device__ __forceinline__ float bf2f(u16 v) {
    return __uint_as_float(((u32)v) << 16);
}
__device__ __forceinline__ u16 f2bf(float f) {
    u32 u = __float_as_uint(f);
    u32 r = (u + 0x7fffu + ((u >> 16) & 1u)) >> 16;  // round-to-nearest-even
    return (u16)r;
}
__device__ __forceinline__ float ld1(const u16* p)   { return bf2f(*p); }
__device__ __forceinline__ float ld1(const float* p) { return *p; }

// ---------- problem constants ----------
#define BB 4
#define NTOK 2048
#define NATOM 16384
#define CTOK 384
#define CA 128
#define NQ 32
#define NK 128
#define NH 4
#define DH 32
#define NWIN 512
#define PAD 48

// Transposed-weight workspace layout (u16 elements).
// Each matrix stored as [N][K] hi-plane, then lo-plane (lo = 0 for bf16 input).
#define WT_WA   0          // [128][384], lo plane at +49152
#define WT_L0   98304      // per-layer block start
#define WT_LSZ  393216     // Q 0 | K 32768 | V 65536 | O 98304 | T1 131072 | T2 262144
#define WT_WO   1277952    // [128][128], lo plane at +16384
#define WT_TOT  1310720

// Aux f32 scratch layout (floats)
#define AX_WCL  0
#define AX_WCM  2048
#define AX_WM1  4096
#define AX_WM2  4352
#define AX_WPB  4608
#define AX_L1G  4672
#define AX_L1B  5056
#define AX_L2G  5440
#define AX_L2B  5824
#define AX_TOT  6208

// =====================================================================
// dtype detector: look at low u16 of 1024 words of W_a.
// flag = 1 (bf16 inputs) or 0 (f32 inputs)
// =====================================================================
__global__ __launch_bounds__(256) void detect_kernel(const u32* __restrict__ wa,
                                                     int* __restrict__ flag)
{
    __shared__ int cnt;
    if (threadIdx.x == 0) cnt = 0;
    __syncthreads();
    int local = 0;
#pragma unroll
    for (int i = 0; i < 4; i++) {
        u32 w = wa[threadIdx.x * 4 + i];
        u32 e = (w >> 7) & 0xFFu;   // exponent field of the LOW u16 as bf16
        if (e >= 95u && e <= 135u) local++;
    }
    atomicAdd(&cnt, local);
    __syncthreads();
    if (threadIdx.x == 0) *flag = (cnt >= 614) ? 1 : 0;
}

// =====================================================================
// Weight transpose + bf16 hi/lo split into WT workspace, plus f32 aux
// conversion.  41 blocks; gated on dtype flag.
// =====================================================================
template<typename TIN>
__global__ __launch_bounds__(256) void wtrans_kernel(
    const int* __restrict__ flag, int want,
    const TIN* __restrict__ Wa, const TIN* __restrict__ Wq,
    const TIN* __restrict__ Wk, const TIN* __restrict__ Wv,
    const TIN* __restrict__ Wo, const TIN* __restrict__ Wt1,
    const TIN* __restrict__ Wt2, const TIN* __restrict__ Wout,
    const TIN* __restrict__ Wcl, const TIN* __restrict__ Wcm,
    const TIN* __restrict__ Wm1, const TIN* __restrict__ Wm2,
    const TIN* __restrict__ Wpb, const TIN* __restrict__ l1g,
    const TIN* __restrict__ l1b, const TIN* __restrict__ l2g,
    const TIN* __restrict__ l2b,
    u16* __restrict__ WT, float* __restrict__ AX)
{
    if (*flag != want) return;
    const int t = blockIdx.x;
    const int tid = threadIdx.x;
    if (t == 40) {   // aux f32 conversion
        for (int i = tid; i < 2048; i += 256) AX[AX_WCL + i] = ld1(Wcl + i);
        for (int i = tid; i < 2048; i += 256) AX[AX_WCM + i] = ld1(Wcm + i);
        AX[AX_WM1 + tid] = ld1(Wm1 + tid);
        AX[AX_WM2 + tid] = ld1(Wm2 + tid);
        if (tid < 64) AX[AX_WPB + tid] = ld1(Wpb + tid);
        for (int i = tid; i < 384; i += 256) {
            AX[AX_L1G + i] = ld1(l1g + i);
            AX[AX_L1B + i] = ld1(l1b + i);
            AX[AX_L2G + i] = ld1(l2g + i);
            AX[AX_L2B + i] = ld1(l2b + i);
        }
        return;
    }
    const TIN* S; int sld; u16* D; int dld; int plane;
    if (t < 3) {                                     // W_a [384][128]
        S = Wa + t * 128 * 128; sld = 128;
        D = WT + WT_WA + t * 128; dld = 384; plane = 49152;
    } else if (t < 15) {                             // Wq/k/v/o [128][128]
        const int i = t - 3, l = i >> 2, m = i & 3;
        const TIN* ms = (m == 0) ? Wq : (m == 1) ? Wk : (m == 2) ? Wv : Wo;
        S = ms + l * 16384; sld = 128;
        D = WT + WT_L0 + l * WT_LSZ + m * 32768; dld = 128; plane = 16384;
    } else if (t < 27) {                             // Wt1 [128][512] col-chunk c
        const int i = t - 15, l = i >> 2, c = i & 3;
        S = Wt1 + l * 65536 + c * 128; sld = 512;
        D = WT + WT_L0 + l * WT_LSZ + 131072 + c * 128 * 128; dld = 128; plane = 65536;
    } else if (t < 39) {                             // Wt2 [512][128] row-chunk c
        const int i = t - 27, l = i >> 2, c = i & 3;
        S = Wt2 + l * 65536 + c * 128 * 128; sld = 128;
        D = WT + WT_L0 + l * WT_LSZ + 262144 + c * 128; dld = 512; plane = 65536;
    } else {                                         // W_out [128][128]
        S = Wout; sld = 128;
        D = WT + WT_WO; dld = 128; plane = 16384;
    }
    for (int id = tid; id < 2048; id += 256) {
        const int n = id >> 4, k0 = (id & 15) << 3;
        union { u16 s[8]; uint4 v; } hi, lo;
#pragma unroll
        for (int j = 0; j < 8; j++) {
            if constexpr (sizeof(TIN) == 2) {
                hi.s[j] = ((const u16*)(const void*)S)[(k0 + j) * sld + n];
                lo.s[j] = 0;
            } else {
                const float v = ((const float*)(const void*)S)[(k0 + j) * sld + n];
                const u16 hv = f2bf(v);
                hi.s[j] = hv;
                lo.s[j] = f2bf(v - bf2f(hv));
            }
        }
        *(uint4*)(D + n * dld + k0) = hi.v;
        *(uint4*)(D + plane + n * dld + k0) = lo.v;
    }
}

// =====================================================================
// Async weight-panel staging via global_load_lds (no staging VGPRs).
// LDS image: [plane][128 rows][256 B] LINEAR in segment order; the XOR
// swizzle byte^((row&7)<<4) is applied to the per-lane GLOBAL source
// (inverse-swz source + swz read = both-sides rule).
// (row&7: 2-way LDS aliasing is ~free; round-13 A/B showed row&15 cost
//  ~8% HBM traffic on mlp_ln for no time gain.)
// =====================================================================
__device__ __forceinline__ void gld16(const void* g, void* l)
{
    __builtin_amdgcn_global_load_lds(
        (const __attribute__((address_space(1))) void*)g,
        (__attribute__((address_space(3))) void*)l, 16, 0, 0);
}

template<int NS, int NTHR>
__device__ __forceinline__ void stage_async(u16* lds, const u16* srcHi,
                                            const u16* srcLo, int strideU16, int tid)
{
    constexpr int NWAVE = NTHR / 64;
    constexpr int NSEG  = NS * 32768 / (NWAVE * 1024);
    const int lane = tid & 63;
    const int wv   = tid >> 6;
#pragma unroll
    for (int i = 0; i < NSEG; i++) {
        const int segoff  = (wv * NSEG + i) << 10;      // byte, wave-uniform
        const int po_full = segoff + lane * 16;
        const int plane   = po_full >> 15;
        const int po      = po_full & 32767;
        const int row     = po >> 8;
        const int colB    = (po & 255) ^ ((row & 7) << 4);
        const u16* g = (plane ? srcLo : srcHi) + row * strideU16 + (colB >> 1);
        gld16(g, (char*)lds + segoff);
    }
}

__device__ __forceinline__ bf16x8 ld_w(const u16* lds, int plane, int row, int kbyte)
{
    union { uint4 q; bf16x8 v; } u;
    u.q = *(const uint4*)((const char*)lds + plane * 32768 + row * 256
                          + (kbyte ^ ((row & 7) << 4)));
    return u.v;
}

// MFMA over one staged panel: acc[2][8] += a{0,1}[kk] @ W(+lo)
template<int NS>
__device__ __forceinline__ void mfma_panel(const u16* Wbuf, const bf16x8* a0,
                                           const bf16x8* a1, int l15, int lg,
                                           f32x4 acc[][8])
{
#pragma unroll
    for (int kk = 0; kk < 4; kk++)
#pragma unroll
        for (int n = 0; n < 8; n++) {
            const int rw = n * 16 + l15, kb = kk * 64 + lg * 16;
            const bf16x8 b = ld_w(Wbuf, 0, rw, kb);
            acc[0][n] = __builtin_amdgcn_mfma_f32_16x16x32_bf16(a0[kk], b, acc[0][n], 0, 0, 0);
            acc[1][n] = __builtin_amdgcn_mfma_f32_16x16x32_bf16(a1[kk], b, acc[1][n], 0, 0, 0);
            if (NS == 2) {
                const bf16x8 bl = ld_w(Wbuf, 1, rw, kb);
                acc[0][n] = __builtin_amdgcn_mfma_f32_16x16x32_bf16(a0[kk], bl, acc[0][n], 0, 0, 0);
                acc[1][n] = __builtin_amdgcn_mfma_f32_16x16x32_bf16(a1[kk], bl, acc[1][n], 0, 0, 0);
            }
        }
}

// Split-A variant: acc += ah@W + al@W (+ ah@Wlo when NS==2)
template<int NS>
__device__ __forceinline__ void mfma_panel_split(const u16* Wbuf,
    const bf16x8* a0h, const bf16x8* a0l, const bf16x8* a1h, const bf16x8* a1l,
    int l15, int lg, f32x4 acc[][8])
{
#pragma unroll
    for (int kk = 0; kk < 4; kk++)
#pragma unroll
        for (int n = 0; n < 8; n++) {
            const int rw = n * 16 + l15, kb = kk * 64 + lg * 16;
            const bf16x8 b = ld_w(Wbuf, 0, rw, kb);
            acc[0][n] = __builtin_amdgcn_mfma_f32_16x16x32_bf16(a0h[kk], b, acc[0][n], 0, 0, 0);
            acc[0][n] = __builtin_amdgcn_mfma_f32_16x16x32_bf16(a0l[kk], b, acc[0][n], 0, 0, 0);
            acc[1][n] = __builtin_amdgcn_mfma_f32_16x16x32_bf16(a1h[kk], b, acc[1][n], 0, 0, 0);
            acc[1][n] = __builtin_amdgcn_mfma_f32_16x16x32_bf16(a1l[kk], b, acc[1][n], 0, 0, 0);
            if (NS == 2) {
                const bf16x8 bl = ld_w(Wbuf, 1, rw, kb);
                acc[0][n] = __builtin_amdgcn_mfma_f32_16x16x32_bf16(a0h[kk], bl, acc[0][n], 0, 0, 0);
                acc[1][n] = __builtin_amdgcn_mfma_f32_16x16x32_bf16(a1h[kk], bl, acc[1][n], 0, 0, 0);
            }
        }
}

__device__ __forceinline__ void splitf8(const float* p, bf16x8* hi, bf16x8* lo)
{
    const float4 f0 = *(const float4*)p;
    const float4 f1 = *(const float4*)(p + 4);
    const float f[8] = {f0.x, f0.y, f0.z, f0.w, f1.x, f1.y, f1.z, f1.w};
    union { u16 s[8]; bf16x8 v; } H, L;
#pragma unroll
    for (int j = 0; j < 8; j++) {
        const u16 hv = f2bf(f[j]);
        H.s[j] = hv;
        L.s[j] = f2bf(f[j] - bf2f(hv));
    }
    *hi = H.v; *lo = L.v;
}

// =====================================================================
// Staged-weight MFMA GEMM (bf16 A): C[M x 128] = A[M x K] @ W.
// 128-row blocks, 256 threads, 4 waves x 32 rows, 2 blocks/CU.
// want < 0: always run; else gated on dtype flag.
// =====================================================================
template<int NS, int KCH, bool OUT_BF16, bool ADD>
__global__ __launch_bounds__(256, 2) void sgemm_bf(
    const int* __restrict__ flag, int want,
    const u16* __restrict__ A, int lda,
    const u16* __restrict__ WHi, const u16* __restrict__ WLo,
    int wstride, int wcstep,
    void* __restrict__ Cv, int ldc)
{
    if (want >= 0 && *flag != want) return;
    __shared__ __align__(16) u16 Wbuf[NS * 16384];
    const int tid = threadIdx.x;
    const int lane = tid & 63, wv = tid >> 6;
    const int l15 = lane & 15, lg = lane >> 4;
    const long long row0 = (long long)blockIdx.x * 128 + wv * 32;

    f32x4 acc[2][8];
    {
        f32x4 z = {0.f, 0.f, 0.f, 0.f};
#pragma unroll
        for (int m = 0; m < 2; m++)
#pragma unroll
            for (int n = 0; n < 8; n++) acc[m][n] = z;
    }

    const u16* A0 = A + (row0 + l15) * (long long)lda + lg * 8;
    const u16* A1 = A0 + 16LL * lda;

    stage_async<NS, 256>(Wbuf, WHi, WLo, wstride, tid);
    for (int ks = 0; ks < KCH; ks++) {
        bf16x8 a0[4], a1[4];
#pragma unroll
        for (int kk = 0; kk < 4; kk++) {
            a0[kk] = *(const bf16x8*)(A0 + ks * 128 + kk * 32);
            a1[kk] = *(const bf16x8*)(A1 + ks * 128 + kk * 32);
        }
        __syncthreads();                       // panel staged (vmcnt drained)
        mfma_panel<NS>(Wbuf, a0, a1, l15, lg, acc);
        if (ks + 1 < KCH) {
            __syncthreads();                   // panel reads done before restage
            stage_async<NS, 256>(Wbuf, WHi + (ks + 1) * wcstep,
                                 WLo + (ks + 1) * wcstep, wstride, tid);
        }
    }

#pragma unroll
    for (int m = 0; m < 2; m++)
#pragma unroll
        for (int r = 0; r < 4; r++) {
            const long long row = row0 + m * 16 + lg * 4 + r;
            if (OUT_BF16) {
                u16* C = (u16*)Cv + row * ldc;
#pragma unroll
                for (int n = 0; n < 8; n++) C[n * 16 + l15] = f2bf(acc[m][n][r]);
            } else {
                float* C = (float*)Cv + row * ldc;
#pragma unroll
                for (int n = 0; n < 8; n++) {
                    float v = acc[m][n][r];
                    if (ADD) v += C[n * 16 + l15];
                    C[n * 16 + l15] = v;
                }
            }
        }
}

// =====================================================================
// Staged-weight MFMA GEMM (f32 A, split in-kernel into hi+lo bf16).
// OM: 0 = f32 store, 1 = bf16 store, 2 = d_out store by *flag
//     (bf16 if flag, else f32 = bf2f(f2bf(v)) to keep bits identical).
// =====================================================================
template<int NS, int KCH, int OM>
__global__ __launch_bounds__(256, 2) void sgemm_f32(
    const int* __restrict__ flag, int want,
    const float* __restrict__ A, int lda,
    const u16* __restrict__ WHi, const u16* __restrict__ WLo,
    int wstride, int wcstep,
    void* __restrict__ Cv, int ldc)
{
    if (want >= 0 && *flag != want) return;
    __shared__ __align__(16) u16 Wbuf[NS * 16384];
    const int tid = threadIdx.x;
    const int lane = tid & 63, wv = tid >> 6;
    const int l15 = lane & 15, lg = lane >> 4;
    const long long row0 = (long long)blockIdx.x * 128 + wv * 32;

    f32x4 acc[2][8];
    {
        f32x4 z = {0.f, 0.f, 0.f, 0.f};
#pragma unroll
        for (int m = 0; m < 2; m++)
#pragma unroll
            for (int n = 0; n < 8; n++) acc[m][n] = z;
    }

    const float* A0 = A + (row0 + l15) * (long long)lda + lg * 8;
    const float* A1 = A0 + 16LL * lda;

    stage_async<NS, 256>(Wbuf, WHi, WLo, wstride, tid);
    for (int ks = 0; ks < KCH; ks++) {
        bf16x8 a0h[4], a0l[4], a1h[4], a1l[4];
#pragma unroll
        for (int kk = 0; kk < 4; kk++) {
            splitf8(A0 + ks * 128 + kk * 32, &a0h[kk], &a0l[kk]);
            splitf8(A1 + ks * 128 + kk * 32, &a1h[kk], &a1l[kk]);
        }
        __syncthreads();
        mfma_panel_split<NS>(Wbuf, a0h, a0l, a1h, a1l, l15, lg, acc);
        if (ks + 1 < KCH) {
            __syncthreads();
            stage_async<NS, 256>(Wbuf, WHi + (ks + 1) * wcstep,
                                 WLo + (ks + 1) * wcstep, wstride, tid);
        }
    }

    const bool asbf = (OM == 2) ? (*flag != 0) : (OM == 1);
#pragma unroll
    for (int m = 0; m < 2; m++)
#pragma unroll
        for (int r = 0; r < 4; r++) {
            const long long row = row0 + m * 16 + lg * 4 + r;
            if (OM == 0) {
                float* C = (float*)Cv + row * ldc;
#pragma unroll
                for (int n = 0; n < 8; n++) C[n * 16 + l15] = acc[m][n][r];
            } else if (asbf) {
                u16* C = (u16*)Cv + row * ldc;
#pragma unroll
                for (int n = 0; n < 8; n++) C[n * 16 + l15] = f2bf(acc[m][n][r]);
            } else {
                float* C = (float*)Cv + row * ldc;
#pragma unroll
                for (int n = 0; n < 8; n++)
                    C[n * 16 + l15] = bf2f(f2bf(acc[m][n][r]));
            }
        }
}

// =====================================================================
// O-projection + residual + fused LN2: x += ob@Wo; h = LN(x)*g+b.
// 128-row blocks, 256 threads; each wave holds full 128-wide rows, so
// LN reduce = 8 local adds + shfl_xor(1,2,4,8) over the l15 group.
// =====================================================================
__global__ __launch_bounds__(256, 2) void sgemm_add_ln(
    const u16* __restrict__ A,
    const u16* __restrict__ WHi, const u16* __restrict__ WLo,
    float* __restrict__ x, const float* __restrict__ g,
    const float* __restrict__ bvec, u16* __restrict__ h)
{
    __shared__ __align__(16) u16 Wbuf[2 * 16384];
    const int tid = threadIdx.x;
    const int lane = tid & 63, wv = tid >> 6;
    const int l15 = lane & 15, lg = lane >> 4;
    const long long row0 = (long long)blockIdx.x * 128 + wv * 32;

    f32x4 acc[2][8];
    {
        f32x4 z = {0.f, 0.f, 0.f, 0.f};
#pragma unroll
        for (int m = 0; m < 2; m++)
#pragma unroll
            for (int n = 0; n < 8; n++) acc[m][n] = z;
    }

    const u16* A0 = A + (row0 + l15) * 128LL + lg * 8;
    const u16* A1 = A0 + 16LL * 128;

    stage_async<2, 256>(Wbuf, WHi, WLo, 128, tid);
    bf16x8 a0[4], a1[4];
#pragma unroll
    for (int kk = 0; kk < 4; kk++) {
        a0[kk] = *(const bf16x8*)(A0 + kk * 32);
        a1[kk] = *(const bf16x8*)(A1 + kk * 32);
    }
    __syncthreads();
    mfma_panel<2>(Wbuf, a0, a1, l15, lg, acc);

    float gv[8], bv[8];
#pragma unroll
    for (int n = 0; n < 8; n++) { gv[n] = g[n * 16 + l15]; bv[n] = bvec[n * 16 + l15]; }

#pragma unroll
    for (int m = 0; m < 2; m++)
#pragma unroll
        for (int r = 0; r < 4; r++) {
            const long long row = row0 + m * 16 + lg * 4 + r;
            float* X = x + row * CA;
            float v[8]; float s = 0.f, sq = 0.f;
#pragma unroll
            for (int n = 0; n < 8; n++) {
                v[n] = X[n * 16 + l15] + acc[m][n][r];
                X[n * 16 + l15] = v[n];
                s += v[n]; sq += v[n] * v[n];
            }
            s  += __shfl_xor(s, 1, 64);  s  += __shfl_xor(s, 2, 64);
            s  += __shfl_xor(s, 4, 64);  s  += __shfl_xor(s, 8, 64);
            sq += __shfl_xor(sq, 1, 64); sq += __shfl_xor(sq, 2, 64);
            sq += __shfl_xor(sq, 4, 64); sq += __shfl_xor(sq, 8, 64);
            const float mean = s * 0.0078125f;
            const float var  = sq * 0.0078125f - mean * mean;
            const float inv  = rsqrtf(var + 1e-5f);
            u16* H = h + row * CA;
#pragma unroll
            for (int n = 0; n < 8; n++)
                H[n * 16 + l15] = f2bf((v[n] - mean) * inv * gv[n] + bv[n]);
        }
}

// =====================================================================
// Fused QKV (512 thr, 256 rows/block): ping-pong two panel buffers;
// next panel's async loads issue before this panel's MFMA.
// =====================================================================
__global__ __launch_bounds__(512, 1) void qkv_fused(
    const u16* __restrict__ h, const u16* __restrict__ wl,
    u16* __restrict__ qb, u16* __restrict__ kb, u16* __restrict__ vb)
{
    __shared__ __align__(16) u16 bufA[2 * 16384];
    __shared__ __align__(16) u16 bufB[2 * 16384];
    const int tid = threadIdx.x;
    const int lane = tid & 63, wv = tid >> 6;
    const int l15 = lane & 15, lg = lane >> 4;
    const long long row0 = (long long)blockIdx.x * 256 + wv * 32;

    bf16x8 a0[4], a1[4];
#pragma unroll
    for (int kk = 0; kk < 4; kk++) {
        a0[kk] = *(const bf16x8*)(h + (row0 + l15) * 128 + kk * 32 + lg * 8);
        a1[kk] = *(const bf16x8*)(h + (row0 + 16 + l15) * 128 + kk * 32 + lg * 8);
    }

    stage_async<2, 512>(bufA, wl, wl + 16384, 128, tid);          // Q
    __syncthreads();

#pragma unroll
    for (int m = 0; m < 3; m++) {
        if (m < 2)   // prefetch next panel
            stage_async<2, 512>((m == 0) ? bufB : bufA,
                                wl + (m + 1) * 32768,
                                wl + (m + 1) * 32768 + 16384, 128, tid);
        f32x4 acc[2][8];
        {
            f32x4 z = {0.f, 0.f, 0.f, 0.f};
#pragma unroll
            for (int i = 0; i < 2; i++)
#pragma unroll
                for (int n = 0; n < 8; n++) acc[i][n] = z;
        }
        const u16* cur = (m == 1) ? bufB : bufA;   // Q:A, K:B, V:A
        mfma_panel<2>(cur, a0, a1, l15, lg, acc);
        u16* out = (m == 0) ? qb : (m == 1) ? kb : vb;
#pragma unroll
        for (int i = 0; i < 2; i++)
#pragma unroll
            for (int r = 0; r < 4; r++) {
                u16* C = out + (row0 + i * 16 + lg * 4 + r) * CA;
#pragma unroll
                for (int n = 0; n < 8; n++) C[n * 16 + l15] = f2bf(acc[i][n][r]);
            }
        if (m < 2) __syncthreads();   // drains prefetch; cur reads done
    }
}

// =====================================================================
// Fused MLP + residual + next-layer LN1 (512 thr, 256 rows/block):
// x += relu(h @ Wt1) @ Wt2; h_out = LN(x)*g+b (EMIT_H).
// Two weight buffers, async staging; hidden transpose via per-wave
// 32x80B quarter buffer (wave-local waits). LDS 148 KB.
// =====================================================================
template<bool EMIT_H>
__global__ __launch_bounds__(512, 1) void mlp_ln(
    const u16* __restrict__ h,
    const u16* __restrict__ W1T, const u16* __restrict__ W2T,
    float* __restrict__ x, const float* __restrict__ g,
    const float* __restrict__ bvec, u16* __restrict__ hout)
{
    __shared__ __align__(16) u16 W1buf[2 * 16384];
    __shared__ __align__(16) u16 W2buf[2 * 16384];
    __shared__ __align__(16) u16 Plq[8][32][40];   // per-wave 32 rows x 80 B
    const int tid = threadIdx.x;
    const int lane = tid & 63, wv = tid >> 6;
    const int l15 = lane & 15, lg = lane >> 4;
    const long long row0 = (long long)blockIdx.x * 256 + wv * 32;
    u16* pw = &Plq[wv][0][0];

    bf16x8 ah0[4], ah1[4];
#pragma unroll
    for (int kk = 0; kk < 4; kk++) {
        ah0[kk] = *(const bf16x8*)(h + (row0 + l15) * 128 + kk * 32 + lg * 8);
        ah1[kk] = *(const bf16x8*)(h + (row0 + 16 + l15) * 128 + kk * 32 + lg * 8);
    }

    f32x4 xacc[2][8];
    {
        f32x4 z = {0.f, 0.f, 0.f, 0.f};
#pragma unroll
        for (int m = 0; m < 2; m++)
#pragma unroll
            for (int n = 0; n < 8; n++) xacc[m][n] = z;
    }

    stage_async<2, 512>(W1buf, W1T, W1T + 65536, 128, tid);
    __syncthreads();

    for (int c = 0; c < 4; c++) {
        // ---- W1 phase: issue W2c loads, MFMA W1 under them ----
        stage_async<2, 512>(W2buf, W2T + c * 128, W2T + 65536 + c * 128, 512, tid);
        f32x4 hacc[2][8];
        {
            f32x4 z = {0.f, 0.f, 0.f, 0.f};
#pragma unroll
            for (int m = 0; m < 2; m++)
#pragma unroll
                for (int n = 0; n < 8; n++) hacc[m][n] = z;
        }
        mfma_panel<2>(W1buf, ah0, ah1, l15, lg, hacc);
        __syncthreads();                 // W2buf staged; all waves done W1 reads

        // ---- W2 phase: issue W1(c+1) loads, quarters + MFMA W2 ----
        if (c < 3)
            stage_async<2, 512>(W1buf, W1T + (c + 1) * 16384,
                                W1T + 65536 + (c + 1) * 16384, 128, tid);
#pragma unroll
        for (int q = 0; q < 4; q++) {
            asm volatile("s_waitcnt lgkmcnt(0)" ::: "memory");
#pragma unroll
            for (int m = 0; m < 2; m++)
#pragma unroll
                for (int j = 0; j < 2; j++)
#pragma unroll
                    for (int r = 0; r < 4; r++)
                        pw[(m * 16 + lg * 4 + r) * 40 + j * 16 + l15]
                            = f2bf(fmaxf(hacc[m][2 * q + j][r], 0.f));
            asm volatile("s_waitcnt lgkmcnt(0)" ::: "memory");
            union { uint4 v; bf16x8 b; } t0, t1;
            t0.v = *(const uint4*)(pw + l15 * 40 + lg * 8);
            t1.v = *(const uint4*)(pw + (16 + l15) * 40 + lg * 8);
#pragma unroll
            for (int n = 0; n < 8; n++) {
                const int rw = n * 16 + l15, kb = q * 64 + lg * 16;
                const bf16x8 b = ld_w(W2buf, 0, rw, kb);
                xacc[0][n] = __builtin_amdgcn_mfma_f32_16x16x32_bf16(t0.b, b, xacc[0][n], 0, 0, 0);
                xacc[1][n] = __builtin_amdgcn_mfma_f32_16x16x32_bf16(t1.b, b, xacc[1][n], 0, 0, 0);
                const bf16x8 bl = ld_w(W2buf, 1, rw, kb);
                xacc[0][n] = __builtin_amdgcn_mfma_f32_16x16x32_bf16(t0.b, bl, xacc[0][n], 0, 0, 0);
                xacc[1][n] = __builtin_amdgcn_mfma_f32_16x16x32_bf16(t1.b, bl, xacc[1][n], 0, 0, 0);
            }
        }
        if (c < 3) __syncthreads();      // W1buf(c+1) staged; W2buf reads done
    }

    float gv[8], bv[8];
    if (EMIT_H) {
#pragma unroll
        for (int n = 0; n < 8; n++) { gv[n] = g[n * 16 + l15]; bv[n] = bvec[n * 16 + l15]; }
    }

#pragma unroll
    for (int m = 0; m < 2; m++)
#pragma unroll
        for (int r = 0; r < 4; r++) {
            const long long row = row0 + m * 16 + lg * 4 + r;
            float* X = x + row * CA;
            float v[8]; float s = 0.f, sq = 0.f;
#pragma unroll
            for (int n = 0; n < 8; n++) {
                v[n] = X[n * 16 + l15] + xacc[m][n][r];
                X[n * 16 + l15] = v[n];
                s += v[n]; sq += v[n] * v[n];
            }
            if (EMIT_H) {
                s  += __shfl_xor(s, 1, 64);  s  += __shfl_xor(s, 2, 64);
                s  += __shfl_xor(s, 4, 64);  s  += __shfl_xor(s, 8, 64);
                sq += __shfl_xor(sq, 1, 64); sq += __shfl_xor(sq, 2, 64);
                sq += __shfl_xor(sq, 4, 64); sq += __shfl_xor(sq, 8, 64);
                const float mean = s * 0.0078125f;
                const float var  = sq * 0.0078125f - mean * mean;
                const float inv  = rsqrtf(var + 1e-5f);
                u16* H = hout + row * CA;
#pragma unroll
                for (int n = 0; n < 8; n++)
                    H[n * 16 + l15] = f2bf((v[n] - mean) * inv * gv[n] + bv[n]);
            }
        }
}

// =====================================================================
// Gather + LN1 of layer 0: one wave per atom row.
// =====================================================================
__global__ __launch_bounds__(256) void gather_ln_kernel(
    const float* __restrict__ atok, const int* __restrict__ idx,
    const float* __restrict__ g, const float* __restrict__ bvec,
    float* __restrict__ x, u16* __restrict__ h)
{
    const int lane = threadIdx.x & 63;
    const int wv   = threadIdx.x >> 6;
    const size_t an = (size_t)blockIdx.x * 4 + wv;
    const int b = (int)(an >> 14);
    const int n = (int)(an & (NATOM - 1));
    const int t = idx[b * NATOM + n];
    const float* src = atok + ((size_t)b * NTOK + t) * CA;
    const float v0 = src[lane], v1 = src[lane + 64];
    float* xr = x + an * CA;
    xr[lane] = v0; xr[lane + 64] = v1;
    float s  = v0 + v1;
    float sq = v0 * v0 + v1 * v1;
#pragma unroll
    for (int off = 32; off > 0; off >>= 1) {
        s  += __shfl_xor(s,  off, 64);
        sq += __shfl_xor(sq, off, 64);
    }
    const float mean = s * 0.0078125f;
    const float var  = sq * 0.0078125f - mean * mean;
    const float inv  = rsqrtf(var + 1e-5f);
    u16* hr = h + an * CA;
    hr[lane]      = f2bf((v0 - mean) * inv * g[lane]      + bvec[lane]);
    hr[lane + 64] = f2bf((v1 - mean) * inv * g[lane + 64] + bvec[lane + 64]);
}

// =====================================================================
// Bias: t[b,a,h] for a < 128 from the pair-MLP (f32 aux weights).
// =====================================================================
__global__ __launch_bounds__(512) void bias_kernel(
    const float* __restrict__ x, const float* __restrict__ AX,
    float* __restrict__ tb)
{
    __shared__ float Wsum[128][16];
    __shared__ float M1[16][16];
    __shared__ float M2[16][16];
    __shared__ float Pb[16][4];
    const int tid = threadIdx.x;
    for (int i = tid; i < 128 * 16; i += 512)
        Wsum[i >> 4][i & 15] = AX[AX_WCL + i] + AX[AX_WCM + i];
    if (tid < 256) M1[tid >> 4][tid & 15] = AX[AX_WM1 + tid];
    if (tid >= 256 && tid < 512) { int t2 = tid - 256; M2[t2 >> 4][t2 & 15] = AX[AX_WM2 + t2]; }
    if (tid < 64) Pb[tid >> 2][tid & 3] = AX[AX_WPB + tid];
    __syncthreads();

    const int b = tid >> 7, a = tid & 127;
    const float* xa = x + ((size_t)b * NATOM + a) * CA;
    float u[16];
#pragma unroll
    for (int p = 0; p < 16; p++) u[p] = 0.f;
    for (int c = 0; c < 128; c++) {
        const float xv = xa[c];
#pragma unroll
        for (int p = 0; p < 16; p++) u[p] = fmaf(xv, Wsum[c][p], u[p]);
    }
    float r1[16];
#pragma unroll
    for (int p = 0; p < 16; p++) r1[p] = 0.f;
    for (int c = 0; c < 16; c++) {
        const float rv = fmaxf(u[c], 0.f);
#pragma unroll
        for (int p = 0; p < 16; p++) r1[p] = fmaf(rv, M1[c][p], r1[p]);
    }
    float r2[16];
#pragma unroll
    for (int p = 0; p < 16; p++) r2[p] = 0.f;
    for (int c = 0; c < 16; c++) {
        const float rv = fmaxf(r1[c], 0.f);
#pragma unroll
        for (int p = 0; p < 16; p++) r2[p] = fmaf(rv, M2[c][p], r2[p]);
    }
#pragma unroll
    for (int hh = 0; hh < 4; hh++) {
        float s = 0.f;
#pragma unroll
        for (int p = 0; p < 16; p++) s = fmaf(r2[p], Pb[p][hh], s);
        tb[(size_t)tid * 4 + hh] = s;
    }
}

// =====================================================================
// Windowed attention via MFMA (verified round 1): one block per (b, w).
// XCD-aware blockIdx swizzle (T1): nwg = 2048 = 8 XCDs x 256, so each
// XCD gets 256 CONSECUTIVE windows -> the 96/128-row K/V window overlap
// between neighbors becomes per-XCD L2 hits instead of HBM refetches.
// (HW-verified round 13: ~23 us total gain.)
// =====================================================================
#define VTP 132   // V^T row stride in u16
#define PPS 68    // P row stride in u16

__global__ __launch_bounds__(256) void attn_kernel(
    const u16* __restrict__ qg, const u16* __restrict__ kg,
    const u16* __restrict__ vg, const float* __restrict__ tb,
    u16* __restrict__ og)
{
    __shared__ __align__(16) u16 VT[128][VTP];    // V^T: [d][j]
    __shared__ __align__(16) u16 Pl[NH][32][PPS]; // per-head P half

    const int tid  = threadIdx.x;
    const int lane = tid & 63;
    const int h    = tid >> 6;             // wave id == head
    const int bw   = (blockIdx.x & 7) * (BB * NWIN / 8) + (blockIdx.x >> 3);
    const int b    = bw >> 9;
    const int w    = bw & (NWIN - 1);
    const int row0 = w * NQ;
    const int kbase = row0 - PAD;          // first key atom (may be < 0)
    const int l15 = lane & 15;
    const int lg  = lane >> 4;

    // ---- stage V^T into LDS (all 256 threads; zero invalid rows) ----
    {
        const int j  = tid & 127;
        const int d0 = (tid >> 7) << 6;    // 0 or 64
        const int ga = kbase + j;
        const bool val = (ga >= 0) && (ga < NATOM);
        const u16* vrow = vg + ((long long)b * NATOM + ga) * CA + d0;
#pragma unroll
        for (int t2 = 0; t2 < 8; t2++) {
            union { uint4 q; u16 s[8]; } u;
            if (val) u.q = *(const uint4*)(vrow + t2 * 8);
            else     u.q = make_uint4(0u, 0u, 0u, 0u);
#pragma unroll
            for (int e = 0; e < 8; e++) VT[d0 + t2 * 8 + e][j] = u.s[e];
        }
    }

    // ---- QK^T: S[32][128] per head, frags direct from global ----
    const long long qoff = ((long long)b * NATOM + row0) * CA + h * DH;
    const long long koff = ((long long)b * NATOM + kbase) * CA + h * DH;
    bf16x8 aq0 = *(const bf16x8*)(qg + qoff + (long long)l15 * CA + lg * 8);
    bf16x8 aq1 = *(const bf16x8*)(qg + qoff + (long long)(l15 + 16) * CA + lg * 8);

    f32x4 acc[2][8];
    {
        f32x4 z = {0.f, 0.f, 0.f, 0.f};
#pragma unroll
        for (int m = 0; m < 2; m++)
#pragma unroll
            for (int n = 0; n < 8; n++) acc[m][n] = z;
    }
#pragma unroll
    for (int n = 0; n < 8; n++) {
        bf16x8 bk = *(const bf16x8*)(kg + koff + (long long)(n * 16 + l15) * CA + lg * 8);
        acc[0][n] = __builtin_amdgcn_mfma_f32_16x16x32_bf16(aq0, bk, acc[0][n], 0, 0, 0);
        acc[1][n] = __builtin_amdgcn_mfma_f32_16x16x32_bf16(aq1, bk, acc[1][n], 0, 0, 0);
    }

    // ---- bias + scale + mask ----
    const float scale = 0.17677669529663687f;  // 1/sqrt(32)
    float tj[8], ti[2][4];
#pragma unroll
    for (int n = 0; n < 8; n++)
        tj[n] = tb[((size_t)b * 128 + n * 16 + l15) * 4 + h];
#pragma unroll
    for (int m = 0; m < 2; m++)
#pragma unroll
        for (int r = 0; r < 4; r++)
            ti[m][r] = tb[((size_t)b * 128 + m * 16 + lg * 4 + r) * 4 + h];

#pragma unroll
    for (int n = 0; n < 8; n++) {
        const int ga = kbase + n * 16 + l15;
        const bool val = (ga >= 0) && (ga < NATOM);
#pragma unroll
        for (int m = 0; m < 2; m++)
#pragma unroll
            for (int r = 0; r < 4; r++) {
                const float s = acc[m][n][r] * scale + ti[m][r] + tj[n];
                acc[m][n][r] = val ? s : -1e9f;
            }
    }

    // ---- softmax ----
    float mx[2][4], inv[2][4];
#pragma unroll
    for (int m = 0; m < 2; m++)
#pragma unroll
        for (int r = 0; r < 4; r++) {
            float v = acc[m][0][r];
#pragma unroll
            for (int n = 1; n < 8; n++) v = fmaxf(v, acc[m][n][r]);
            v = fmaxf(v, __shfl_xor(v, 1, 64));
            v = fmaxf(v, __shfl_xor(v, 2, 64));
            v = fmaxf(v, __shfl_xor(v, 4, 64));
            v = fmaxf(v, __shfl_xor(v, 8, 64));
            mx[m][r] = v;
        }
#pragma unroll
    for (int m = 0; m < 2; m++)
#pragma unroll
        for (int n = 0; n < 8; n++)
#pragma unroll
            for (int r = 0; r < 4; r++)
                acc[m][n][r] = __expf(acc[m][n][r] - mx[m][r]);
#pragma unroll
    for (int m = 0; m < 2; m++)
#pragma unroll
        for (int r = 0; r < 4; r++) {
            float v = 0.f;
#pragma unroll
            for (int n = 0; n < 8; n++) v += acc[m][n][r];
            v += __shfl_xor(v, 1, 64);
            v += __shfl_xor(v, 2, 64);
            v += __shfl_xor(v, 4, 64);
            v += __shfl_xor(v, 8, 64);
            inv[m][r] = 1.0f / v;
        }

    __syncthreads();   // V^T staged

    // ---- PV ----
    f32x4 o[2][2];
    {
        f32x4 z = {0.f, 0.f, 0.f, 0.f};
        o[0][0] = z; o[0][1] = z; o[1][0] = z; o[1][1] = z;
    }
    union B8 { bf16x8 v; uint2 u[2]; };
#pragma unroll
    for (int half = 0; half < 2; half++) {
        asm volatile("s_waitcnt lgkmcnt(0)" ::: "memory");
#pragma unroll
        for (int m = 0; m < 2; m++)
#pragma unroll
            for (int nn = 0; nn < 4; nn++)
#pragma unroll
                for (int r = 0; r < 4; r++)
                    Pl[h][m * 16 + lg * 4 + r][nn * 16 + l15]
                        = f2bf(acc[m][half * 4 + nn][r]);
        asm volatile("s_waitcnt lgkmcnt(0)" ::: "memory");
#pragma unroll
        for (int ks2 = 0; ks2 < 2; ks2++) {
            const int jo = ks2 * 32 + lg * 8;
            const int jg = half * 64 + jo;
            B8 pa0, pa1, vb0, vb1;
            pa0.u[0] = *(const uint2*)&Pl[h][l15][jo];
            pa0.u[1] = *(const uint2*)&Pl[h][l15][jo + 4];
            pa1.u[0] = *(const uint2*)&Pl[h][l15 + 16][jo];
            pa1.u[1] = *(const uint2*)&Pl[h][l15 + 16][jo + 4];
            vb0.u[0] = *(const uint2*)&VT[h * DH + l15][jg];
            vb0.u[1] = *(const uint2*)&VT[h * DH + l15][jg + 4];
            vb1.u[0] = *(const uint2*)&VT[h * DH + 16 + l15][jg];
            vb1.u[1] = *(const uint2*)&VT[h * DH + 16 + l15][jg + 4];
            o[0][0] = __builtin_amdgcn_mfma_f32_16x16x32_bf16(pa0.v, vb0.v, o[0][0], 0, 0, 0);
            o[0][1] = __builtin_amdgcn_mfma_f32_16x16x32_bf16(pa0.v, vb1.v, o[0][1], 0, 0, 0);
            o[1][0] = __builtin_amdgcn_mfma_f32_16x16x32_bf16(pa1.v, vb0.v, o[1][0], 0, 0, 0);
            o[1][1] = __builtin_amdgcn_mfma_f32_16x16x32_bf16(pa1.v, vb1.v, o[1][1], 0, 0, 0);
        }
    }

#pragma unroll
    for (int m = 0; m < 2; m++)
#pragma unroll
        for (int n = 0; n < 2; n++)
#pragma unroll
            for (int r = 0; r < 4; r++)
                og[((long long)b * NATOM + row0 + m * 16 + lg * 4 + r) * CA
                   + h * DH + n * 16 + l15]
                    = f2bf(o[m][n][r] * inv[m][r]);
}

// =====================================================================
// Launch — single dtype-independent pipeline; only wtrans + token
// projection are flag-gated pairs.  Final GEMM writes d_out directly.
// =====================================================================
extern "C" void kernel_launch(void* const* d_in, const int* in_sizes, int n_in,
                              void* d_out, int out_size, void* d_ws, size_t ws_size,
                              hipStream_t stream)
{
    (void)in_sizes; (void)n_in; (void)out_size;
    const size_t NEL = (size_t)BB * NATOM * CA;   // 8388608

    char* p = (char*)d_ws;
    float* x    = (float*)p;  p += NEL * 4;
    u16*   h    = (u16*)p;    p += NEL * 2;
    u16*   qb   = (u16*)p;    p += NEL * 2;
    u16*   kb   = (u16*)p;    p += NEL * 2;
    u16*   vb   = (u16*)p;    p += NEL * 2;
    u16*   ob   = (u16*)p;    p += NEL * 2;
    float* atok = (float*)p;  p += (size_t)BB * NTOK * CA * 4;
    float* tbv  = (float*)p;  p += 8192;
    int*   flag = (int*)p;    p += 256;
    u16*   wt   = (u16*)p;    p += (size_t)WT_TOT * 2;
    float* aux  = (float*)p;  p += AX_TOT * 4;
    if ((size_t)(p - (char*)d_ws) > ws_size) return;  // workspace too small

    // 1) detect input storage dtype (writes flag: 1=bf16, 0=f32)
    detect_kernel<<<1, 256, 0, stream>>>((const u32*)d_in[3], flag);

    // 2) weight preprocessing (gated pair; exactly one runs)
    wtrans_kernel<u16><<<41, 256, 0, stream>>>(
        flag, 1, (const u16*)d_in[3], (const u16*)d_in[10], (const u16*)d_in[11],
        (const u16*)d_in[12], (const u16*)d_in[13], (const u16*)d_in[16],
        (const u16*)d_in[17], (const u16*)d_in[4], (const u16*)d_in[5],
        (const u16*)d_in[6], (const u16*)d_in[7], (const u16*)d_in[8],
        (const u16*)d_in[9], (const u16*)d_in[14], (const u16*)d_in[15],
        (const u16*)d_in[18], (const u16*)d_in[19], wt, aux);
    wtrans_kernel<float><<<41, 256, 0, stream>>>(
        flag, 0, (const float*)d_in[3], (const float*)d_in[10], (const float*)d_in[11],
        (const float*)d_in[12], (const float*)d_in[13], (const float*)d_in[16],
        (const float*)d_in[17], (const float*)d_in[4], (const float*)d_in[5],
        (const float*)d_in[6], (const float*)d_in[7], (const float*)d_in[8],
        (const float*)d_in[9], (const float*)d_in[14], (const float*)d_in[15],
        (const float*)d_in[18], (const float*)d_in[19], wt, aux);

    // 3) token projection (gated pair)
    sgemm_bf<1, 3, false, false><<<BB * NTOK / 128, 256, 0, stream>>>(
        flag, 1, (const u16*)d_in[0], CTOK, wt + WT_WA, wt + WT_WA + 49152,
        CTOK, 128, atok, CA);
    sgemm_f32<2, 3, 0><<<BB * NTOK / 128, 256, 0, stream>>>(
        flag, 0, (const float*)d_in[0], CTOK, wt + WT_WA, wt + WT_WA + 49152,
        CTOK, 128, atok, CA);

    // 4) gather + layer-0 LN1
    gather_ln_kernel<<<BB * NATOM / 4, 256, 0, stream>>>(
        atok, (const int*)d_in[2], aux + AX_L1G, aux + AX_L1B, x, h);
    bias_kernel<<<1, 512, 0, stream>>>(x, aux, tbv);

    // 5) layers
    for (int l = 0; l < 3; l++) {
        u16* wl = wt + WT_L0 + (size_t)l * WT_LSZ;
        qkv_fused<<<256, 512, 0, stream>>>(h, wl, qb, kb, vb);
        attn_kernel<<<BB * NWIN, 256, 0, stream>>>(qb, kb, vb, tbv, ob);
        sgemm_add_ln<<<512, 256, 0, stream>>>(
            ob, wl + 98304, wl + 98304 + 16384, x,
            aux + AX_L2G + l * 128, aux + AX_L2B + l * 128, h);
        if (l < 2)
            mlp_ln<true><<<256, 512, 0, stream>>>(
                h, wl + 131072, wl + 262144, x,
                aux + AX_L1G + (l + 1) * 128, aux + AX_L1B + (l + 1) * 128, h);
        else
            mlp_ln<false><<<256, 512, 0, stream>>>(
                h, wl + 131072, wl + 262144, x, aux, aux, h);
    }

    // 6) out = x @ W_out -> d_out directly, format by flag (always runs)
    sgemm_f32<2, 1, 2><<<512, 256, 0, stream>>>(
        flag, -1, x, CA, wt + WT_WO, wt + WT_WO + 16384, CA, 0, d_out, CA);
}

// Round 15
// 532.439 us; speedup vs baseline: 1.1417x; 1.0110x over previous
//
#include <hip/hip_runtime.h>

typedef unsigned short u16;
typedef unsigned int   u32;

typedef __attribute__((ext_vector_type(8))) __bf16 bf16x8;
typedef __attribute__((ext_vector_type(4))) float  f32x4;

// ---------- scalar/vec conversion helpers ----------
__device__ __forceinline__ float bf2f(u16 v) {
    return __uint_as_float(((u32)v) << 16);
}
__device__ __forceinline__ u16 f2bf(float f) {
    u32 u = __float_as_uint(f);
    u32 r = (u + 0x7fffu + ((u >> 16) & 1u)) >> 16;  // round-to-nearest-even
    return (u16)r;
}
__device__ __forceinline__ float ld1(const u16* p)   { return bf2f(*p); }
__device__ __forceinline__ float ld1(const float* p) { return *p; }

// ---------- problem constants ----------
#define BB 4
#define NTOK 2048
#define NATOM 16384
#define CTOK 384
#define CA 128
#define NQ 32
#define NK 128
#define NH 4
#define DH 32
#define NWIN 512
#define PAD 48

// Transposed-weight workspace layout (u16 elements).
// Each matrix stored as [N][K] hi-plane, then lo-plane (lo = 0 for bf16 input).
#define WT_WA   0          // [128][384], lo plane at +49152
#define WT_L0   98304      // per-layer block start
#define WT_LSZ  393216     // Q 0 | K 32768 | V 65536 | O 98304 | T1 131072 | T2 262144
#define WT_WO   1277952    // [128][128], lo plane at +16384
#define WT_TOT  1310720

// Aux f32 scratch layout (floats)
#define AX_WCL  0
#define AX_WCM  2048
#define AX_WM1  4096
#define AX_WM2  4352
#define AX_WPB  4608
#define AX_L1G  4672
#define AX_L1B  5056
#define AX_L2G  5440
#define AX_L2B  5824
#define AX_TOT  6208

// =====================================================================
// dtype detector: look at low u16 of 1024 words of W_a.
// flag = 1 (bf16 inputs) or 0 (f32 inputs)
// =====================================================================
__global__ __launch_bounds__(256) void detect_kernel(const u32* __restrict__ wa,
                                                     int* __restrict__ flag)
{
    __shared__ int cnt;
    if (threadIdx.x == 0) cnt = 0;
    __syncthreads();
    int local = 0;
#pragma unroll
    for (int i = 0; i < 4; i++) {
        u32 w = wa[threadIdx.x * 4 + i];
        u32 e = (w >> 7) & 0xFFu;   // exponent field of the LOW u16 as bf16
        if (e >= 95u && e <= 135u) local++;
    }
    atomicAdd(&cnt, local);
    __syncthreads();
    if (threadIdx.x == 0) *flag = (cnt >= 614) ? 1 : 0;
}

// =====================================================================
// Weight transpose + bf16 hi/lo split into WT workspace, plus f32 aux
// conversion.  41 blocks; gated on dtype flag.
// =====================================================================
template<typename TIN>
__global__ __launch_bounds__(256) void wtrans_kernel(
    const int* __restrict__ flag, int want,
    const TIN* __restrict__ Wa, const TIN* __restrict__ Wq,
    const TIN* __restrict__ Wk, const TIN* __restrict__ Wv,
    const TIN* __restrict__ Wo, const TIN* __restrict__ Wt1,
    const TIN* __restrict__ Wt2, const TIN* __restrict__ Wout,
    const TIN* __restrict__ Wcl, const TIN* __restrict__ Wcm,
    const TIN* __restrict__ Wm1, const TIN* __restrict__ Wm2,
    const TIN* __restrict__ Wpb, const TIN* __restrict__ l1g,
    const TIN* __restrict__ l1b, const TIN* __restrict__ l2g,
    const TIN* __restrict__ l2b,
    u16* __restrict__ WT, float* __restrict__ AX)
{
    if (*flag != want) return;
    const int t = blockIdx.x;
    const int tid = threadIdx.x;
    if (t == 40) {   // aux f32 conversion
        for (int i = tid; i < 2048; i += 256) AX[AX_WCL + i] = ld1(Wcl + i);
        for (int i = tid; i < 2048; i += 256) AX[AX_WCM + i] = ld1(Wcm + i);
        AX[AX_WM1 + tid] = ld1(Wm1 + tid);
        AX[AX_WM2 + tid] = ld1(Wm2 + tid);
        if (tid < 64) AX[AX_WPB + tid] = ld1(Wpb + tid);
        for (int i = tid; i < 384; i += 256) {
            AX[AX_L1G + i] = ld1(l1g + i);
            AX[AX_L1B + i] = ld1(l1b + i);
            AX[AX_L2G + i] = ld1(l2g + i);
            AX[AX_L2B + i] = ld1(l2b + i);
        }
        return;
    }
    const TIN* S; int sld; u16* D; int dld; int plane;
    if (t < 3) {                                     // W_a [384][128]
        S = Wa + t * 128 * 128; sld = 128;
        D = WT + WT_WA + t * 128; dld = 384; plane = 49152;
    } else if (t < 15) {                             // Wq/k/v/o [128][128]
        const int i = t - 3, l = i >> 2, m = i & 3;
        const TIN* ms = (m == 0) ? Wq : (m == 1) ? Wk : (m == 2) ? Wv : Wo;
        S = ms + l * 16384; sld = 128;
        D = WT + WT_L0 + l * WT_LSZ + m * 32768; dld = 128; plane = 16384;
    } else if (t < 27) {                             // Wt1 [128][512] col-chunk c
        const int i = t - 15, l = i >> 2, c = i & 3;
        S = Wt1 + l * 65536 + c * 128; sld = 512;
        D = WT + WT_L0 + l * WT_LSZ + 131072 + c * 128 * 128; dld = 128; plane = 65536;
    } else if (t < 39) {                             // Wt2 [512][128] row-chunk c
        const int i = t - 27, l = i >> 2, c = i & 3;
        S = Wt2 + l * 65536 + c * 128 * 128; sld = 128;
        D = WT + WT_L0 + l * WT_LSZ + 262144 + c * 128; dld = 512; plane = 65536;
    } else {                                         // W_out [128][128]
        S = Wout; sld = 128;
        D = WT + WT_WO; dld = 128; plane = 16384;
    }
    for (int id = tid; id < 2048; id += 256) {
        const int n = id >> 4, k0 = (id & 15) << 3;
        union { u16 s[8]; uint4 v; } hi, lo;
#pragma unroll
        for (int j = 0; j < 8; j++) {
            if constexpr (sizeof(TIN) == 2) {
                hi.s[j] = ((const u16*)(const void*)S)[(k0 + j) * sld + n];
                lo.s[j] = 0;
            } else {
                const float v = ((const float*)(const void*)S)[(k0 + j) * sld + n];
                const u16 hv = f2bf(v);
                hi.s[j] = hv;
                lo.s[j] = f2bf(v - bf2f(hv));
            }
        }
        *(uint4*)(D + n * dld + k0) = hi.v;
        *(uint4*)(D + plane + n * dld + k0) = lo.v;
    }
}

// =====================================================================
// Async weight-panel staging via global_load_lds (no staging VGPRs).
// LDS image: [plane][128 rows][256 B] LINEAR in segment order; the XOR
// swizzle byte^((row&7)<<4) is applied to the per-lane GLOBAL source
// (inverse-swz source + swz read = both-sides rule).
// (row&7: 2-way LDS aliasing is ~free; round-13 A/B showed row&15 cost
//  ~8% HBM traffic on mlp_ln for no time gain.)
// =====================================================================
__device__ __forceinline__ void gld16(const void* g, void* l)
{
    __builtin_amdgcn_global_load_lds(
        (const __attribute__((address_space(1))) void*)g,
        (__attribute__((address_space(3))) void*)l, 16, 0, 0);
}

template<int NS, int NTHR>
__device__ __forceinline__ void stage_async(u16* lds, const u16* srcHi,
                                            const u16* srcLo, int strideU16, int tid)
{
    constexpr int NWAVE = NTHR / 64;
    constexpr int NSEG  = NS * 32768 / (NWAVE * 1024);
    const int lane = tid & 63;
    const int wv   = tid >> 6;
#pragma unroll
    for (int i = 0; i < NSEG; i++) {
        const int segoff  = (wv * NSEG + i) << 10;      // byte, wave-uniform
        const int po_full = segoff + lane * 16;
        const int plane   = po_full >> 15;
        const int po      = po_full & 32767;
        const int row     = po >> 8;
        const int colB    = (po & 255) ^ ((row & 7) << 4);
        const u16* g = (plane ? srcLo : srcHi) + row * strideU16 + (colB >> 1);
        gld16(g, (char*)lds + segoff);
    }
}

__device__ __forceinline__ bf16x8 ld_w(const u16* lds, int plane, int row, int kbyte)
{
    union { uint4 q; bf16x8 v; } u;
    u.q = *(const uint4*)((const char*)lds + plane * 32768 + row * 256
                          + (kbyte ^ ((row & 7) << 4)));
    return u.v;
}

// MFMA over one staged panel: acc[2][8] += a{0,1}[kk] @ W(+lo)
template<int NS>
__device__ __forceinline__ void mfma_panel(const u16* Wbuf, const bf16x8* a0,
                                           const bf16x8* a1, int l15, int lg,
                                           f32x4 acc[][8])
{
#pragma unroll
    for (int kk = 0; kk < 4; kk++)
#pragma unroll
        for (int n = 0; n < 8; n++) {
            const int rw = n * 16 + l15, kb = kk * 64 + lg * 16;
            const bf16x8 b = ld_w(Wbuf, 0, rw, kb);
            acc[0][n] = __builtin_amdgcn_mfma_f32_16x16x32_bf16(a0[kk], b, acc[0][n], 0, 0, 0);
            acc[1][n] = __builtin_amdgcn_mfma_f32_16x16x32_bf16(a1[kk], b, acc[1][n], 0, 0, 0);
            if (NS == 2) {
                const bf16x8 bl = ld_w(Wbuf, 1, rw, kb);
                acc[0][n] = __builtin_amdgcn_mfma_f32_16x16x32_bf16(a0[kk], bl, acc[0][n], 0, 0, 0);
                acc[1][n] = __builtin_amdgcn_mfma_f32_16x16x32_bf16(a1[kk], bl, acc[1][n], 0, 0, 0);
            }
        }
}

// Split-A variant: acc += ah@W + al@W (+ ah@Wlo when NS==2)
template<int NS>
__device__ __forceinline__ void mfma_panel_split(const u16* Wbuf,
    const bf16x8* a0h, const bf16x8* a0l, const bf16x8* a1h, const bf16x8* a1l,
    int l15, int lg, f32x4 acc[][8])
{
#pragma unroll
    for (int kk = 0; kk < 4; kk++)
#pragma unroll
        for (int n = 0; n < 8; n++) {
            const int rw = n * 16 + l15, kb = kk * 64 + lg * 16;
            const bf16x8 b = ld_w(Wbuf, 0, rw, kb);
            acc[0][n] = __builtin_amdgcn_mfma_f32_16x16x32_bf16(a0h[kk], b, acc[0][n], 0, 0, 0);
            acc[0][n] = __builtin_amdgcn_mfma_f32_16x16x32_bf16(a0l[kk], b, acc[0][n], 0, 0, 0);
            acc[1][n] = __builtin_amdgcn_mfma_f32_16x16x32_bf16(a1h[kk], b, acc[1][n], 0, 0, 0);
            acc[1][n] = __builtin_amdgcn_mfma_f32_16x16x32_bf16(a1l[kk], b, acc[1][n], 0, 0, 0);
            if (NS == 2) {
                const bf16x8 bl = ld_w(Wbuf, 1, rw, kb);
                acc[0][n] = __builtin_amdgcn_mfma_f32_16x16x32_bf16(a0h[kk], bl, acc[0][n], 0, 0, 0);
                acc[1][n] = __builtin_amdgcn_mfma_f32_16x16x32_bf16(a1h[kk], bl, acc[1][n], 0, 0, 0);
            }
        }
}

__device__ __forceinline__ void splitf8(const float* p, bf16x8* hi, bf16x8* lo)
{
    const float4 f0 = *(const float4*)p;
    const float4 f1 = *(const float4*)(p + 4);
    const float f[8] = {f0.x, f0.y, f0.z, f0.w, f1.x, f1.y, f1.z, f1.w};
    union { u16 s[8]; bf16x8 v; } H, L;
#pragma unroll
    for (int j = 0; j < 8; j++) {
        const u16 hv = f2bf(f[j]);
        H.s[j] = hv;
        L.s[j] = f2bf(f[j] - bf2f(hv));
    }
    *hi = H.v; *lo = L.v;
}

// =====================================================================
// Staged-weight MFMA GEMM (bf16 A): C[M x 128] = A[M x K] @ W.
// 128-row blocks, 256 threads, 4 waves x 32 rows, 2 blocks/CU.
// want < 0: always run; else gated on dtype flag.
// =====================================================================
template<int NS, int KCH, bool OUT_BF16, bool ADD>
__global__ __launch_bounds__(256, 2) void sgemm_bf(
    const int* __restrict__ flag, int want,
    const u16* __restrict__ A, int lda,
    const u16* __restrict__ WHi, const u16* __restrict__ WLo,
    int wstride, int wcstep,
    void* __restrict__ Cv, int ldc)
{
    if (want >= 0 && *flag != want) return;
    __shared__ __align__(16) u16 Wbuf[NS * 16384];
    const int tid = threadIdx.x;
    const int lane = tid & 63, wv = tid >> 6;
    const int l15 = lane & 15, lg = lane >> 4;
    const long long row0 = (long long)blockIdx.x * 128 + wv * 32;

    f32x4 acc[2][8];
    {
        f32x4 z = {0.f, 0.f, 0.f, 0.f};
#pragma unroll
        for (int m = 0; m < 2; m++)
#pragma unroll
            for (int n = 0; n < 8; n++) acc[m][n] = z;
    }

    const u16* A0 = A + (row0 + l15) * (long long)lda + lg * 8;
    const u16* A1 = A0 + 16LL * lda;

    stage_async<NS, 256>(Wbuf, WHi, WLo, wstride, tid);
    for (int ks = 0; ks < KCH; ks++) {
        bf16x8 a0[4], a1[4];
#pragma unroll
        for (int kk = 0; kk < 4; kk++) {
            a0[kk] = *(const bf16x8*)(A0 + ks * 128 + kk * 32);
            a1[kk] = *(const bf16x8*)(A1 + ks * 128 + kk * 32);
        }
        __syncthreads();                       // panel staged (vmcnt drained)
        mfma_panel<NS>(Wbuf, a0, a1, l15, lg, acc);
        if (ks + 1 < KCH) {
            __syncthreads();                   // panel reads done before restage
            stage_async<NS, 256>(Wbuf, WHi + (ks + 1) * wcstep,
                                 WLo + (ks + 1) * wcstep, wstride, tid);
        }
    }

#pragma unroll
    for (int m = 0; m < 2; m++)
#pragma unroll
        for (int r = 0; r < 4; r++) {
            const long long row = row0 + m * 16 + lg * 4 + r;
            if (OUT_BF16) {
                u16* C = (u16*)Cv + row * ldc;
#pragma unroll
                for (int n = 0; n < 8; n++) C[n * 16 + l15] = f2bf(acc[m][n][r]);
            } else {
                float* C = (float*)Cv + row * ldc;
#pragma unroll
                for (int n = 0; n < 8; n++) {
                    float v = acc[m][n][r];
                    if (ADD) v += C[n * 16 + l15];
                    C[n * 16 + l15] = v;
                }
            }
        }
}

// =====================================================================
// Staged-weight MFMA GEMM (f32 A, split in-kernel into hi+lo bf16).
// OM: 0 = f32 store, 1 = bf16 store, 2 = d_out store by *flag
//     (bf16 if flag, else f32 = bf2f(f2bf(v)) to keep bits identical).
// =====================================================================
template<int NS, int KCH, int OM>
__global__ __launch_bounds__(256, 2) void sgemm_f32(
    const int* __restrict__ flag, int want,
    const float* __restrict__ A, int lda,
    const u16* __restrict__ WHi, const u16* __restrict__ WLo,
    int wstride, int wcstep,
    void* __restrict__ Cv, int ldc)
{
    if (want >= 0 && *flag != want) return;
    __shared__ __align__(16) u16 Wbuf[NS * 16384];
    const int tid = threadIdx.x;
    const int lane = tid & 63, wv = tid >> 6;
    const int l15 = lane & 15, lg = lane >> 4;
    const long long row0 = (long long)blockIdx.x * 128 + wv * 32;

    f32x4 acc[2][8];
    {
        f32x4 z = {0.f, 0.f, 0.f, 0.f};
#pragma unroll
        for (int m = 0; m < 2; m++)
#pragma unroll
            for (int n = 0; n < 8; n++) acc[m][n] = z;
    }

    const float* A0 = A + (row0 + l15) * (long long)lda + lg * 8;
    const float* A1 = A0 + 16LL * lda;

    stage_async<NS, 256>(Wbuf, WHi, WLo, wstride, tid);
    for (int ks = 0; ks < KCH; ks++) {
        bf16x8 a0h[4], a0l[4], a1h[4], a1l[4];
#pragma unroll
        for (int kk = 0; kk < 4; kk++) {
            splitf8(A0 + ks * 128 + kk * 32, &a0h[kk], &a0l[kk]);
            splitf8(A1 + ks * 128 + kk * 32, &a1h[kk], &a1l[kk]);
        }
        __syncthreads();
        mfma_panel_split<NS>(Wbuf, a0h, a0l, a1h, a1l, l15, lg, acc);
        if (ks + 1 < KCH) {
            __syncthreads();
            stage_async<NS, 256>(Wbuf, WHi + (ks + 1) * wcstep,
                                 WLo + (ks + 1) * wcstep, wstride, tid);
        }
    }

    const bool asbf = (OM == 2) ? (*flag != 0) : (OM == 1);
#pragma unroll
    for (int m = 0; m < 2; m++)
#pragma unroll
        for (int r = 0; r < 4; r++) {
            const long long row = row0 + m * 16 + lg * 4 + r;
            if (OM == 0) {
                float* C = (float*)Cv + row * ldc;
#pragma unroll
                for (int n = 0; n < 8; n++) C[n * 16 + l15] = acc[m][n][r];
            } else if (asbf) {
                u16* C = (u16*)Cv + row * ldc;
#pragma unroll
                for (int n = 0; n < 8; n++) C[n * 16 + l15] = f2bf(acc[m][n][r]);
            } else {
                float* C = (float*)Cv + row * ldc;
#pragma unroll
                for (int n = 0; n < 8; n++)
                    C[n * 16 + l15] = bf2f(f2bf(acc[m][n][r]));
            }
        }
}

// =====================================================================
// O-projection + residual + fused LN2: x += ob@Wo; h = LN(x)*g+b.
// 128-row blocks, 256 threads; each wave holds full 128-wide rows, so
// LN reduce = 8 local adds + shfl_xor(1,2,4,8) over the l15 group.
// =====================================================================
__global__ __launch_bounds__(256, 2) void sgemm_add_ln(
    const u16* __restrict__ A,
    const u16* __restrict__ WHi, const u16* __restrict__ WLo,
    float* __restrict__ x, const float* __restrict__ g,
    const float* __restrict__ bvec, u16* __restrict__ h)
{
    __shared__ __align__(16) u16 Wbuf[2 * 16384];
    const int tid = threadIdx.x;
    const int lane = tid & 63, wv = tid >> 6;
    const int l15 = lane & 15, lg = lane >> 4;
    const long long row0 = (long long)blockIdx.x * 128 + wv * 32;

    f32x4 acc[2][8];
    {
        f32x4 z = {0.f, 0.f, 0.f, 0.f};
#pragma unroll
        for (int m = 0; m < 2; m++)
#pragma unroll
            for (int n = 0; n < 8; n++) acc[m][n] = z;
    }

    const u16* A0 = A + (row0 + l15) * 128LL + lg * 8;
    const u16* A1 = A0 + 16LL * 128;

    stage_async<2, 256>(Wbuf, WHi, WLo, 128, tid);
    bf16x8 a0[4], a1[4];
#pragma unroll
    for (int kk = 0; kk < 4; kk++) {
        a0[kk] = *(const bf16x8*)(A0 + kk * 32);
        a1[kk] = *(const bf16x8*)(A1 + kk * 32);
    }
    __syncthreads();
    mfma_panel<2>(Wbuf, a0, a1, l15, lg, acc);

    float gv[8], bv[8];
#pragma unroll
    for (int n = 0; n < 8; n++) { gv[n] = g[n * 16 + l15]; bv[n] = bvec[n * 16 + l15]; }

#pragma unroll
    for (int m = 0; m < 2; m++)
#pragma unroll
        for (int r = 0; r < 4; r++) {
            const long long row = row0 + m * 16 + lg * 4 + r;
            float* X = x + row * CA;
            float v[8]; float s = 0.f, sq = 0.f;
#pragma unroll
            for (int n = 0; n < 8; n++) {
                v[n] = X[n * 16 + l15] + acc[m][n][r];
                X[n * 16 + l15] = v[n];
                s += v[n]; sq += v[n] * v[n];
            }
            s  += __shfl_xor(s, 1, 64);  s  += __shfl_xor(s, 2, 64);
            s  += __shfl_xor(s, 4, 64);  s  += __shfl_xor(s, 8, 64);
            sq += __shfl_xor(sq, 1, 64); sq += __shfl_xor(sq, 2, 64);
            sq += __shfl_xor(sq, 4, 64); sq += __shfl_xor(sq, 8, 64);
            const float mean = s * 0.0078125f;
            const float var  = sq * 0.0078125f - mean * mean;
            const float inv  = rsqrtf(var + 1e-5f);
            u16* H = h + row * CA;
#pragma unroll
            for (int n = 0; n < 8; n++)
                H[n * 16 + l15] = f2bf((v[n] - mean) * inv * gv[n] + bv[n]);
        }
}

// =====================================================================
// Fused QKV (512 thr, 256 rows/block): ping-pong two panel buffers;
// next panel's async loads issue before this panel's MFMA.
// =====================================================================
__global__ __launch_bounds__(512, 1) void qkv_fused(
    const u16* __restrict__ h, const u16* __restrict__ wl,
    u16* __restrict__ qb, u16* __restrict__ kb, u16* __restrict__ vb)
{
    __shared__ __align__(16) u16 bufA[2 * 16384];
    __shared__ __align__(16) u16 bufB[2 * 16384];
    const int tid = threadIdx.x;
    const int lane = tid & 63, wv = tid >> 6;
    const int l15 = lane & 15, lg = lane >> 4;
    const long long row0 = (long long)blockIdx.x * 256 + wv * 32;

    bf16x8 a0[4], a1[4];
#pragma unroll
    for (int kk = 0; kk < 4; kk++) {
        a0[kk] = *(const bf16x8*)(h + (row0 + l15) * 128 + kk * 32 + lg * 8);
        a1[kk] = *(const bf16x8*)(h + (row0 + 16 + l15) * 128 + kk * 32 + lg * 8);
    }

    stage_async<2, 512>(bufA, wl, wl + 16384, 128, tid);          // Q
    __syncthreads();

#pragma unroll
    for (int m = 0; m < 3; m++) {
        if (m < 2)   // prefetch next panel
            stage_async<2, 512>((m == 0) ? bufB : bufA,
                                wl + (m + 1) * 32768,
                                wl + (m + 1) * 32768 + 16384, 128, tid);
        f32x4 acc[2][8];
        {
            f32x4 z = {0.f, 0.f, 0.f, 0.f};
#pragma unroll
            for (int i = 0; i < 2; i++)
#pragma unroll
                for (int n = 0; n < 8; n++) acc[i][n] = z;
        }
        const u16* cur = (m == 1) ? bufB : bufA;   // Q:A, K:B, V:A
        mfma_panel<2>(cur, a0, a1, l15, lg, acc);
        u16* out = (m == 0) ? qb : (m == 1) ? kb : vb;
#pragma unroll
        for (int i = 0; i < 2; i++)
#pragma unroll
            for (int r = 0; r < 4; r++) {
                u16* C = out + (row0 + i * 16 + lg * 4 + r) * CA;
#pragma unroll
                for (int n = 0; n < 8; n++) C[n * 16 + l15] = f2bf(acc[i][n][r]);
            }
        if (m < 2) __syncthreads();   // drains prefetch; cur reads done
    }
}

// =====================================================================
// Fused MLP + residual + next-layer LN1 (512 thr, 256 rows/block):
// x += relu(h @ Wt1) @ Wt2; h_out = LN(x)*g+b (EMIT_H).
// Two weight buffers, async staging; hidden transpose via per-wave
// 32x80B quarter buffer (wave-local waits). LDS 148 KB.
// =====================================================================
template<bool EMIT_H>
__global__ __launch_bounds__(512, 1) void mlp_ln(
    const u16* __restrict__ h,
    const u16* __restrict__ W1T, const u16* __restrict__ W2T,
    float* __restrict__ x, const float* __restrict__ g,
    const float* __restrict__ bvec, u16* __restrict__ hout)
{
    __shared__ __align__(16) u16 W1buf[2 * 16384];
    __shared__ __align__(16) u16 W2buf[2 * 16384];
    __shared__ __align__(16) u16 Plq[8][32][40];   // per-wave 32 rows x 80 B
    const int tid = threadIdx.x;
    const int lane = tid & 63, wv = tid >> 6;
    const int l15 = lane & 15, lg = lane >> 4;
    const long long row0 = (long long)blockIdx.x * 256 + wv * 32;
    u16* pw = &Plq[wv][0][0];

    bf16x8 ah0[4], ah1[4];
#pragma unroll
    for (int kk = 0; kk < 4; kk++) {
        ah0[kk] = *(const bf16x8*)(h + (row0 + l15) * 128 + kk * 32 + lg * 8);
        ah1[kk] = *(const bf16x8*)(h + (row0 + 16 + l15) * 128 + kk * 32 + lg * 8);
    }

    f32x4 xacc[2][8];
    {
        f32x4 z = {0.f, 0.f, 0.f, 0.f};
#pragma unroll
        for (int m = 0; m < 2; m++)
#pragma unroll
            for (int n = 0; n < 8; n++) xacc[m][n] = z;
    }

    stage_async<2, 512>(W1buf, W1T, W1T + 65536, 128, tid);
    __syncthreads();

    for (int c = 0; c < 4; c++) {
        // ---- W1 phase: issue W2c loads, MFMA W1 under them ----
        stage_async<2, 512>(W2buf, W2T + c * 128, W2T + 65536 + c * 128, 512, tid);
        f32x4 hacc[2][8];
        {
            f32x4 z = {0.f, 0.f, 0.f, 0.f};
#pragma unroll
            for (int m = 0; m < 2; m++)
#pragma unroll
                for (int n = 0; n < 8; n++) hacc[m][n] = z;
        }
        mfma_panel<2>(W1buf, ah0, ah1, l15, lg, hacc);
        __syncthreads();                 // W2buf staged; all waves done W1 reads

        // ---- W2 phase: issue W1(c+1) loads, quarters + MFMA W2 ----
        if (c < 3)
            stage_async<2, 512>(W1buf, W1T + (c + 1) * 16384,
                                W1T + 65536 + (c + 1) * 16384, 128, tid);
#pragma unroll
        for (int q = 0; q < 4; q++) {
            asm volatile("s_waitcnt lgkmcnt(0)" ::: "memory");
#pragma unroll
            for (int m = 0; m < 2; m++)
#pragma unroll
                for (int j = 0; j < 2; j++)
#pragma unroll
                    for (int r = 0; r < 4; r++)
                        pw[(m * 16 + lg * 4 + r) * 40 + j * 16 + l15]
                            = f2bf(fmaxf(hacc[m][2 * q + j][r], 0.f));
            asm volatile("s_waitcnt lgkmcnt(0)" ::: "memory");
            union { uint4 v; bf16x8 b; } t0, t1;
            t0.v = *(const uint4*)(pw + l15 * 40 + lg * 8);
            t1.v = *(const uint4*)(pw + (16 + l15) * 40 + lg * 8);
#pragma unroll
            for (int n = 0; n < 8; n++) {
                const int rw = n * 16 + l15, kb = q * 64 + lg * 16;
                const bf16x8 b = ld_w(W2buf, 0, rw, kb);
                xacc[0][n] = __builtin_amdgcn_mfma_f32_16x16x32_bf16(t0.b, b, xacc[0][n], 0, 0, 0);
                xacc[1][n] = __builtin_amdgcn_mfma_f32_16x16x32_bf16(t1.b, b, xacc[1][n], 0, 0, 0);
                const bf16x8 bl = ld_w(W2buf, 1, rw, kb);
                xacc[0][n] = __builtin_amdgcn_mfma_f32_16x16x32_bf16(t0.b, bl, xacc[0][n], 0, 0, 0);
                xacc[1][n] = __builtin_amdgcn_mfma_f32_16x16x32_bf16(t1.b, bl, xacc[1][n], 0, 0, 0);
            }
        }
        if (c < 3) __syncthreads();      // W1buf(c+1) staged; W2buf reads done
    }

    float gv[8], bv[8];
    if (EMIT_H) {
#pragma unroll
        for (int n = 0; n < 8; n++) { gv[n] = g[n * 16 + l15]; bv[n] = bvec[n * 16 + l15]; }
    }

#pragma unroll
    for (int m = 0; m < 2; m++)
#pragma unroll
        for (int r = 0; r < 4; r++) {
            const long long row = row0 + m * 16 + lg * 4 + r;
            float* X = x + row * CA;
            float v[8]; float s = 0.f, sq = 0.f;
#pragma unroll
            for (int n = 0; n < 8; n++) {
                v[n] = X[n * 16 + l15] + xacc[m][n][r];
                X[n * 16 + l15] = v[n];
                s += v[n]; sq += v[n] * v[n];
            }
            if (EMIT_H) {
                s  += __shfl_xor(s, 1, 64);  s  += __shfl_xor(s, 2, 64);
                s  += __shfl_xor(s, 4, 64);  s  += __shfl_xor(s, 8, 64);
                sq += __shfl_xor(sq, 1, 64); sq += __shfl_xor(sq, 2, 64);
                sq += __shfl_xor(sq, 4, 64); sq += __shfl_xor(sq, 8, 64);
                const float mean = s * 0.0078125f;
                const float var  = sq * 0.0078125f - mean * mean;
                const float inv  = rsqrtf(var + 1e-5f);
                u16* H = hout + row * CA;
#pragma unroll
                for (int n = 0; n < 8; n++)
                    H[n * 16 + l15] = f2bf((v[n] - mean) * inv * gv[n] + bv[n]);
            }
        }
}

// =====================================================================
// Gather + LN1 of layer 0: one wave per atom row.
// =====================================================================
__global__ __launch_bounds__(256) void gather_ln_kernel(
    const float* __restrict__ atok, const int* __restrict__ idx,
    const float* __restrict__ g, const float* __restrict__ bvec,
    float* __restrict__ x, u16* __restrict__ h)
{
    const int lane = threadIdx.x & 63;
    const int wv   = threadIdx.x >> 6;
    const size_t an = (size_t)blockIdx.x * 4 + wv;
    const int b = (int)(an >> 14);
    const int n = (int)(an & (NATOM - 1));
    const int t = idx[b * NATOM + n];
    const float* src = atok + ((size_t)b * NTOK + t) * CA;
    const float v0 = src[lane], v1 = src[lane + 64];
    float* xr = x + an * CA;
    xr[lane] = v0; xr[lane + 64] = v1;
    float s  = v0 + v1;
    float sq = v0 * v0 + v1 * v1;
#pragma unroll
    for (int off = 32; off > 0; off >>= 1) {
        s  += __shfl_xor(s,  off, 64);
        sq += __shfl_xor(sq, off, 64);
    }
    const float mean = s * 0.0078125f;
    const float var  = sq * 0.0078125f - mean * mean;
    const float inv  = rsqrtf(var + 1e-5f);
    u16* hr = h + an * CA;
    hr[lane]      = f2bf((v0 - mean) * inv * g[lane]      + bvec[lane]);
    hr[lane + 64] = f2bf((v1 - mean) * inv * g[lane + 64] + bvec[lane + 64]);
}

// =====================================================================
// Bias: t[b,a,h] for a < 128 from the pair-MLP (f32 aux weights).
// Parallelized: grid = BB (one batch per block, 4 CUs), 128 threads.
// =====================================================================
__global__ __launch_bounds__(128) void bias_kernel(
    const float* __restrict__ x, const float* __restrict__ AX,
    float* __restrict__ tb)
{
    __shared__ float Wsum[128][16];
    __shared__ float M1[16][16];
    __shared__ float M2[16][16];
    __shared__ float Pb[16][4];
    const int tid = threadIdx.x;
    const int b   = blockIdx.x;
    for (int i = tid; i < 128 * 16; i += 128)
        Wsum[i >> 4][i & 15] = AX[AX_WCL + i] + AX[AX_WCM + i];
    for (int i = tid; i < 256; i += 128) {
        M1[i >> 4][i & 15] = AX[AX_WM1 + i];
        M2[i >> 4][i & 15] = AX[AX_WM2 + i];
    }
    if (tid < 64) Pb[tid >> 2][tid & 3] = AX[AX_WPB + tid];
    __syncthreads();

    const int a = tid;
    const float* xa = x + ((size_t)b * NATOM + a) * CA;
    float u[16];
#pragma unroll
    for (int p = 0; p < 16; p++) u[p] = 0.f;
    for (int c = 0; c < 128; c++) {
        const float xv = xa[c];
#pragma unroll
        for (int p = 0; p < 16; p++) u[p] = fmaf(xv, Wsum[c][p], u[p]);
    }
    float r1[16];
#pragma unroll
    for (int p = 0; p < 16; p++) r1[p] = 0.f;
    for (int c = 0; c < 16; c++) {
        const float rv = fmaxf(u[c], 0.f);
#pragma unroll
        for (int p = 0; p < 16; p++) r1[p] = fmaf(rv, M1[c][p], r1[p]);
    }
    float r2[16];
#pragma unroll
    for (int p = 0; p < 16; p++) r2[p] = 0.f;
    for (int c = 0; c < 16; c++) {
        const float rv = fmaxf(r1[c], 0.f);
#pragma unroll
        for (int p = 0; p < 16; p++) r2[p] = fmaf(rv, M2[c][p], r2[p]);
    }
#pragma unroll
    for (int hh = 0; hh < 4; hh++) {
        float s = 0.f;
#pragma unroll
        for (int p = 0; p < 16; p++) s = fmaf(r2[p], Pb[p][hh], s);
        tb[((size_t)b * 128 + a) * 4 + hh] = s;
    }
}

// =====================================================================
// Windowed attention via MFMA (verified round 1): one block per (b, w).
// XCD-aware blockIdx swizzle (T1): nwg = 2048 = 8 XCDs x 256, so each
// XCD gets 256 CONSECUTIVE windows -> the 96/128-row K/V window overlap
// between neighbors becomes per-XCD L2 hits instead of HBM refetches.
// (HW-verified round 13: ~23 us total gain.)
// =====================================================================
#define VTP 132   // V^T row stride in u16
#define PPS 68    // P row stride in u16

__global__ __launch_bounds__(256) void attn_kernel(
    const u16* __restrict__ qg, const u16* __restrict__ kg,
    const u16* __restrict__ vg, const float* __restrict__ tb,
    u16* __restrict__ og)
{
    __shared__ __align__(16) u16 VT[128][VTP];    // V^T: [d][j]
    __shared__ __align__(16) u16 Pl[NH][32][PPS]; // per-head P half

    const int tid  = threadIdx.x;
    const int lane = tid & 63;
    const int h    = tid >> 6;             // wave id == head
    const int bw   = (blockIdx.x & 7) * (BB * NWIN / 8) + (blockIdx.x >> 3);
    const int b    = bw >> 9;
    const int w    = bw & (NWIN - 1);
    const int row0 = w * NQ;
    const int kbase = row0 - PAD;          // first key atom (may be < 0)
    const int l15 = lane & 15;
    const int lg  = lane >> 4;

    // ---- stage V^T into LDS (all 256 threads; zero invalid rows) ----
    {
        const int j  = tid & 127;
        const int d0 = (tid >> 7) << 6;    // 0 or 64
        const int ga = kbase + j;
        const bool val = (ga >= 0) && (ga < NATOM);
        const u16* vrow = vg + ((long long)b * NATOM + ga) * CA + d0;
#pragma unroll
        for (int t2 = 0; t2 < 8; t2++) {
            union { uint4 q; u16 s[8]; } u;
            if (val) u.q = *(const uint4*)(vrow + t2 * 8);
            else     u.q = make_uint4(0u, 0u, 0u, 0u);
#pragma unroll
            for (int e = 0; e < 8; e++) VT[d0 + t2 * 8 + e][j] = u.s[e];
        }
    }

    // ---- QK^T: S[32][128] per head, frags direct from global ----
    const long long qoff = ((long long)b * NATOM + row0) * CA + h * DH;
    const long long koff = ((long long)b * NATOM + kbase) * CA + h * DH;
    bf16x8 aq0 = *(const bf16x8*)(qg + qoff + (long long)l15 * CA + lg * 8);
    bf16x8 aq1 = *(const bf16x8*)(qg + qoff + (long long)(l15 + 16) * CA + lg * 8);

    f32x4 acc[2][8];
    {
        f32x4 z = {0.f, 0.f, 0.f, 0.f};
#pragma unroll
        for (int m = 0; m < 2; m++)
#pragma unroll
            for (int n = 0; n < 8; n++) acc[m][n] = z;
    }
#pragma unroll
    for (int n = 0; n < 8; n++) {
        bf16x8 bk = *(const bf16x8*)(kg + koff + (long long)(n * 16 + l15) * CA + lg * 8);
        acc[0][n] = __builtin_amdgcn_mfma_f32_16x16x32_bf16(aq0, bk, acc[0][n], 0, 0, 0);
        acc[1][n] = __builtin_amdgcn_mfma_f32_16x16x32_bf16(aq1, bk, acc[1][n], 0, 0, 0);
    }

    // ---- bias + scale + mask ----
    const float scale = 0.17677669529663687f;  // 1/sqrt(32)
    float tj[8], ti[2][4];
#pragma unroll
    for (int n = 0; n < 8; n++)
        tj[n] = tb[((size_t)b * 128 + n * 16 + l15) * 4 + h];
#pragma unroll
    for (int m = 0; m < 2; m++)
#pragma unroll
        for (int r = 0; r < 4; r++)
            ti[m][r] = tb[((size_t)b * 128 + m * 16 + lg * 4 + r) * 4 + h];

#pragma unroll
    for (int n = 0; n < 8; n++) {
        const int ga = kbase + n * 16 + l15;
        const bool val = (ga >= 0) && (ga < NATOM);
#pragma unroll
        for (int m = 0; m < 2; m++)
#pragma unroll
            for (int r = 0; r < 4; r++) {
                const float s = acc[m][n][r] * scale + ti[m][r] + tj[n];
                acc[m][n][r] = val ? s : -1e9f;
            }
    }

    // ---- softmax ----
    float mx[2][4], inv[2][4];
#pragma unroll
    for (int m = 0; m < 2; m++)
#pragma unroll
        for (int r = 0; r < 4; r++) {
            float v = acc[m][0][r];
#pragma unroll
            for (int n = 1; n < 8; n++) v = fmaxf(v, acc[m][n][r]);
            v = fmaxf(v, __shfl_xor(v, 1, 64));
            v = fmaxf(v, __shfl_xor(v, 2, 64));
            v = fmaxf(v, __shfl_xor(v, 4, 64));
            v = fmaxf(v, __shfl_xor(v, 8, 64));
            mx[m][r] = v;
        }
#pragma unroll
    for (int m = 0; m < 2; m++)
#pragma unroll
        for (int n = 0; n < 8; n++)
#pragma unroll
            for (int r = 0; r < 4; r++)
                acc[m][n][r] = __expf(acc[m][n][r] - mx[m][r]);
#pragma unroll
    for (int m = 0; m < 2; m++)
#pragma unroll
        for (int r = 0; r < 4; r++) {
            float v = 0.f;
#pragma unroll
            for (int n = 0; n < 8; n++) v += acc[m][n][r];
            v += __shfl_xor(v, 1, 64);
            v += __shfl_xor(v, 2, 64);
            v += __shfl_xor(v, 4, 64);
            v += __shfl_xor(v, 8, 64);
            inv[m][r] = 1.0f / v;
        }

    __syncthreads();   // V^T staged

    // ---- PV ----
    f32x4 o[2][2];
    {
        f32x4 z = {0.f, 0.f, 0.f, 0.f};
        o[0][0] = z; o[0][1] = z; o[1][0] = z; o[1][1] = z;
    }
    union B8 { bf16x8 v; uint2 u[2]; };
#pragma unroll
    for (int half = 0; half < 2; half++) {
        asm volatile("s_waitcnt lgkmcnt(0)" ::: "memory");
#pragma unroll
        for (int m = 0; m < 2; m++)
#pragma unroll
            for (int nn = 0; nn < 4; nn++)
#pragma unroll
                for (int r = 0; r < 4; r++)
                    Pl[h][m * 16 + lg * 4 + r][nn * 16 + l15]
                        = f2bf(acc[m][half * 4 + nn][r]);
        asm volatile("s_waitcnt lgkmcnt(0)" ::: "memory");
#pragma unroll
        for (int ks2 = 0; ks2 < 2; ks2++) {
            const int jo = ks2 * 32 + lg * 8;
            const int jg = half * 64 + jo;
            B8 pa0, pa1, vb0, vb1;
            pa0.u[0] = *(const uint2*)&Pl[h][l15][jo];
            pa0.u[1] = *(const uint2*)&Pl[h][l15][jo + 4];
            pa1.u[0] = *(const uint2*)&Pl[h][l15 + 16][jo];
            pa1.u[1] = *(const uint2*)&Pl[h][l15 + 16][jo + 4];
            vb0.u[0] = *(const uint2*)&VT[h * DH + l15][jg];
            vb0.u[1] = *(const uint2*)&VT[h * DH + l15][jg + 4];
            vb1.u[0] = *(const uint2*)&VT[h * DH + 16 + l15][jg];
            vb1.u[1] = *(const uint2*)&VT[h * DH + 16 + l15][jg + 4];
            o[0][0] = __builtin_amdgcn_mfma_f32_16x16x32_bf16(pa0.v, vb0.v, o[0][0], 0, 0, 0);
            o[0][1] = __builtin_amdgcn_mfma_f32_16x16x32_bf16(pa0.v, vb1.v, o[0][1], 0, 0, 0);
            o[1][0] = __builtin_amdgcn_mfma_f32_16x16x32_bf16(pa1.v, vb0.v, o[1][0], 0, 0, 0);
            o[1][1] = __builtin_amdgcn_mfma_f32_16x16x32_bf16(pa1.v, vb1.v, o[1][1], 0, 0, 0);
        }
    }

#pragma unroll
    for (int m = 0; m < 2; m++)
#pragma unroll
        for (int n = 0; n < 2; n++)
#pragma unroll
            for (int r = 0; r < 4; r++)
                og[((long long)b * NATOM + row0 + m * 16 + lg * 4 + r) * CA
                   + h * DH + n * 16 + l15]
                    = f2bf(o[m][n][r] * inv[m][r]);
}

// =====================================================================
// Launch — single dtype-independent pipeline; only wtrans + token
// projection are flag-gated pairs.  Final GEMM writes d_out directly.
// =====================================================================
extern "C" void kernel_launch(void* const* d_in, const int* in_sizes, int n_in,
                              void* d_out, int out_size, void* d_ws, size_t ws_size,
                              hipStream_t stream)
{
    (void)in_sizes; (void)n_in; (void)out_size;
    const size_t NEL = (size_t)BB * NATOM * CA;   // 8388608

    char* p = (char*)d_ws;
    float* x    = (float*)p;  p += NEL * 4;
    u16*   h    = (u16*)p;    p += NEL * 2;
    u16*   qb   = (u16*)p;    p += NEL * 2;
    u16*   kb   = (u16*)p;    p += NEL * 2;
    u16*   vb   = (u16*)p;    p += NEL * 2;
    u16*   ob   = (u16*)p;    p += NEL * 2;
    float* atok = (float*)p;  p += (size_t)BB * NTOK * CA * 4;
    float* tbv  = (float*)p;  p += 8192;
    int*   flag = (int*)p;    p += 256;
    u16*   wt   = (u16*)p;    p += (size_t)WT_TOT * 2;
    float* aux  = (float*)p;  p += AX_TOT * 4;
    if ((size_t)(p - (char*)d_ws) > ws_size) return;  // workspace too small

    // 1) detect input storage dtype (writes flag: 1=bf16, 0=f32)
    detect_kernel<<<1, 256, 0, stream>>>((const u32*)d_in[3], flag);

    // 2) weight preprocessing (gated pair; exactly one runs)
    wtrans_kernel<u16><<<41, 256, 0, stream>>>(
        flag, 1, (const u16*)d_in[3], (const u16*)d_in[10], (const u16*)d_in[11],
        (const u16*)d_in[12], (const u16*)d_in[13], (const u16*)d_in[16],
        (const u16*)d_in[17], (const u16*)d_in[4], (const u16*)d_in[5],
        (const u16*)d_in[6], (const u16*)d_in[7], (const u16*)d_in[8],
        (const u16*)d_in[9], (const u16*)d_in[14], (const u16*)d_in[15],
        (const u16*)d_in[18], (const u16*)d_in[19], wt, aux);
    wtrans_kernel<float><<<41, 256, 0, stream>>>(
        flag, 0, (const float*)d_in[3], (const float*)d_in[10], (const float*)d_in[11],
        (const float*)d_in[12], (const float*)d_in[13], (const float*)d_in[16],
        (const float*)d_in[17], (const float*)d_in[4], (const float*)d_in[5],
        (const float*)d_in[6], (const float*)d_in[7], (const float*)d_in[8],
        (const float*)d_in[9], (const float*)d_in[14], (const float*)d_in[15],
        (const float*)d_in[18], (const float*)d_in[19], wt, aux);

    // 3) token projection (gated pair)
    sgemm_bf<1, 3, false, false><<<BB * NTOK / 128, 256, 0, stream>>>(
        flag, 1, (const u16*)d_in[0], CTOK, wt + WT_WA, wt + WT_WA + 49152,
        CTOK, 128, atok, CA);
    sgemm_f32<2, 3, 0><<<BB * NTOK / 128, 256, 0, stream>>>(
        flag, 0, (const float*)d_in[0], CTOK, wt + WT_WA, wt + WT_WA + 49152,
        CTOK, 128, atok, CA);

    // 4) gather + layer-0 LN1
    gather_ln_kernel<<<BB * NATOM / 4, 256, 0, stream>>>(
        atok, (const int*)d_in[2], aux + AX_L1G, aux + AX_L1B, x, h);
    bias_kernel<<<BB, 128, 0, stream>>>(x, aux, tbv);

    // 5) layers
    for (int l = 0; l < 3; l++) {
        u16* wl = wt + WT_L0 + (size_t)l * WT_LSZ;
        qkv_fused<<<256, 512, 0, stream>>>(h, wl, qb, kb, vb);
        attn_kernel<<<BB * NWIN, 256, 0, stream>>>(qb, kb, vb, tbv, ob);
        sgemm_add_ln<<<512, 256, 0, stream>>>(
            ob, wl + 98304, wl + 98304 + 16384, x,
            aux + AX_L2G + l * 128, aux + AX_L2B + l * 128, h);
        if (l < 2)
            mlp_ln<true><<<256, 512, 0, stream>>>(
                h, wl + 131072, wl + 262144, x,
                aux + AX_L1G + (l + 1) * 128, aux + AX_L1B + (l + 1) * 128, h);
        else
            mlp_ln<false><<<256, 512, 0, stream>>>(
                h, wl + 131072, wl + 262144, x, aux, aux, h);
    }

    // 6) out = x @ W_out -> d_out directly, format by flag (always runs)
    sgemm_f32<2, 1, 2><<<512, 256, 0, stream>>>(
        flag, -1, x, CA, wt + WT_WO, wt + WT_WO + 16384, CA, 0, d_out, CA);
}